// Round 6
// baseline (1731.507 us; speedup 1.0000x reference)
//
#include <hip/hip_runtime.h>
#include <hip/hip_bf16.h>
#include <hip/hip_cooperative_groups.h>

namespace cg = cooperative_groups;

// Representation_32074815766664 — bf16 I/O (runtime-detected f32 fallback),
// bf16 MFMA internally, f32 accumulation/state.
//
// R16 changes vs R15 (1515 us — REGRESSION, reverted):
//  - R15 post-mortem: packing the tree onto 64 CUs quadrupled per-CU L2
//    weight demand (75 MB/level streams) -> L2-delivery-bound on 1/4 of the
//    machine, +23 us/level. Tree reverted to the R12-proven work assignment:
//    grid (32,8), 256 thr, 4 waves sharing one jt weight tile, unroll 4.
//  - New lever: the 20 tree levels are now ONE cooperative kernel with
//    cg::this_grid().sync() between levels (identical per-level body).
//    Removes 19 launch+drain boundaries (~2-5 us each); 256 blocks x 256 thr
//    co-resident (no LDS). Bias loads + weight base hoisted out of the level
//    loop. h_f32 written only on the final level.
//  - lstm1 FROZEN at R12 form (265 us verified).

typedef __bf16 bf16x8 __attribute__((ext_vector_type(8)));
typedef float f32x4 __attribute__((ext_vector_type(4)));

#define MROWS 10240
#define LDH1  552     // padded LDS stride (2-way bank aliasing only)
#define L1_ROWS 48
#define L1_BLOCKS 214 // ceil(10240/48)

// pf (canonical f32 params) offsets
#define PF_BIAS1   0
#define PF_BIAS2   2048
#define PF_CONDB   4096
#define PF_SAMPB   4352
#define PF_BCAT2   4608
#define PF_B3CAT   5120
#define PF_BN1G    5632
#define PF_BN1B    5888
#define PF_BN2G    6144
#define PF_BN2B    6656
#define PF_BN3G    7168
#define PF_BN3B    7424
#define PF_OW      7680
#define PF_OB      8192
#define PF_TOTAL   8194

// sig(x) = 1/(1+exp(-x)); robust without clamps: exp->inf => rcp->0.
__device__ __forceinline__ float fsig(float x) {
  return __builtin_amdgcn_rcpf(1.0f + __expf(-x));
}
// tanh(x) = 2*sig(2x) - 1; robust at both infinities.
__device__ __forceinline__ float ftanh(float x) {
  return fmaf(2.0f, __builtin_amdgcn_rcpf(1.0f + __expf(-2.0f * x)), -1.0f);
}
__device__ __forceinline__ bf16x8 bzero8() {
  bf16x8 z;
#pragma unroll
  for (int i = 0; i < 8; ++i) z[i] = (__bf16)0.0f;
  return z;
}
__device__ __forceinline__ float ld_in(const void* p, long i, int bf) {
  return bf ? (float)((const __bf16*)p)[i] : ((const float*)p)[i];
}

// ---------------- detect ----------------
__global__ void detect_kernel(const unsigned* __restrict__ masks, int* __restrict__ flag) {
  if (blockIdx.x == 0 && threadIdx.x == 0)
    *flag = (masks[0] == 0x3F803F80u) ? 1 : 0;
}

// ---------------- prep: canonicalize; w1s swizzled, w2s swizzled ----------------
// w1s: elem((cgt*17+kk)*4+g, lane, e) = w_aug1[g*512+cgt*16+(lane&15)][kk*32+(lane>>4)*8+e]
__global__ void prep_kernel(const int* __restrict__ flagp,
    const void* w_ih1, const void* w_hh1, const void* b_ih1, const void* b_hh1,
    const void* w_ih2, const void* w_hh2, const void* b_ih2, const void* b_hh2,
    const void* t1_w2, const void* t2_w2, const void* t1_b2, const void* t2_b2,
    const void* cond_w, const void* cond_b, const void* sample_w, const void* sample_b,
    const void* bn1_g, const void* bn1_b, const void* bn2_g, const void* bn2_b,
    const void* bn3_g, const void* bn3_b,
    const void* t1_w3, const void* t1_b3, const void* t2_w3, const void* t2_b3,
    const void* t1_ow, const void* t1_ob, const void* t2_ow, const void* t2_ob,
    const void* masks,
    __bf16* __restrict__ w1s, __bf16* __restrict__ w2s,
    __bf16* __restrict__ wcat2, __bf16* __restrict__ cond_w_bf,
    __bf16* __restrict__ sample_w_bf, __bf16* __restrict__ w3cat_bf,
    float* __restrict__ mask_f, float* __restrict__ pf)
{
  const int bf = *flagp;
  const int S1 = 2048 * 544;   // w1s swizzled
  const int S2 = 2048 * 1152;  // w2s swizzled
  const int S3 = 512 * 512;
  const int S4 = 256 * 512;
  const int S5 = 256 * 1000;
  const int S6 = 512 * 256;
  const int S7 = 10240;
  const int total = S1 + S2 + S3 + S4 + S5 + S6 + S7 + PF_TOTAL;
  for (int idx = blockIdx.x * blockDim.x + threadIdx.x; idx < total;
       idx += gridDim.x * blockDim.x) {
    int i = idx;
    if (i < S1) {
      int e = i & 7, l = (i >> 3) & 63, g = (i >> 9) & 3;
      int grp = i >> 11;               // cgt*17 + kk
      int kk = grp % 17, cgt = grp / 17;
      int colq = l & 15, quad = l >> 4;
      int row = g * 512 + cgt * 16 + colq;
      int k = kk * 32 + quad * 8 + e;
      float v = (k < 512) ? ld_in(w_hh1, (long)row * 512 + k, bf)
              : (k < 525) ? ld_in(w_ih1, (long)row * 13 + (k - 512), bf) : 0.0f;
      w1s[i] = (__bf16)v;
      continue;
    }
    i -= S1;
    if (i < S2) {
      int e = i & 7, l = (i >> 3) & 63, g = (i >> 9) & 3;
      int grp = i >> 11;               // jt*36 + kk
      int kk = grp % 36, jt = grp / 36;
      int colq = l & 15, quad = l >> 4;
      int row = g * 512 + jt * 16 + colq;
      int k = kk * 32 + quad * 8 + e;
      float v = (k < 635) ? ld_in(w_ih2, (long)row * 635 + k, bf)
              : (k < 640) ? 0.0f : ld_in(w_hh2, (long)row * 512 + (k - 640), bf);
      w2s[i] = (__bf16)v;
      continue;
    }
    i -= S2;
    if (i < S3) {
      int r = i >> 9, k = i & 511;
      wcat2[i] = (__bf16)((r < 256) ? ld_in(t1_w2, r * 512 + k, bf)
                                    : ld_in(t2_w2, (r - 256) * 512 + k, bf));
      continue;
    }
    i -= S3;
    if (i < S4) { cond_w_bf[i] = (__bf16)ld_in(cond_w, i, bf); continue; }
    i -= S4;
    if (i < S5) { sample_w_bf[i] = (__bf16)ld_in(sample_w, i, bf); continue; }
    i -= S5;
    if (i < S6) {
      int r = i >> 8, k = i & 255;
      w3cat_bf[i] = (__bf16)((r < 256) ? ld_in(t1_w3, r * 256 + k, bf)
                                       : ld_in(t2_w3, (r - 256) * 256 + k, bf));
      continue;
    }
    i -= S6;
    if (i < S7) { mask_f[i] = ld_in(masks, i, bf); continue; }
    i -= S7;
    {
      int j = i;
      float v;
      if      (j < 2048) v = ld_in(b_ih1, j, bf) + ld_in(b_hh1, j, bf);
      else if (j < 4096) v = ld_in(b_ih2, j - 2048, bf) + ld_in(b_hh2, j - 2048, bf);
      else if (j < 4352) v = ld_in(cond_b, j - 4096, bf);
      else if (j < 4608) v = ld_in(sample_b, j - 4352, bf);
      else if (j < 5120) { int k = j - 4608; v = (k < 256) ? ld_in(t1_b2, k, bf) : ld_in(t2_b2, k - 256, bf); }
      else if (j < 5632) { int k = j - 5120; v = (k < 256) ? ld_in(t1_b3, k, bf) : ld_in(t2_b3, k - 256, bf); }
      else if (j < 5888) v = ld_in(bn1_g, j - 5632, bf);
      else if (j < 6144) v = ld_in(bn1_b, j - 5888, bf);
      else if (j < 6656) v = ld_in(bn2_g, j - 6144, bf);
      else if (j < 7168) v = ld_in(bn2_b, j - 6656, bf);
      else if (j < 7424) v = ld_in(bn3_g, j - 7168, bf);
      else if (j < 7680) v = ld_in(bn3_b, j - 7424, bf);
      else if (j < 8192) { int k = j - 7680; v = (k < 256) ? ld_in(t1_ow, k, bf) : ld_in(t2_ow, k - 256, bf); }
      else v = (j == 8192) ? ld_in(t1_ob, 0, bf) : ld_in(t2_ob, 0, bf);
      pf[j] = v;
    }
  }
}

// ---------------- samples -> bf16 (only needed on f32 path) ----------------
__global__ void conv_samples_kernel(const int* __restrict__ flagp,
                                    const void* __restrict__ samples,
                                    __bf16* __restrict__ dst)
{
  const int bf = *flagp;
  if (bf) return;   // bf16 input is already the matrix the GEMM reads
  for (long i = blockIdx.x * blockDim.x + threadIdx.x; i < 10240000L;
       i += (long)gridDim.x * blockDim.x)
    dst[i] = (__bf16)ld_in(samples, i, bf);
}

// ---------------- featcopy (Astage stride 640) ----------------
__global__ void featcopy_kernel(const int* __restrict__ flagp,
                                const void* __restrict__ ops,
                                const void* __restrict__ extra,
                                __bf16* __restrict__ Astage)
{
  const int bf = *flagp;
  int idx = blockIdx.x * blockDim.x + threadIdx.x;  // exactly 10240*128
  int m = idx >> 7, c = idx & 127;
  float v; int col;
  if (c < 15)       { v = ld_in(ops, (long)m * 15 + c, bf);            col = c; }
  else if (c < 123) { v = ld_in(extra, (long)m * 108 + (c - 15), bf);  col = c; }
  else              { v = 0.0f;                                        col = 512 + c; } // 635..639
  Astage[(size_t)m * 640 + col] = (__bf16)v;
}

// ---------------- fused 10-step LSTM-1 — R12 form (FROZEN) ----------
// grid 214 x 1024 threads (16 waves). Block owns 48 rows. Wave owns 32 hidden
// cols (cg<2). 4 waves/SIMD. hbuf[2]: augmented h[48][552]. One barrier per
// timestep. kk loop unroll 1, direct hbuf indexing (R11: full unroll spills;
// R13: loop-carried pointers break LDS addrspace inference).
__global__ __launch_bounds__(1024, 4) void lstm1_kernel(
    const int* __restrict__ flagp,
    const void* __restrict__ cond1,     // (10240,10,13)
    const __bf16* __restrict__ w1s,     // swizzled (2048x544)
    const float*  __restrict__ bias,    // (2048)
    __bf16* __restrict__ h_out)         // (10272,512) padded
{
  __shared__ __attribute__((aligned(16))) __bf16 hbuf[2][L1_ROWS * LDH1];
  const int bf   = *flagp;
  const int tid  = threadIdx.x;
  const int wave = tid >> 6;
  const int lane = tid & 63;
  const int colq = lane & 15;
  const int quad = lane >> 4;
  const int r0   = blockIdx.x * L1_ROWS;

  {
    bf16x8 z8 = bzero8();
    for (int i = tid * 8; i < 2 * L1_ROWS * LDH1; i += 1024 * 8)
      *(bf16x8*)&hbuf[0][i] = z8;
  }
  __syncthreads();
  if (tid < L1_ROWS * 8) {           // stage x_0 into buf 0
    int row = tid >> 3, jj = tid & 7;
    int gr = r0 + row;
    if (gr < MROWS) {
      long base = (long)gr * 130;  // t=0
      hbuf[0][row * LDH1 + 512 + jj] = (__bf16)ld_in(cond1, base + jj, bf);
      if (jj < 5) hbuf[0][row * LDH1 + 520 + jj] = (__bf16)ld_in(cond1, base + 8 + jj, bf);
    }
  }
  __syncthreads();

  float c_reg[2][3][4];
#pragma unroll
  for (int a = 0; a < 2; ++a)
#pragma unroll
    for (int b = 0; b < 3; ++b)
#pragma unroll
      for (int r = 0; r < 4; ++r) c_reg[a][b][r] = 0.0f;

  const int jbase = wave * 32;

  // biases hoisted out of the t loop (barrier blocks compiler hoisting)
  float bI[2], bF[2], bG[2], bO[2];
#pragma unroll
  for (int cg = 0; cg < 2; ++cg) {
    const int j = jbase + cg * 16 + colq;
    bI[cg] = bias[j];
    bF[cg] = bias[512 + j];
    bG[cg] = bias[1024 + j];
    bO[cg] = bias[1536 + j];
  }

#pragma unroll 1
  for (int t = 0; t < 10; ++t) {
    const __bf16* hcur = hbuf[t & 1];
    __bf16* hnxt = hbuf[(t + 1) & 1];
#pragma unroll
    for (int cg = 0; cg < 2; ++cg) {
      const int jc = jbase + cg * 16;
      f32x4 acc[3][4];
#pragma unroll
      for (int a = 0; a < 3; ++a)
#pragma unroll
        for (int g = 0; g < 4; ++g)
#pragma unroll
          for (int r = 0; r < 4; ++r) acc[a][g][r] = 0.0f;

      // col-tile index 0..31 = wave*2+cg (same swizzle as 8-wave wave*4+cg)
      const __bf16* wp = w1s + ((size_t)(wave * 2 + cg) * 17 * 4 * 512) + (lane << 3);
#pragma unroll 1
      for (int kk = 0; kk < 17; ++kk) {
        const int kof = (kk << 5) + (quad << 3);
        bf16x8 af[3];
#pragma unroll
        for (int rt = 0; rt < 3; ++rt)
          af[rt] = *(const bf16x8*)&hcur[(rt * 16 + colq) * LDH1 + kof];
        bf16x8 bfr[4];
#pragma unroll
        for (int g = 0; g < 4; ++g)
          bfr[g] = *(const bf16x8*)&wp[(kk * 4 + g) << 9];
#pragma unroll
        for (int g = 0; g < 4; ++g)
#pragma unroll
          for (int rt = 0; rt < 3; ++rt)
            acc[rt][g] = __builtin_amdgcn_mfma_f32_16x16x32_bf16(af[rt], bfr[g], acc[rt][g], 0, 0, 0);
      }
#pragma unroll
      for (int rt = 0; rt < 3; ++rt)
#pragma unroll
        for (int r = 0; r < 4; ++r) {
          float c = fsig(acc[rt][1][r] + bF[cg]) * c_reg[cg][rt][r]
                  + fsig(acc[rt][0][r] + bI[cg]) * ftanh(acc[rt][2][r] + bG[cg]);
          c_reg[cg][rt][r] = c;
          float h = fsig(acc[rt][3][r] + bO[cg]) * ftanh(c);
          hnxt[(rt * 16 + quad * 4 + r) * LDH1 + jc + colq] = (__bf16)h;
        }
    }
    if (t < 9 && tid < L1_ROWS * 8) {   // stage x_{t+1} into next buffer
      int row = tid >> 3, jj = tid & 7;
      int gr = r0 + row;
      if (gr < MROWS) {
        long base = ((long)gr * 10 + (t + 1)) * 13;
        hnxt[row * LDH1 + 512 + jj] = (__bf16)ld_in(cond1, base + jj, bf);
        if (jj < 5) hnxt[row * LDH1 + 520 + jj] = (__bf16)ld_in(cond1, base + 8 + jj, bf);
      }
    }
    __syncthreads();
  }

  // final h is in buffer 0 (t=10 even)
  for (int i = tid; i < L1_ROWS * 64; i += 1024) {
    int row = i >> 6;
    int cb  = (i & 63) << 3;
    *(bf16x8*)&h_out[(size_t)(r0 + row) * 512 + cb] = *(const bf16x8*)&hbuf[0][row * LDH1 + cb];
  }
}

// ---------------- generic MFMA GEMM: out = act(A @ W^T + bias) [* mask] ----------------
template<int ACT, int OUTBF, int MASKED>
__global__ __launch_bounds__(256, 4) void gemm_kernel(
    const __bf16* __restrict__ A, int lda,
    const __bf16* __restrict__ W, int ldw,
    const float* __restrict__ bias,
    float* __restrict__ outf, __bf16* __restrict__ outb, int ldc,
    const float* __restrict__ mask, int K)
{
  const int tid  = threadIdx.x;
  const int wave = tid >> 6;
  const int lane = tid & 63;
  const int colq = lane & 15;
  const int quad = lane >> 4;
  const int m0 = blockIdx.y * 64 + (wave >> 1) * 32;
  const int n0 = blockIdx.x * 64 + (wave & 1) * 32;

  f32x4 acc[2][2];
#pragma unroll
  for (int a = 0; a < 2; ++a)
#pragma unroll
    for (int b = 0; b < 2; ++b)
#pragma unroll
      for (int r = 0; r < 4; ++r) acc[a][b][r] = 0.0f;

  const int nk = (K + 31) >> 5;
  for (int kk = 0; kk < nk; ++kk) {
    const int kof = (kk << 5) + (quad << 3);
    bf16x8 a0, a1, b0, b1;
    if (kof < K) {
      a0 = *(const bf16x8*)&A[(size_t)(m0 + colq) * lda + kof];
      a1 = *(const bf16x8*)&A[(size_t)(m0 + 16 + colq) * lda + kof];
      b0 = *(const bf16x8*)&W[(size_t)(n0 + colq) * ldw + kof];
      b1 = *(const bf16x8*)&W[(size_t)(n0 + 16 + colq) * ldw + kof];
    } else {
      a0 = bzero8(); a1 = a0; b0 = a0; b1 = a0;
    }
    acc[0][0] = __builtin_amdgcn_mfma_f32_16x16x32_bf16(a0, b0, acc[0][0], 0, 0, 0);
    acc[0][1] = __builtin_amdgcn_mfma_f32_16x16x32_bf16(a0, b1, acc[0][1], 0, 0, 0);
    acc[1][0] = __builtin_amdgcn_mfma_f32_16x16x32_bf16(a1, b0, acc[1][0], 0, 0, 0);
    acc[1][1] = __builtin_amdgcn_mfma_f32_16x16x32_bf16(a1, b1, acc[1][1], 0, 0, 0);
  }
#pragma unroll
  for (int ai = 0; ai < 2; ++ai)
#pragma unroll
    for (int bi = 0; bi < 2; ++bi) {
      const int col = n0 + bi * 16 + colq;
      const float bv = bias[col];
#pragma unroll
      for (int r = 0; r < 4; ++r) {
        const int row = m0 + ai * 16 + quad * 4 + r;
        float v = acc[ai][bi][r] + bv;
        if (ACT) v = fmaxf(v, 0.0f);
        if (MASKED) v *= mask[row];
        if (OUTBF) outb[(size_t)row * ldc + col] = (__bf16)v;
        else       outf[(size_t)row * ldc + col] = v;
      }
    }
}

// ---------------- samples GEMM: A chosen by dtype flag ----------------
// out = relu(A @ W^T + b) * mask -> Astage cols 379..634 (ldc 640), K=1000.
__global__ __launch_bounds__(256, 4) void sampgemm_kernel(
    const int* __restrict__ flagp,
    const void* __restrict__ samples_raw,   // bf16 path reads this directly
    const __bf16* __restrict__ samp_bf,     // f32 path: converted copy
    const __bf16* __restrict__ W,
    const float* __restrict__ bias,
    __bf16* __restrict__ outb,
    const float* __restrict__ mask)
{
  const __bf16* A = (*flagp) ? (const __bf16*)samples_raw : samp_bf;
  const int tid  = threadIdx.x;
  const int wave = tid >> 6;
  const int lane = tid & 63;
  const int colq = lane & 15;
  const int quad = lane >> 4;
  const int m0 = blockIdx.y * 64 + (wave >> 1) * 32;
  const int n0 = blockIdx.x * 64 + (wave & 1) * 32;
  const int K = 1000;

  f32x4 acc[2][2];
#pragma unroll
  for (int a = 0; a < 2; ++a)
#pragma unroll
    for (int b = 0; b < 2; ++b)
#pragma unroll
      for (int r = 0; r < 4; ++r) acc[a][b][r] = 0.0f;

  for (int kk = 0; kk < 32; ++kk) {
    const int kof = (kk << 5) + (quad << 3);
    bf16x8 a0, a1, b0, b1;
    if (kof < K) {
      a0 = *(const bf16x8*)&A[(size_t)(m0 + colq) * 1000 + kof];
      a1 = *(const bf16x8*)&A[(size_t)(m0 + 16 + colq) * 1000 + kof];
      b0 = *(const bf16x8*)&W[(size_t)(n0 + colq) * 1000 + kof];
      b1 = *(const bf16x8*)&W[(size_t)(n0 + 16 + colq) * 1000 + kof];
    } else {
      a0 = bzero8(); a1 = a0; b0 = a0; b1 = a0;
    }
    acc[0][0] = __builtin_amdgcn_mfma_f32_16x16x32_bf16(a0, b0, acc[0][0], 0, 0, 0);
    acc[0][1] = __builtin_amdgcn_mfma_f32_16x16x32_bf16(a0, b1, acc[0][1], 0, 0, 0);
    acc[1][0] = __builtin_amdgcn_mfma_f32_16x16x32_bf16(a1, b0, acc[1][0], 0, 0, 0);
    acc[1][1] = __builtin_amdgcn_mfma_f32_16x16x32_bf16(a1, b1, acc[1][1], 0, 0, 0);
  }
#pragma unroll
  for (int ai = 0; ai < 2; ++ai)
#pragma unroll
    for (int bi = 0; bi < 2; ++bi) {
      const int col = n0 + bi * 16 + colq;
      const float bv = bias[col];
#pragma unroll
      for (int r = 0; r < 4; ++r) {
        const int row = m0 + ai * 16 + quad * 4 + r;
        float v = fmaxf(acc[ai][bi][r] + bv, 0.0f) * mask[row];
        outb[(size_t)row * 640 + col] = (__bf16)v;
      }
    }
}

// ---------------- cooperative fused tree: 20 levels, grid.sync between ----------
// Work assignment per level = R12-proven treelvl: 256 blocks (32 jt x 8 mt),
// 256 thr (4 waves = 4 row sub-tiles), unroll 4. Weight base + biases hoisted
// across levels. grid.sync() provides cross-XCD visibility of h/c ping-pong.
__global__ __launch_bounds__(256, 4) void tree_kernel(
    const __bf16* Astage,     // (20,512,640) level features
    const __bf16* w2s,        // swizzled (2048x1152)
    const float*  bias,       // 2048 (PF_BIAS2)
    const int*    mapping_all,// (20,2,512)
    __bf16* hs0, __bf16* hs1,
    float*  cs0, float*  cs1,
    float*  h_f32)
{
  cg::grid_group grid = cg::this_grid();
  const int tid  = threadIdx.x;
  const int wv   = tid >> 6;
  const int lane = tid & 63;
  const int colq = lane & 15;
  const int quad = lane >> 4;
  const int jt = blockIdx.x;
  const int mt = blockIdx.y;
  const int rowA = mt * 64 + wv * 16 + colq;
  const int mrow0 = mt * 64 + wv * 16 + quad * 4;

  const __bf16* wbase = w2s + (size_t)jt * 36 * 4 * 512 + (lane << 3);
  const int j = jt * 16 + colq;
  const float bi  = bias[j];
  const float bff = bias[512 + j];
  const float bg  = bias[1024 + j];
  const float bo  = bias[1536 + j];

#pragma unroll 1
  for (int lvl = 19; lvl >= 0; --lvl) {
    const int first = (lvl == 19);
    const __bf16* Alvl = Astage + (size_t)lvl * 512 * 640;
    const int* mapping = mapping_all + lvl * 1024;
    __bf16* h_dst = (lvl & 1) ? hs1 : hs0;
    float*  c_dst = (lvl & 1) ? cs1 : cs0;
    const __bf16* h_src = (lvl & 1) ? hs0 : hs1;
    const float*  c_src = (lvl & 1) ? cs0 : cs1;

    int i0 = 0, i1 = 0;
    if (!first) { i0 = mapping[rowA]; i1 = mapping[512 + rowA]; }
    const float s0 = (i0 > 0) ? 0.5f : 0.0f;
    const float s1 = (i1 > 0) ? 0.5f : 0.0f;
    const __bf16* h0p = h_src + (size_t)((i0 > 0 ? i0 : 1) - 1) * 512;
    const __bf16* h1p = h_src + (size_t)((i1 > 0 ? i1 : 1) - 1) * 512;

    f32x4 acc[4];
#pragma unroll
    for (int g = 0; g < 4; ++g)
#pragma unroll
      for (int r = 0; r < 4; ++r) acc[g][r] = 0.0f;

    const __bf16* arow = Alvl + (size_t)rowA * 640;

#pragma unroll 4
    for (int kk = 0; kk < 20; ++kk) {          // feature part of K
      const int kof = (kk << 5) + (quad << 3);
      bf16x8 afr = *(const bf16x8*)&arow[kof];
      bf16x8 b0 = *(const bf16x8*)&wbase[(kk * 4 + 0) << 9];
      bf16x8 b1 = *(const bf16x8*)&wbase[(kk * 4 + 1) << 9];
      bf16x8 b2 = *(const bf16x8*)&wbase[(kk * 4 + 2) << 9];
      bf16x8 b3 = *(const bf16x8*)&wbase[(kk * 4 + 3) << 9];
      acc[0] = __builtin_amdgcn_mfma_f32_16x16x32_bf16(afr, b0, acc[0], 0, 0, 0);
      acc[1] = __builtin_amdgcn_mfma_f32_16x16x32_bf16(afr, b1, acc[1], 0, 0, 0);
      acc[2] = __builtin_amdgcn_mfma_f32_16x16x32_bf16(afr, b2, acc[2], 0, 0, 0);
      acc[3] = __builtin_amdgcn_mfma_f32_16x16x32_bf16(afr, b3, acc[3], 0, 0, 0);
    }
#pragma unroll 4
    for (int kk = 20; kk < 36; ++kk) {         // gathered-h part of K
      const int kh = ((kk - 20) << 5) + (quad << 3);
      bf16x8 v0 = *(const bf16x8*)&h0p[kh];
      bf16x8 v1 = *(const bf16x8*)&h1p[kh];
      bf16x8 afr;
#pragma unroll
      for (int e = 0; e < 8; ++e)
        afr[e] = (__bf16)((float)v0[e] * s0 + (float)v1[e] * s1);
      bf16x8 b0 = *(const bf16x8*)&wbase[(kk * 4 + 0) << 9];
      bf16x8 b1 = *(const bf16x8*)&wbase[(kk * 4 + 1) << 9];
      bf16x8 b2 = *(const bf16x8*)&wbase[(kk * 4 + 2) << 9];
      bf16x8 b3 = *(const bf16x8*)&wbase[(kk * 4 + 3) << 9];
      acc[0] = __builtin_amdgcn_mfma_f32_16x16x32_bf16(afr, b0, acc[0], 0, 0, 0);
      acc[1] = __builtin_amdgcn_mfma_f32_16x16x32_bf16(afr, b1, acc[1], 0, 0, 0);
      acc[2] = __builtin_amdgcn_mfma_f32_16x16x32_bf16(afr, b2, acc[2], 0, 0, 0);
      acc[3] = __builtin_amdgcn_mfma_f32_16x16x32_bf16(afr, b3, acc[3], 0, 0, 0);
    }

    // epilogue: i,f,g,o -> c,h
#pragma unroll
    for (int r = 0; r < 4; ++r) {
      const int mrow = mrow0 + r;
      float ci = 0.0f;
      if (!first) {
        int a0 = mapping[mrow], a1 = mapping[512 + mrow];
        if (a0 > 0) ci += c_src[(size_t)(a0 - 1) * 512 + j];
        if (a1 > 0) ci += c_src[(size_t)(a1 - 1) * 512 + j];
        ci *= 0.5f;
      }
      float c = fsig(acc[1][r] + bff) * ci + fsig(acc[0][r] + bi) * ftanh(acc[2][r] + bg);
      float h = fsig(acc[3][r] + bo) * ftanh(c);
      h_dst[(size_t)mrow * 512 + j] = (__bf16)h;
      c_dst[(size_t)mrow * 512 + j] = c;
      if (lvl == 0) h_f32[(size_t)mrow * 512 + j] = h;
    }

    if (lvl > 0) grid.sync();   // next level gathers this level's h/c
  }
}

// ---------------- batchnorm helpers ----------------
__global__ void stats1_kernel(const float* __restrict__ in, int ld, int N,
                              int rows_per_blk, float* __restrict__ partial)
{
  int b = blockIdx.x;
  int r0 = b * rows_per_blk;
  for (int c = threadIdx.x; c < N; c += blockDim.x) {
    float s = 0.0f, sq = 0.0f;
    for (int r = 0; r < rows_per_blk; ++r) {
      float v = in[(size_t)(r0 + r) * ld + c];
      s += v; sq += v * v;
    }
    partial[(size_t)(2 * b) * N + c] = s;
    partial[(size_t)(2 * b + 1) * N + c] = sq;
  }
}

__global__ void stats2_kernel(const float* __restrict__ partial, int nb, int N,
                              float invM, float* __restrict__ stats)
{
  int c = blockIdx.x * blockDim.x + threadIdx.x;
  if (c >= N) return;
  float s = 0.0f, sq = 0.0f;
  for (int b = 0; b < nb; ++b) {
    s  += partial[(size_t)(2 * b) * N + c];
    sq += partial[(size_t)(2 * b + 1) * N + c];
  }
  float mean = s * invM;
  float var  = sq * invM - mean * mean;
  stats[c]     = mean;
  stats[N + c] = rsqrtf(fmaxf(var, 0.0f) + 1e-5f);
}

__global__ void norm_kernel(const float* __restrict__ in, int ldin,
                            const float* __restrict__ stats, int N, int cshift, int gmask,
                            const float* __restrict__ g, const float* __restrict__ b,
                            __bf16* __restrict__ outp, int ldc, int total)
{
  for (int idx = blockIdx.x * blockDim.x + threadIdx.x; idx < total;
       idx += gridDim.x * blockDim.x) {
    int row = idx >> cshift;
    int c = idx & (N - 1);
    float v = (in[(size_t)row * ldin + c] - stats[c]) * stats[N + c];
    int gi = c & gmask;
    v = v * g[gi] + b[gi];
    outp[(size_t)row * ldc + c] = (__bf16)v;
  }
}

// ---------------- output heads ----------------
__global__ void head_kernel(const int* __restrict__ flagp,
                            const __bf16* __restrict__ tmp3,
                            const float* __restrict__ pf,
                            void* __restrict__ outp)
{
  const int bf = *flagp;
  int idx = blockIdx.x * blockDim.x + threadIdx.x;
  if (idx >= 1024) return;
  int which = idx >> 9;
  int n = idx & 511;
  const __bf16* row = tmp3 + (size_t)n * 512 + which * 256;
  const float* ow = pf + PF_OW + which * 256;
  float s = pf[PF_OB + which];
  for (int k = 0; k < 256; ++k) s += (float)row[k] * ow[k];
  float v = fsig(s);
  if (bf) ((__bf16*)outp)[idx] = (__bf16)v;
  else    ((float*)outp)[idx]  = v;
}

// ---------------- launch ----------------
extern "C" void kernel_launch(void* const* d_in, const int* in_sizes, int n_in,
                              void* d_out, int out_size, void* d_ws, size_t ws_size,
                              hipStream_t stream) {
  const void* operators       = d_in[0];
  const void* extra_infos     = d_in[1];
  const void* condition1s     = d_in[2];
  const void* samples         = d_in[4];
  const void* condition_masks = d_in[5];
  const int*  mapping         = (const int*)d_in[6];
  (void)in_sizes; (void)n_in; (void)out_size; (void)ws_size;

  char* ws = (char*)d_ws;
  size_t off = 0;
  auto alloc = [&](size_t bytes) -> void* {
    void* p = ws + off;
    off += (bytes + 255) & ~(size_t)255;
    return p;
  };
  int*    flag     = (int*)   alloc(256);
  __bf16* w1s      = (__bf16*)alloc((size_t)2048 * 544 * 2);
  __bf16* w2s      = (__bf16*)alloc((size_t)2048 * 1152 * 2);
  __bf16* wcat2    = (__bf16*)alloc(512 * 512 * 2);
  __bf16* cond_w_bf   = (__bf16*)alloc(256 * 512 * 2);
  __bf16* sample_w_bf = (__bf16*)alloc(256 * 1000 * 2);
  __bf16* w3cat_bf    = (__bf16*)alloc(512 * 256 * 2);
  float*  mask_f   = (float*) alloc(10240 * 4);
  float*  pf       = (float*) alloc(PF_TOTAL * 4);
  __bf16* samp_bf  = (__bf16*)alloc((size_t)10240 * 1000 * 2);
  __bf16* h_last   = (__bf16*)alloc((size_t)10272 * 512 * 2);
  float*  condtmp  = (float*) alloc((size_t)10240 * 256 * 4);
  __bf16* Astage   = (__bf16*)alloc((size_t)20 * 512 * 640 * 2);
  __bf16* hs0      = (__bf16*)alloc(512 * 512 * 2);
  __bf16* hs1      = (__bf16*)alloc(512 * 512 * 2);
  float*  cs0      = (float*) alloc(512 * 512 * 4);
  float*  cs1      = (float*) alloc(512 * 512 * 4);
  float*  h_f32    = (float*) alloc(512 * 512 * 4);
  __bf16* zbuf     = (__bf16*)alloc(512 * 512 * 2);
  float*  tmp1     = (float*) alloc(512 * 512 * 4);
  __bf16* tmp2     = (__bf16*)alloc(512 * 512 * 2);
  __bf16* tmp3     = (__bf16*)alloc(512 * 512 * 2);
  float*  partial  = (float*) alloc(64 * 2 * 512 * 4);
  float*  statsb   = (float*) alloc(2 * 512 * 4);

  detect_kernel<<<1, 64, 0, stream>>>((const unsigned*)condition_masks, flag);
  prep_kernel<<<4096, 256, 0, stream>>>(flag,
      d_in[7], d_in[8], d_in[9], d_in[10],
      d_in[17], d_in[18], d_in[19], d_in[20],
      d_in[23], d_in[25], d_in[24], d_in[26],
      d_in[13], d_in[14], d_in[11], d_in[12],
      d_in[15], d_in[16], d_in[21], d_in[22],
      d_in[27], d_in[28],
      d_in[29], d_in[30], d_in[31], d_in[32],
      d_in[33], d_in[34], d_in[35], d_in[36],
      condition_masks,
      w1s, w2s, wcat2, cond_w_bf, sample_w_bf, w3cat_bf, mask_f, pf);
  conv_samples_kernel<<<4096, 256, 0, stream>>>(flag, samples, samp_bf);
  featcopy_kernel<<<5120, 256, 0, stream>>>(flag, operators, extra_infos, Astage);
  lstm1_kernel<<<L1_BLOCKS, 1024, 0, stream>>>(flag, condition1s, w1s, pf + PF_BIAS1, h_last);

  // cond = bn1(relu(h_last @ cond_w^T + cond_b)) -> Astage cols 123..378
  gemm_kernel<1,0,0><<<dim3(4,160), 256, 0, stream>>>(h_last, 512, cond_w_bf, 512,
      pf + PF_CONDB, condtmp, nullptr, 256, nullptr, 512);
  stats1_kernel<<<64, 256, 0, stream>>>(condtmp, 256, 256, 160, partial);
  stats2_kernel<<<1, 256, 0, stream>>>(partial, 64, 256, 1.0f / 10240.0f, statsb);
  norm_kernel<<<2560, 256, 0, stream>>>(condtmp, 256, statsb, 256, 8, 255,
      pf + PF_BN1G, pf + PF_BN1B, Astage + 123, 640, 10240 * 256);

  // samp = relu(samples @ sample_w^T + sample_b) * mask -> Astage cols 379..634
  sampgemm_kernel<<<dim3(4,160), 256, 0, stream>>>(flag, samples, samp_bf,
      sample_w_bf, pf + PF_SAMPB, Astage + 379, mask_f);

  // tree: all 20 levels in ONE cooperative kernel (grid.sync between levels)
  {
    const __bf16* tAst = Astage;
    const __bf16* tW   = w2s;
    const float*  tB   = pf + PF_BIAS2;
    const int*    tMap = mapping;
    __bf16* th0 = hs0; __bf16* th1 = hs1;
    float*  tc0 = cs0; float*  tc1 = cs1;
    float*  thf = h_f32;
    void* targs[] = { (void*)&tAst, (void*)&tW, (void*)&tB, (void*)&tMap,
                      (void*)&th0, (void*)&th1, (void*)&tc0, (void*)&tc1,
                      (void*)&thf };
    hipLaunchCooperativeKernel((const void*)tree_kernel,
                               dim3(32, 8), dim3(256, 1, 1), targs, 0, stream);
  }

  // z = bn2(hid)
  stats1_kernel<<<8, 256, 0, stream>>>(h_f32, 512, 512, 64, partial);
  stats2_kernel<<<2, 256, 0, stream>>>(partial, 8, 512, 1.0f / 512.0f, statsb);
  norm_kernel<<<256, 256, 0, stream>>>(h_f32, 512, statsb, 512, 9, 511,
      pf + PF_BN2G, pf + PF_BN2B, zbuf, 512, 512 * 512);

  // [t1|t2] = bn3(relu(z @ [t1_w2;t2_w2]^T + b))
  gemm_kernel<1,0,0><<<dim3(8,8), 256, 0, stream>>>(zbuf, 512, wcat2, 512,
      pf + PF_BCAT2, tmp1, nullptr, 512, nullptr, 512);
  stats1_kernel<<<8, 256, 0, stream>>>(tmp1, 512, 512, 64, partial);
  stats2_kernel<<<2, 256, 0, stream>>>(partial, 8, 512, 1.0f / 512.0f, statsb);
  norm_kernel<<<256, 256, 0, stream>>>(tmp1, 512, statsb, 512, 9, 255,
      pf + PF_BN3G, pf + PF_BN3B, tmp2, 512, 512 * 512);

  // relu(t @ w3^T + b3) for both heads
  gemm_kernel<1,1,0><<<dim3(4,8), 256, 0, stream>>>(tmp2, 512, w3cat_bf, 256,
      pf + PF_B3CAT, nullptr, tmp3, 512, nullptr, 256);
  gemm_kernel<1,1,0><<<dim3(4,8), 256, 0, stream>>>(tmp2 + 256, 512, w3cat_bf + 256 * 256, 256,
      pf + PF_B3CAT + 256, nullptr, tmp3 + 256, 512, nullptr, 256);

  head_kernel<<<4, 256, 0, stream>>>(flag, tmp3, pf, d_out);
}

// Round 7
// 978.156 us; speedup vs baseline: 1.7702x; 1.7702x over previous
//
#include <hip/hip_runtime.h>
#include <hip/hip_bf16.h>

// Representation_32074815766664 — bf16 I/O (runtime-detected f32 fallback),
// bf16 MFMA internally, f32 accumulation/state.
//
// R17 changes vs R16 (1731 us — REGRESSION, reverted):
//  - R16 post-mortem: cooperative tree = 1026 us alone. grid.sync()'s
//    device-scope acquire invalidates per-XCD L2 -> w2s (4.7MB) re-fetched
//    from HBM every level (FETCH 105MB = 20 x 5.2MB), fully-exposed misses
//    at 1 wave/SIMD. Persistent+grid.sync forfeits L2 reuse on MI355X.
//    Tree back to 20 separate launches (L2 stays warm across launches).
//  - New lever: split-K treelvl. 512-thr blocks, same grid (32,8) (same
//    per-XCD L2 footprint as proven R12 form): waves 0-3 compute feature-K
//    (kk 0..19), waves 4-7 gathered-h-K (kk 20..35) of the SAME output
//    tiles; 16KB LDS reduction; waves 0-3 do the unchanged epilogue.
//    2 waves/SIMD instead of 1 -> the two K-phases overlap instead of
//    serializing. Budget: lstm1 265 / tree ~320 / other ~440.
//  - lstm1 FROZEN at R12 form (265 us verified).

typedef __bf16 bf16x8 __attribute__((ext_vector_type(8)));
typedef float f32x4 __attribute__((ext_vector_type(4)));

#define MROWS 10240
#define LDH1  552     // padded LDS stride (2-way bank aliasing only)
#define L1_ROWS 48
#define L1_BLOCKS 214 // ceil(10240/48)

// pf (canonical f32 params) offsets
#define PF_BIAS1   0
#define PF_BIAS2   2048
#define PF_CONDB   4096
#define PF_SAMPB   4352
#define PF_BCAT2   4608
#define PF_B3CAT   5120
#define PF_BN1G    5632
#define PF_BN1B    5888
#define PF_BN2G    6144
#define PF_BN2B    6656
#define PF_BN3G    7168
#define PF_BN3B    7424
#define PF_OW      7680
#define PF_OB      8192
#define PF_TOTAL   8194

// sig(x) = 1/(1+exp(-x)); robust without clamps: exp->inf => rcp->0.
__device__ __forceinline__ float fsig(float x) {
  return __builtin_amdgcn_rcpf(1.0f + __expf(-x));
}
// tanh(x) = 2*sig(2x) - 1; robust at both infinities.
__device__ __forceinline__ float ftanh(float x) {
  return fmaf(2.0f, __builtin_amdgcn_rcpf(1.0f + __expf(-2.0f * x)), -1.0f);
}
__device__ __forceinline__ bf16x8 bzero8() {
  bf16x8 z;
#pragma unroll
  for (int i = 0; i < 8; ++i) z[i] = (__bf16)0.0f;
  return z;
}
__device__ __forceinline__ float ld_in(const void* p, long i, int bf) {
  return bf ? (float)((const __bf16*)p)[i] : ((const float*)p)[i];
}

// ---------------- detect ----------------
__global__ void detect_kernel(const unsigned* __restrict__ masks, int* __restrict__ flag) {
  if (blockIdx.x == 0 && threadIdx.x == 0)
    *flag = (masks[0] == 0x3F803F80u) ? 1 : 0;
}

// ---------------- prep: canonicalize; w1s swizzled, w2s swizzled ----------------
// w1s: elem((cgt*17+kk)*4+g, lane, e) = w_aug1[g*512+cgt*16+(lane&15)][kk*32+(lane>>4)*8+e]
__global__ void prep_kernel(const int* __restrict__ flagp,
    const void* w_ih1, const void* w_hh1, const void* b_ih1, const void* b_hh1,
    const void* w_ih2, const void* w_hh2, const void* b_ih2, const void* b_hh2,
    const void* t1_w2, const void* t2_w2, const void* t1_b2, const void* t2_b2,
    const void* cond_w, const void* cond_b, const void* sample_w, const void* sample_b,
    const void* bn1_g, const void* bn1_b, const void* bn2_g, const void* bn2_b,
    const void* bn3_g, const void* bn3_b,
    const void* t1_w3, const void* t1_b3, const void* t2_w3, const void* t2_b3,
    const void* t1_ow, const void* t1_ob, const void* t2_ow, const void* t2_ob,
    const void* masks,
    __bf16* __restrict__ w1s, __bf16* __restrict__ w2s,
    __bf16* __restrict__ wcat2, __bf16* __restrict__ cond_w_bf,
    __bf16* __restrict__ sample_w_bf, __bf16* __restrict__ w3cat_bf,
    float* __restrict__ mask_f, float* __restrict__ pf)
{
  const int bf = *flagp;
  const int S1 = 2048 * 544;   // w1s swizzled
  const int S2 = 2048 * 1152;  // w2s swizzled
  const int S3 = 512 * 512;
  const int S4 = 256 * 512;
  const int S5 = 256 * 1000;
  const int S6 = 512 * 256;
  const int S7 = 10240;
  const int total = S1 + S2 + S3 + S4 + S5 + S6 + S7 + PF_TOTAL;
  for (int idx = blockIdx.x * blockDim.x + threadIdx.x; idx < total;
       idx += gridDim.x * blockDim.x) {
    int i = idx;
    if (i < S1) {
      int e = i & 7, l = (i >> 3) & 63, g = (i >> 9) & 3;
      int grp = i >> 11;               // cgt*17 + kk
      int kk = grp % 17, cgt = grp / 17;
      int colq = l & 15, quad = l >> 4;
      int row = g * 512 + cgt * 16 + colq;
      int k = kk * 32 + quad * 8 + e;
      float v = (k < 512) ? ld_in(w_hh1, (long)row * 512 + k, bf)
              : (k < 525) ? ld_in(w_ih1, (long)row * 13 + (k - 512), bf) : 0.0f;
      w1s[i] = (__bf16)v;
      continue;
    }
    i -= S1;
    if (i < S2) {
      int e = i & 7, l = (i >> 3) & 63, g = (i >> 9) & 3;
      int grp = i >> 11;               // jt*36 + kk
      int kk = grp % 36, jt = grp / 36;
      int colq = l & 15, quad = l >> 4;
      int row = g * 512 + jt * 16 + colq;
      int k = kk * 32 + quad * 8 + e;
      float v = (k < 635) ? ld_in(w_ih2, (long)row * 635 + k, bf)
              : (k < 640) ? 0.0f : ld_in(w_hh2, (long)row * 512 + (k - 640), bf);
      w2s[i] = (__bf16)v;
      continue;
    }
    i -= S2;
    if (i < S3) {
      int r = i >> 9, k = i & 511;
      wcat2[i] = (__bf16)((r < 256) ? ld_in(t1_w2, r * 512 + k, bf)
                                    : ld_in(t2_w2, (r - 256) * 512 + k, bf));
      continue;
    }
    i -= S3;
    if (i < S4) { cond_w_bf[i] = (__bf16)ld_in(cond_w, i, bf); continue; }
    i -= S4;
    if (i < S5) { sample_w_bf[i] = (__bf16)ld_in(sample_w, i, bf); continue; }
    i -= S5;
    if (i < S6) {
      int r = i >> 8, k = i & 255;
      w3cat_bf[i] = (__bf16)((r < 256) ? ld_in(t1_w3, r * 256 + k, bf)
                                       : ld_in(t2_w3, (r - 256) * 256 + k, bf));
      continue;
    }
    i -= S6;
    if (i < S7) { mask_f[i] = ld_in(masks, i, bf); continue; }
    i -= S7;
    {
      int j = i;
      float v;
      if      (j < 2048) v = ld_in(b_ih1, j, bf) + ld_in(b_hh1, j, bf);
      else if (j < 4096) v = ld_in(b_ih2, j - 2048, bf) + ld_in(b_hh2, j - 2048, bf);
      else if (j < 4352) v = ld_in(cond_b, j - 4096, bf);
      else if (j < 4608) v = ld_in(sample_b, j - 4352, bf);
      else if (j < 5120) { int k = j - 4608; v = (k < 256) ? ld_in(t1_b2, k, bf) : ld_in(t2_b2, k - 256, bf); }
      else if (j < 5632) { int k = j - 5120; v = (k < 256) ? ld_in(t1_b3, k, bf) : ld_in(t2_b3, k - 256, bf); }
      else if (j < 5888) v = ld_in(bn1_g, j - 5632, bf);
      else if (j < 6144) v = ld_in(bn1_b, j - 5888, bf);
      else if (j < 6656) v = ld_in(bn2_g, j - 6144, bf);
      else if (j < 7168) v = ld_in(bn2_b, j - 6656, bf);
      else if (j < 7424) v = ld_in(bn3_g, j - 7168, bf);
      else if (j < 7680) v = ld_in(bn3_b, j - 7424, bf);
      else if (j < 8192) { int k = j - 7680; v = (k < 256) ? ld_in(t1_ow, k, bf) : ld_in(t2_ow, k - 256, bf); }
      else v = (j == 8192) ? ld_in(t1_ob, 0, bf) : ld_in(t2_ob, 0, bf);
      pf[j] = v;
    }
  }
}

// ---------------- samples -> bf16 (only needed on f32 path) ----------------
__global__ void conv_samples_kernel(const int* __restrict__ flagp,
                                    const void* __restrict__ samples,
                                    __bf16* __restrict__ dst)
{
  const int bf = *flagp;
  if (bf) return;   // bf16 input is already the matrix the GEMM reads
  for (long i = blockIdx.x * blockDim.x + threadIdx.x; i < 10240000L;
       i += (long)gridDim.x * blockDim.x)
    dst[i] = (__bf16)ld_in(samples, i, bf);
}

// ---------------- featcopy (Astage stride 640) ----------------
__global__ void featcopy_kernel(const int* __restrict__ flagp,
                                const void* __restrict__ ops,
                                const void* __restrict__ extra,
                                __bf16* __restrict__ Astage)
{
  const int bf = *flagp;
  int idx = blockIdx.x * blockDim.x + threadIdx.x;  // exactly 10240*128
  int m = idx >> 7, c = idx & 127;
  float v; int col;
  if (c < 15)       { v = ld_in(ops, (long)m * 15 + c, bf);            col = c; }
  else if (c < 123) { v = ld_in(extra, (long)m * 108 + (c - 15), bf);  col = c; }
  else              { v = 0.0f;                                        col = 512 + c; } // 635..639
  Astage[(size_t)m * 640 + col] = (__bf16)v;
}

// ---------------- fused 10-step LSTM-1 — R12 form (FROZEN) ----------
// grid 214 x 1024 threads (16 waves). Block owns 48 rows. Wave owns 32 hidden
// cols (cg<2). 4 waves/SIMD. hbuf[2]: augmented h[48][552]. One barrier per
// timestep. kk loop unroll 1, direct hbuf indexing (R11: full unroll spills;
// R13: loop-carried pointers break LDS addrspace inference).
__global__ __launch_bounds__(1024, 4) void lstm1_kernel(
    const int* __restrict__ flagp,
    const void* __restrict__ cond1,     // (10240,10,13)
    const __bf16* __restrict__ w1s,     // swizzled (2048x544)
    const float*  __restrict__ bias,    // (2048)
    __bf16* __restrict__ h_out)         // (10272,512) padded
{
  __shared__ __attribute__((aligned(16))) __bf16 hbuf[2][L1_ROWS * LDH1];
  const int bf   = *flagp;
  const int tid  = threadIdx.x;
  const int wave = tid >> 6;
  const int lane = tid & 63;
  const int colq = lane & 15;
  const int quad = lane >> 4;
  const int r0   = blockIdx.x * L1_ROWS;

  {
    bf16x8 z8 = bzero8();
    for (int i = tid * 8; i < 2 * L1_ROWS * LDH1; i += 1024 * 8)
      *(bf16x8*)&hbuf[0][i] = z8;
  }
  __syncthreads();
  if (tid < L1_ROWS * 8) {           // stage x_0 into buf 0
    int row = tid >> 3, jj = tid & 7;
    int gr = r0 + row;
    if (gr < MROWS) {
      long base = (long)gr * 130;  // t=0
      hbuf[0][row * LDH1 + 512 + jj] = (__bf16)ld_in(cond1, base + jj, bf);
      if (jj < 5) hbuf[0][row * LDH1 + 520 + jj] = (__bf16)ld_in(cond1, base + 8 + jj, bf);
    }
  }
  __syncthreads();

  float c_reg[2][3][4];
#pragma unroll
  for (int a = 0; a < 2; ++a)
#pragma unroll
    for (int b = 0; b < 3; ++b)
#pragma unroll
      for (int r = 0; r < 4; ++r) c_reg[a][b][r] = 0.0f;

  const int jbase = wave * 32;

  // biases hoisted out of the t loop (barrier blocks compiler hoisting)
  float bI[2], bF[2], bG[2], bO[2];
#pragma unroll
  for (int cg = 0; cg < 2; ++cg) {
    const int j = jbase + cg * 16 + colq;
    bI[cg] = bias[j];
    bF[cg] = bias[512 + j];
    bG[cg] = bias[1024 + j];
    bO[cg] = bias[1536 + j];
  }

#pragma unroll 1
  for (int t = 0; t < 10; ++t) {
    const __bf16* hcur = hbuf[t & 1];
    __bf16* hnxt = hbuf[(t + 1) & 1];
#pragma unroll
    for (int cg = 0; cg < 2; ++cg) {
      const int jc = jbase + cg * 16;
      f32x4 acc[3][4];
#pragma unroll
      for (int a = 0; a < 3; ++a)
#pragma unroll
        for (int g = 0; g < 4; ++g)
#pragma unroll
          for (int r = 0; r < 4; ++r) acc[a][g][r] = 0.0f;

      // col-tile index 0..31 = wave*2+cg (same swizzle as 8-wave wave*4+cg)
      const __bf16* wp = w1s + ((size_t)(wave * 2 + cg) * 17 * 4 * 512) + (lane << 3);
#pragma unroll 1
      for (int kk = 0; kk < 17; ++kk) {
        const int kof = (kk << 5) + (quad << 3);
        bf16x8 af[3];
#pragma unroll
        for (int rt = 0; rt < 3; ++rt)
          af[rt] = *(const bf16x8*)&hcur[(rt * 16 + colq) * LDH1 + kof];
        bf16x8 bfr[4];
#pragma unroll
        for (int g = 0; g < 4; ++g)
          bfr[g] = *(const bf16x8*)&wp[(kk * 4 + g) << 9];
#pragma unroll
        for (int g = 0; g < 4; ++g)
#pragma unroll
          for (int rt = 0; rt < 3; ++rt)
            acc[rt][g] = __builtin_amdgcn_mfma_f32_16x16x32_bf16(af[rt], bfr[g], acc[rt][g], 0, 0, 0);
      }
#pragma unroll
      for (int rt = 0; rt < 3; ++rt)
#pragma unroll
        for (int r = 0; r < 4; ++r) {
          float c = fsig(acc[rt][1][r] + bF[cg]) * c_reg[cg][rt][r]
                  + fsig(acc[rt][0][r] + bI[cg]) * ftanh(acc[rt][2][r] + bG[cg]);
          c_reg[cg][rt][r] = c;
          float h = fsig(acc[rt][3][r] + bO[cg]) * ftanh(c);
          hnxt[(rt * 16 + quad * 4 + r) * LDH1 + jc + colq] = (__bf16)h;
        }
    }
    if (t < 9 && tid < L1_ROWS * 8) {   // stage x_{t+1} into next buffer
      int row = tid >> 3, jj = tid & 7;
      int gr = r0 + row;
      if (gr < MROWS) {
        long base = ((long)gr * 10 + (t + 1)) * 13;
        hnxt[row * LDH1 + 512 + jj] = (__bf16)ld_in(cond1, base + jj, bf);
        if (jj < 5) hnxt[row * LDH1 + 520 + jj] = (__bf16)ld_in(cond1, base + 8 + jj, bf);
      }
    }
    __syncthreads();
  }

  // final h is in buffer 0 (t=10 even)
  for (int i = tid; i < L1_ROWS * 64; i += 1024) {
    int row = i >> 6;
    int cb  = (i & 63) << 3;
    *(bf16x8*)&h_out[(size_t)(r0 + row) * 512 + cb] = *(const bf16x8*)&hbuf[0][row * LDH1 + cb];
  }
}

// ---------------- generic MFMA GEMM: out = act(A @ W^T + bias) [* mask] ----------------
template<int ACT, int OUTBF, int MASKED>
__global__ __launch_bounds__(256, 4) void gemm_kernel(
    const __bf16* __restrict__ A, int lda,
    const __bf16* __restrict__ W, int ldw,
    const float* __restrict__ bias,
    float* __restrict__ outf, __bf16* __restrict__ outb, int ldc,
    const float* __restrict__ mask, int K)
{
  const int tid  = threadIdx.x;
  const int wave = tid >> 6;
  const int lane = tid & 63;
  const int colq = lane & 15;
  const int quad = lane >> 4;
  const int m0 = blockIdx.y * 64 + (wave >> 1) * 32;
  const int n0 = blockIdx.x * 64 + (wave & 1) * 32;

  f32x4 acc[2][2];
#pragma unroll
  for (int a = 0; a < 2; ++a)
#pragma unroll
    for (int b = 0; b < 2; ++b)
#pragma unroll
      for (int r = 0; r < 4; ++r) acc[a][b][r] = 0.0f;

  const int nk = (K + 31) >> 5;
  for (int kk = 0; kk < nk; ++kk) {
    const int kof = (kk << 5) + (quad << 3);
    bf16x8 a0, a1, b0, b1;
    if (kof < K) {
      a0 = *(const bf16x8*)&A[(size_t)(m0 + colq) * lda + kof];
      a1 = *(const bf16x8*)&A[(size_t)(m0 + 16 + colq) * lda + kof];
      b0 = *(const bf16x8*)&W[(size_t)(n0 + colq) * ldw + kof];
      b1 = *(const bf16x8*)&W[(size_t)(n0 + 16 + colq) * ldw + kof];
    } else {
      a0 = bzero8(); a1 = a0; b0 = a0; b1 = a0;
    }
    acc[0][0] = __builtin_amdgcn_mfma_f32_16x16x32_bf16(a0, b0, acc[0][0], 0, 0, 0);
    acc[0][1] = __builtin_amdgcn_mfma_f32_16x16x32_bf16(a0, b1, acc[0][1], 0, 0, 0);
    acc[1][0] = __builtin_amdgcn_mfma_f32_16x16x32_bf16(a1, b0, acc[1][0], 0, 0, 0);
    acc[1][1] = __builtin_amdgcn_mfma_f32_16x16x32_bf16(a1, b1, acc[1][1], 0, 0, 0);
  }
#pragma unroll
  for (int ai = 0; ai < 2; ++ai)
#pragma unroll
    for (int bi = 0; bi < 2; ++bi) {
      const int col = n0 + bi * 16 + colq;
      const float bv = bias[col];
#pragma unroll
      for (int r = 0; r < 4; ++r) {
        const int row = m0 + ai * 16 + quad * 4 + r;
        float v = acc[ai][bi][r] + bv;
        if (ACT) v = fmaxf(v, 0.0f);
        if (MASKED) v *= mask[row];
        if (OUTBF) outb[(size_t)row * ldc + col] = (__bf16)v;
        else       outf[(size_t)row * ldc + col] = v;
      }
    }
}

// ---------------- samples GEMM: A chosen by dtype flag ----------------
// out = relu(A @ W^T + b) * mask -> Astage cols 379..634 (ldc 640), K=1000.
__global__ __launch_bounds__(256, 4) void sampgemm_kernel(
    const int* __restrict__ flagp,
    const void* __restrict__ samples_raw,   // bf16 path reads this directly
    const __bf16* __restrict__ samp_bf,     // f32 path: converted copy
    const __bf16* __restrict__ W,
    const float* __restrict__ bias,
    __bf16* __restrict__ outb,
    const float* __restrict__ mask)
{
  const __bf16* A = (*flagp) ? (const __bf16*)samples_raw : samp_bf;
  const int tid  = threadIdx.x;
  const int wave = tid >> 6;
  const int lane = tid & 63;
  const int colq = lane & 15;
  const int quad = lane >> 4;
  const int m0 = blockIdx.y * 64 + (wave >> 1) * 32;
  const int n0 = blockIdx.x * 64 + (wave & 1) * 32;
  const int K = 1000;

  f32x4 acc[2][2];
#pragma unroll
  for (int a = 0; a < 2; ++a)
#pragma unroll
    for (int b = 0; b < 2; ++b)
#pragma unroll
      for (int r = 0; r < 4; ++r) acc[a][b][r] = 0.0f;

  for (int kk = 0; kk < 32; ++kk) {
    const int kof = (kk << 5) + (quad << 3);
    bf16x8 a0, a1, b0, b1;
    if (kof < K) {
      a0 = *(const bf16x8*)&A[(size_t)(m0 + colq) * 1000 + kof];
      a1 = *(const bf16x8*)&A[(size_t)(m0 + 16 + colq) * 1000 + kof];
      b0 = *(const bf16x8*)&W[(size_t)(n0 + colq) * 1000 + kof];
      b1 = *(const bf16x8*)&W[(size_t)(n0 + 16 + colq) * 1000 + kof];
    } else {
      a0 = bzero8(); a1 = a0; b0 = a0; b1 = a0;
    }
    acc[0][0] = __builtin_amdgcn_mfma_f32_16x16x32_bf16(a0, b0, acc[0][0], 0, 0, 0);
    acc[0][1] = __builtin_amdgcn_mfma_f32_16x16x32_bf16(a0, b1, acc[0][1], 0, 0, 0);
    acc[1][0] = __builtin_amdgcn_mfma_f32_16x16x32_bf16(a1, b0, acc[1][0], 0, 0, 0);
    acc[1][1] = __builtin_amdgcn_mfma_f32_16x16x32_bf16(a1, b1, acc[1][1], 0, 0, 0);
  }
#pragma unroll
  for (int ai = 0; ai < 2; ++ai)
#pragma unroll
    for (int bi = 0; bi < 2; ++bi) {
      const int col = n0 + bi * 16 + colq;
      const float bv = bias[col];
#pragma unroll
      for (int r = 0; r < 4; ++r) {
        const int row = m0 + ai * 16 + quad * 4 + r;
        float v = fmaxf(acc[ai][bi][r] + bv, 0.0f) * mask[row];
        outb[(size_t)row * 640 + col] = (__bf16)v;
      }
    }
}

// ---------------- fused tree level: split-K gather + GEMM(K=1152) + cell ----------
// R17: 512 thr (8 waves), same grid (32,8) as R12-proven form. Waves 0-3:
// feature-K (kk 0..19). Waves 4-7: gathered-h-K (kk 20..35) of the SAME
// output tiles. 16KB LDS reduction; waves 0-3 run the unchanged epilogue.
// 2 waves/SIMD (was 1): the two K-phases overlap. Loads direct-indexed.
__global__ __launch_bounds__(512, 2) void treelvl_kernel(
    const __bf16* __restrict__ Alvl,    // (512,640) level features
    const __bf16* __restrict__ w2s,     // swizzled (2048x1152)
    const float* __restrict__ bias,     // 2048
    const int* __restrict__ mapping,    // level's (2,512)
    const __bf16* __restrict__ h_src, const float* __restrict__ c_src,
    __bf16* __restrict__ h_dst, float* __restrict__ c_dst,
    float* __restrict__ h_f32, int first, int last)
{
  __shared__ __attribute__((aligned(16))) float red[4 * 64 * 16];  // 16 KB
  const int tid  = threadIdx.x;
  const int wave = tid >> 6;          // 0..7
  const int lane = tid & 63;
  const int colq = lane & 15;
  const int quad = lane >> 4;
  const int wv   = wave & 3;          // row sub-tile 0..3
  const int half = wave >> 3 ? 0 : (wave >> 2);  // 0 for waves 0-3, 1 for 4-7
  const int jt = blockIdx.x;
  const int mt = blockIdx.y;
  const int rowA = mt * 64 + wv * 16 + colq;

  const __bf16* wbase = w2s + (size_t)jt * 36 * 4 * 512 + (lane << 3);

  f32x4 acc[4];
#pragma unroll
  for (int g = 0; g < 4; ++g)
#pragma unroll
    for (int r = 0; r < 4; ++r) acc[g][r] = 0.0f;

  if (half == 0) {
    // ---- feature part of K: kk 0..19 ----
    const __bf16* arow = Alvl + (size_t)rowA * 640;
#pragma unroll 4
    for (int kk = 0; kk < 20; ++kk) {
      const int kof = (kk << 5) + (quad << 3);
      bf16x8 afr = *(const bf16x8*)&arow[kof];
      bf16x8 b0 = *(const bf16x8*)&wbase[(kk * 4 + 0) << 9];
      bf16x8 b1 = *(const bf16x8*)&wbase[(kk * 4 + 1) << 9];
      bf16x8 b2 = *(const bf16x8*)&wbase[(kk * 4 + 2) << 9];
      bf16x8 b3 = *(const bf16x8*)&wbase[(kk * 4 + 3) << 9];
      acc[0] = __builtin_amdgcn_mfma_f32_16x16x32_bf16(afr, b0, acc[0], 0, 0, 0);
      acc[1] = __builtin_amdgcn_mfma_f32_16x16x32_bf16(afr, b1, acc[1], 0, 0, 0);
      acc[2] = __builtin_amdgcn_mfma_f32_16x16x32_bf16(afr, b2, acc[2], 0, 0, 0);
      acc[3] = __builtin_amdgcn_mfma_f32_16x16x32_bf16(afr, b3, acc[3], 0, 0, 0);
    }
  } else {
    // ---- gathered-h part of K: kk 20..35 ----
    int i0 = 0, i1 = 0;
    if (!first) { i0 = mapping[rowA]; i1 = mapping[512 + rowA]; }
    const float s0 = (i0 > 0) ? 0.5f : 0.0f;
    const float s1 = (i1 > 0) ? 0.5f : 0.0f;
    const __bf16* h0p = h_src + (size_t)((i0 > 0 ? i0 : 1) - 1) * 512;
    const __bf16* h1p = h_src + (size_t)((i1 > 0 ? i1 : 1) - 1) * 512;
#pragma unroll 4
    for (int kk = 20; kk < 36; ++kk) {
      const int kh = ((kk - 20) << 5) + (quad << 3);
      bf16x8 v0 = *(const bf16x8*)&h0p[kh];
      bf16x8 v1 = *(const bf16x8*)&h1p[kh];
      bf16x8 afr;
#pragma unroll
      for (int e = 0; e < 8; ++e)
        afr[e] = (__bf16)((float)v0[e] * s0 + (float)v1[e] * s1);
      bf16x8 b0 = *(const bf16x8*)&wbase[(kk * 4 + 0) << 9];
      bf16x8 b1 = *(const bf16x8*)&wbase[(kk * 4 + 1) << 9];
      bf16x8 b2 = *(const bf16x8*)&wbase[(kk * 4 + 2) << 9];
      bf16x8 b3 = *(const bf16x8*)&wbase[(kk * 4 + 3) << 9];
      acc[0] = __builtin_amdgcn_mfma_f32_16x16x32_bf16(afr, b0, acc[0], 0, 0, 0);
      acc[1] = __builtin_amdgcn_mfma_f32_16x16x32_bf16(afr, b1, acc[1], 0, 0, 0);
      acc[2] = __builtin_amdgcn_mfma_f32_16x16x32_bf16(afr, b2, acc[2], 0, 0, 0);
      acc[3] = __builtin_amdgcn_mfma_f32_16x16x32_bf16(afr, b3, acc[3], 0, 0, 0);
    }
    // stash partials for waves 0-3
    float* rp = &red[(wv * 64 + lane) * 16];
#pragma unroll
    for (int g = 0; g < 4; ++g)
      *(f32x4*)&rp[g * 4] = acc[g];
  }
  __syncthreads();
  if (half == 1) return;

  // waves 0-3: combine partials, then the unchanged epilogue
  {
    const float* rp = &red[(wv * 64 + lane) * 16];
#pragma unroll
    for (int g = 0; g < 4; ++g) {
      f32x4 p = *(const f32x4*)&rp[g * 4];
#pragma unroll
      for (int r = 0; r < 4; ++r) acc[g][r] += p[r];
    }
  }

  // epilogue: i,f,g,o -> c,h
  const int j = jt * 16 + colq;
  const float bi  = bias[j];
  const float bff = bias[512 + j];
  const float bg  = bias[1024 + j];
  const float bo  = bias[1536 + j];
#pragma unroll
  for (int r = 0; r < 4; ++r) {
    const int mrow = mt * 64 + wv * 16 + quad * 4 + r;
    float ci = 0.0f;
    if (!first) {
      int a0 = mapping[mrow], a1 = mapping[512 + mrow];
      if (a0 > 0) ci += c_src[(size_t)(a0 - 1) * 512 + j];
      if (a1 > 0) ci += c_src[(size_t)(a1 - 1) * 512 + j];
      ci *= 0.5f;
    }
    float c = fsig(acc[1][r] + bff) * ci + fsig(acc[0][r] + bi) * ftanh(acc[2][r] + bg);
    float h = fsig(acc[3][r] + bo) * ftanh(c);
    h_dst[(size_t)mrow * 512 + j] = (__bf16)h;
    c_dst[(size_t)mrow * 512 + j] = c;
    if (last) h_f32[(size_t)mrow * 512 + j] = h;
  }
}

// ---------------- batchnorm helpers ----------------
__global__ void stats1_kernel(const float* __restrict__ in, int ld, int N,
                              int rows_per_blk, float* __restrict__ partial)
{
  int b = blockIdx.x;
  int r0 = b * rows_per_blk;
  for (int c = threadIdx.x; c < N; c += blockDim.x) {
    float s = 0.0f, sq = 0.0f;
    for (int r = 0; r < rows_per_blk; ++r) {
      float v = in[(size_t)(r0 + r) * ld + c];
      s += v; sq += v * v;
    }
    partial[(size_t)(2 * b) * N + c] = s;
    partial[(size_t)(2 * b + 1) * N + c] = sq;
  }
}

__global__ void stats2_kernel(const float* __restrict__ partial, int nb, int N,
                              float invM, float* __restrict__ stats)
{
  int c = blockIdx.x * blockDim.x + threadIdx.x;
  if (c >= N) return;
  float s = 0.0f, sq = 0.0f;
  for (int b = 0; b < nb; ++b) {
    s  += partial[(size_t)(2 * b) * N + c];
    sq += partial[(size_t)(2 * b + 1) * N + c];
  }
  float mean = s * invM;
  float var  = sq * invM - mean * mean;
  stats[c]     = mean;
  stats[N + c] = rsqrtf(fmaxf(var, 0.0f) + 1e-5f);
}

__global__ void norm_kernel(const float* __restrict__ in, int ldin,
                            const float* __restrict__ stats, int N, int cshift, int gmask,
                            const float* __restrict__ g, const float* __restrict__ b,
                            __bf16* __restrict__ outp, int ldc, int total)
{
  for (int idx = blockIdx.x * blockDim.x + threadIdx.x; idx < total;
       idx += gridDim.x * blockDim.x) {
    int row = idx >> cshift;
    int c = idx & (N - 1);
    float v = (in[(size_t)row * ldin + c] - stats[c]) * stats[N + c];
    int gi = c & gmask;
    v = v * g[gi] + b[gi];
    outp[(size_t)row * ldc + c] = (__bf16)v;
  }
}

// ---------------- output heads ----------------
__global__ void head_kernel(const int* __restrict__ flagp,
                            const __bf16* __restrict__ tmp3,
                            const float* __restrict__ pf,
                            void* __restrict__ outp)
{
  const int bf = *flagp;
  int idx = blockIdx.x * blockDim.x + threadIdx.x;
  if (idx >= 1024) return;
  int which = idx >> 9;
  int n = idx & 511;
  const __bf16* row = tmp3 + (size_t)n * 512 + which * 256;
  const float* ow = pf + PF_OW + which * 256;
  float s = pf[PF_OB + which];
  for (int k = 0; k < 256; ++k) s += (float)row[k] * ow[k];
  float v = fsig(s);
  if (bf) ((__bf16*)outp)[idx] = (__bf16)v;
  else    ((float*)outp)[idx]  = v;
}

// ---------------- launch ----------------
extern "C" void kernel_launch(void* const* d_in, const int* in_sizes, int n_in,
                              void* d_out, int out_size, void* d_ws, size_t ws_size,
                              hipStream_t stream) {
  const void* operators       = d_in[0];
  const void* extra_infos     = d_in[1];
  const void* condition1s     = d_in[2];
  const void* samples         = d_in[4];
  const void* condition_masks = d_in[5];
  const int*  mapping         = (const int*)d_in[6];
  (void)in_sizes; (void)n_in; (void)out_size; (void)ws_size;

  char* ws = (char*)d_ws;
  size_t off = 0;
  auto alloc = [&](size_t bytes) -> void* {
    void* p = ws + off;
    off += (bytes + 255) & ~(size_t)255;
    return p;
  };
  int*    flag     = (int*)   alloc(256);
  __bf16* w1s      = (__bf16*)alloc((size_t)2048 * 544 * 2);
  __bf16* w2s      = (__bf16*)alloc((size_t)2048 * 1152 * 2);
  __bf16* wcat2    = (__bf16*)alloc(512 * 512 * 2);
  __bf16* cond_w_bf   = (__bf16*)alloc(256 * 512 * 2);
  __bf16* sample_w_bf = (__bf16*)alloc(256 * 1000 * 2);
  __bf16* w3cat_bf    = (__bf16*)alloc(512 * 256 * 2);
  float*  mask_f   = (float*) alloc(10240 * 4);
  float*  pf       = (float*) alloc(PF_TOTAL * 4);
  __bf16* samp_bf  = (__bf16*)alloc((size_t)10240 * 1000 * 2);
  __bf16* h_last   = (__bf16*)alloc((size_t)10272 * 512 * 2);
  float*  condtmp  = (float*) alloc((size_t)10240 * 256 * 4);
  __bf16* Astage   = (__bf16*)alloc((size_t)20 * 512 * 640 * 2);
  __bf16* hs0      = (__bf16*)alloc(512 * 512 * 2);
  __bf16* hs1      = (__bf16*)alloc(512 * 512 * 2);
  float*  cs0      = (float*) alloc(512 * 512 * 4);
  float*  cs1      = (float*) alloc(512 * 512 * 4);
  float*  h_f32    = (float*) alloc(512 * 512 * 4);
  __bf16* zbuf     = (__bf16*)alloc(512 * 512 * 2);
  float*  tmp1     = (float*) alloc(512 * 512 * 4);
  __bf16* tmp2     = (__bf16*)alloc(512 * 512 * 2);
  __bf16* tmp3     = (__bf16*)alloc(512 * 512 * 2);
  float*  partial  = (float*) alloc(64 * 2 * 512 * 4);
  float*  statsb   = (float*) alloc(2 * 512 * 4);

  detect_kernel<<<1, 64, 0, stream>>>((const unsigned*)condition_masks, flag);
  prep_kernel<<<4096, 256, 0, stream>>>(flag,
      d_in[7], d_in[8], d_in[9], d_in[10],
      d_in[17], d_in[18], d_in[19], d_in[20],
      d_in[23], d_in[25], d_in[24], d_in[26],
      d_in[13], d_in[14], d_in[11], d_in[12],
      d_in[15], d_in[16], d_in[21], d_in[22],
      d_in[27], d_in[28],
      d_in[29], d_in[30], d_in[31], d_in[32],
      d_in[33], d_in[34], d_in[35], d_in[36],
      condition_masks,
      w1s, w2s, wcat2, cond_w_bf, sample_w_bf, w3cat_bf, mask_f, pf);
  conv_samples_kernel<<<4096, 256, 0, stream>>>(flag, samples, samp_bf);
  featcopy_kernel<<<5120, 256, 0, stream>>>(flag, operators, extra_infos, Astage);
  lstm1_kernel<<<L1_BLOCKS, 1024, 0, stream>>>(flag, condition1s, w1s, pf + PF_BIAS1, h_last);

  // cond = bn1(relu(h_last @ cond_w^T + cond_b)) -> Astage cols 123..378
  gemm_kernel<1,0,0><<<dim3(4,160), 256, 0, stream>>>(h_last, 512, cond_w_bf, 512,
      pf + PF_CONDB, condtmp, nullptr, 256, nullptr, 512);
  stats1_kernel<<<64, 256, 0, stream>>>(condtmp, 256, 256, 160, partial);
  stats2_kernel<<<1, 256, 0, stream>>>(partial, 64, 256, 1.0f / 10240.0f, statsb);
  norm_kernel<<<2560, 256, 0, stream>>>(condtmp, 256, statsb, 256, 8, 255,
      pf + PF_BN1G, pf + PF_BN1B, Astage + 123, 640, 10240 * 256);

  // samp = relu(samples @ sample_w^T + sample_b) * mask -> Astage cols 379..634
  sampgemm_kernel<<<dim3(4,160), 256, 0, stream>>>(flag, samples, samp_bf,
      sample_w_bf, pf + PF_SAMPB, Astage + 379, mask_f);

  // tree: lvl 19 (zero state) down to 0; ping-pong state by level parity
  for (int lvl = 19; lvl >= 0; --lvl) {
    __bf16* hd = (lvl & 1) ? hs1 : hs0;
    float*  cd = (lvl & 1) ? cs1 : cs0;
    const __bf16* hsrc = (lvl & 1) ? hs0 : hs1;
    const float*  csrc = (lvl & 1) ? cs0 : cs1;
    treelvl_kernel<<<dim3(32,8), 512, 0, stream>>>(
        Astage + (size_t)lvl * 512 * 640, w2s, pf + PF_BIAS2,
        mapping + lvl * 1024, hsrc, csrc, hd, cd, h_f32,
        (lvl == 19) ? 1 : 0, (lvl == 0) ? 1 : 0);
  }

  // z = bn2(hid)
  stats1_kernel<<<8, 256, 0, stream>>>(h_f32, 512, 512, 64, partial);
  stats2_kernel<<<2, 256, 0, stream>>>(partial, 8, 512, 1.0f / 512.0f, statsb);
  norm_kernel<<<256, 256, 0, stream>>>(h_f32, 512, statsb, 512, 9, 511,
      pf + PF_BN2G, pf + PF_BN2B, zbuf, 512, 512 * 512);

  // [t1|t2] = bn3(relu(z @ [t1_w2;t2_w2]^T + b))
  gemm_kernel<1,0,0><<<dim3(8,8), 256, 0, stream>>>(zbuf, 512, wcat2, 512,
      pf + PF_BCAT2, tmp1, nullptr, 512, nullptr, 512);
  stats1_kernel<<<8, 256, 0, stream>>>(tmp1, 512, 512, 64, partial);
  stats2_kernel<<<2, 256, 0, stream>>>(partial, 8, 512, 1.0f / 512.0f, statsb);
  norm_kernel<<<256, 256, 0, stream>>>(tmp1, 512, statsb, 512, 9, 255,
      pf + PF_BN3G, pf + PF_BN3B, tmp2, 512, 512 * 512);

  // relu(t @ w3^T + b3) for both heads
  gemm_kernel<1,1,0><<<dim3(4,8), 256, 0, stream>>>(tmp2, 512, w3cat_bf, 256,
      pf + PF_B3CAT, nullptr, tmp3, 512, nullptr, 256);
  gemm_kernel<1,1,0><<<dim3(4,8), 256, 0, stream>>>(tmp2 + 256, 512, w3cat_bf + 256 * 256, 256,
      pf + PF_B3CAT + 256, nullptr, tmp3 + 256, 512, nullptr, 256);

  head_kernel<<<4, 256, 0, stream>>>(flag, tmp3, pf, d_out);
}

// Round 8
// 955.303 us; speedup vs baseline: 1.8125x; 1.0239x over previous
//
#include <hip/hip_runtime.h>
#include <hip/hip_bf16.h>

// Representation_32074815766664 — bf16 I/O (runtime-detected f32 fallback),
// bf16 MFMA internally, f32 accumulation/state.
//
// R18 changes vs R17 (978 us — WIN, best so far):
//  - R17 post-mortem: split-K tree paid (~-65 us). Critical path is now the
//    gathered-h half (16 K-iters at 2 waves/SIMD). Deepen the same lever:
//    quarter-K. 1024-thr blocks, 16 waves = 4 K-quarters x 4 row-subtiles
//    (feature kk 0-9 / 10-19, h kk 20-27 / 28-35). Traffic invariant (each
//    wave loads a disjoint kk slice of W; per-block L2 footprint unchanged
//    — the R15 mistake was moving traffic, this doesn't). 48KB LDS, 3
//    reduction slots, scalar-f32 conflict-free layout. 4 waves/SIMD.
//  - head_kernel: was a 256-iter serial dot per thread (uncoalesced,
//    ~20-30 us for 0.5 MFLOP). Now one wave per output: 4 coalesced
//    loads/lane + shfl_down tree.
//  - lstm1 FROZEN at R12 form (267 us verified).

typedef __bf16 bf16x8 __attribute__((ext_vector_type(8)));
typedef float f32x4 __attribute__((ext_vector_type(4)));

#define MROWS 10240
#define LDH1  552     // padded LDS stride (2-way bank aliasing only)
#define L1_ROWS 48
#define L1_BLOCKS 214 // ceil(10240/48)

// pf (canonical f32 params) offsets
#define PF_BIAS1   0
#define PF_BIAS2   2048
#define PF_CONDB   4096
#define PF_SAMPB   4352
#define PF_BCAT2   4608
#define PF_B3CAT   5120
#define PF_BN1G    5632
#define PF_BN1B    5888
#define PF_BN2G    6144
#define PF_BN2B    6656
#define PF_BN3G    7168
#define PF_BN3B    7424
#define PF_OW      7680
#define PF_OB      8192
#define PF_TOTAL   8194

// sig(x) = 1/(1+exp(-x)); robust without clamps: exp->inf => rcp->0.
__device__ __forceinline__ float fsig(float x) {
  return __builtin_amdgcn_rcpf(1.0f + __expf(-x));
}
// tanh(x) = 2*sig(2x) - 1; robust at both infinities.
__device__ __forceinline__ float ftanh(float x) {
  return fmaf(2.0f, __builtin_amdgcn_rcpf(1.0f + __expf(-2.0f * x)), -1.0f);
}
__device__ __forceinline__ bf16x8 bzero8() {
  bf16x8 z;
#pragma unroll
  for (int i = 0; i < 8; ++i) z[i] = (__bf16)0.0f;
  return z;
}
__device__ __forceinline__ float ld_in(const void* p, long i, int bf) {
  return bf ? (float)((const __bf16*)p)[i] : ((const float*)p)[i];
}

// ---------------- detect ----------------
__global__ void detect_kernel(const unsigned* __restrict__ masks, int* __restrict__ flag) {
  if (blockIdx.x == 0 && threadIdx.x == 0)
    *flag = (masks[0] == 0x3F803F80u) ? 1 : 0;
}

// ---------------- prep: canonicalize; w1s swizzled, w2s swizzled ----------------
// w1s: elem((cgt*17+kk)*4+g, lane, e) = w_aug1[g*512+cgt*16+(lane&15)][kk*32+(lane>>4)*8+e]
__global__ void prep_kernel(const int* __restrict__ flagp,
    const void* w_ih1, const void* w_hh1, const void* b_ih1, const void* b_hh1,
    const void* w_ih2, const void* w_hh2, const void* b_ih2, const void* b_hh2,
    const void* t1_w2, const void* t2_w2, const void* t1_b2, const void* t2_b2,
    const void* cond_w, const void* cond_b, const void* sample_w, const void* sample_b,
    const void* bn1_g, const void* bn1_b, const void* bn2_g, const void* bn2_b,
    const void* bn3_g, const void* bn3_b,
    const void* t1_w3, const void* t1_b3, const void* t2_w3, const void* t2_b3,
    const void* t1_ow, const void* t1_ob, const void* t2_ow, const void* t2_ob,
    const void* masks,
    __bf16* __restrict__ w1s, __bf16* __restrict__ w2s,
    __bf16* __restrict__ wcat2, __bf16* __restrict__ cond_w_bf,
    __bf16* __restrict__ sample_w_bf, __bf16* __restrict__ w3cat_bf,
    float* __restrict__ mask_f, float* __restrict__ pf)
{
  const int bf = *flagp;
  const int S1 = 2048 * 544;   // w1s swizzled
  const int S2 = 2048 * 1152;  // w2s swizzled
  const int S3 = 512 * 512;
  const int S4 = 256 * 512;
  const int S5 = 256 * 1000;
  const int S6 = 512 * 256;
  const int S7 = 10240;
  const int total = S1 + S2 + S3 + S4 + S5 + S6 + S7 + PF_TOTAL;
  for (int idx = blockIdx.x * blockDim.x + threadIdx.x; idx < total;
       idx += gridDim.x * blockDim.x) {
    int i = idx;
    if (i < S1) {
      int e = i & 7, l = (i >> 3) & 63, g = (i >> 9) & 3;
      int grp = i >> 11;               // cgt*17 + kk
      int kk = grp % 17, cgt = grp / 17;
      int colq = l & 15, quad = l >> 4;
      int row = g * 512 + cgt * 16 + colq;
      int k = kk * 32 + quad * 8 + e;
      float v = (k < 512) ? ld_in(w_hh1, (long)row * 512 + k, bf)
              : (k < 525) ? ld_in(w_ih1, (long)row * 13 + (k - 512), bf) : 0.0f;
      w1s[i] = (__bf16)v;
      continue;
    }
    i -= S1;
    if (i < S2) {
      int e = i & 7, l = (i >> 3) & 63, g = (i >> 9) & 3;
      int grp = i >> 11;               // jt*36 + kk
      int kk = grp % 36, jt = grp / 36;
      int colq = l & 15, quad = l >> 4;
      int row = g * 512 + jt * 16 + colq;
      int k = kk * 32 + quad * 8 + e;
      float v = (k < 635) ? ld_in(w_ih2, (long)row * 635 + k, bf)
              : (k < 640) ? 0.0f : ld_in(w_hh2, (long)row * 512 + (k - 640), bf);
      w2s[i] = (__bf16)v;
      continue;
    }
    i -= S2;
    if (i < S3) {
      int r = i >> 9, k = i & 511;
      wcat2[i] = (__bf16)((r < 256) ? ld_in(t1_w2, r * 512 + k, bf)
                                    : ld_in(t2_w2, (r - 256) * 512 + k, bf));
      continue;
    }
    i -= S3;
    if (i < S4) { cond_w_bf[i] = (__bf16)ld_in(cond_w, i, bf); continue; }
    i -= S4;
    if (i < S5) { sample_w_bf[i] = (__bf16)ld_in(sample_w, i, bf); continue; }
    i -= S5;
    if (i < S6) {
      int r = i >> 8, k = i & 255;
      w3cat_bf[i] = (__bf16)((r < 256) ? ld_in(t1_w3, r * 256 + k, bf)
                                       : ld_in(t2_w3, (r - 256) * 256 + k, bf));
      continue;
    }
    i -= S6;
    if (i < S7) { mask_f[i] = ld_in(masks, i, bf); continue; }
    i -= S7;
    {
      int j = i;
      float v;
      if      (j < 2048) v = ld_in(b_ih1, j, bf) + ld_in(b_hh1, j, bf);
      else if (j < 4096) v = ld_in(b_ih2, j - 2048, bf) + ld_in(b_hh2, j - 2048, bf);
      else if (j < 4352) v = ld_in(cond_b, j - 4096, bf);
      else if (j < 4608) v = ld_in(sample_b, j - 4352, bf);
      else if (j < 5120) { int k = j - 4608; v = (k < 256) ? ld_in(t1_b2, k, bf) : ld_in(t2_b2, k - 256, bf); }
      else if (j < 5632) { int k = j - 5120; v = (k < 256) ? ld_in(t1_b3, k, bf) : ld_in(t2_b3, k - 256, bf); }
      else if (j < 5888) v = ld_in(bn1_g, j - 5632, bf);
      else if (j < 6144) v = ld_in(bn1_b, j - 5888, bf);
      else if (j < 6656) v = ld_in(bn2_g, j - 6144, bf);
      else if (j < 7168) v = ld_in(bn2_b, j - 6656, bf);
      else if (j < 7424) v = ld_in(bn3_g, j - 7168, bf);
      else if (j < 7680) v = ld_in(bn3_b, j - 7424, bf);
      else if (j < 8192) { int k = j - 7680; v = (k < 256) ? ld_in(t1_ow, k, bf) : ld_in(t2_ow, k - 256, bf); }
      else v = (j == 8192) ? ld_in(t1_ob, 0, bf) : ld_in(t2_ob, 0, bf);
      pf[j] = v;
    }
  }
}

// ---------------- samples -> bf16 (only needed on f32 path) ----------------
__global__ void conv_samples_kernel(const int* __restrict__ flagp,
                                    const void* __restrict__ samples,
                                    __bf16* __restrict__ dst)
{
  const int bf = *flagp;
  if (bf) return;   // bf16 input is already the matrix the GEMM reads
  for (long i = blockIdx.x * blockDim.x + threadIdx.x; i < 10240000L;
       i += (long)gridDim.x * blockDim.x)
    dst[i] = (__bf16)ld_in(samples, i, bf);
}

// ---------------- featcopy (Astage stride 640) ----------------
__global__ void featcopy_kernel(const int* __restrict__ flagp,
                                const void* __restrict__ ops,
                                const void* __restrict__ extra,
                                __bf16* __restrict__ Astage)
{
  const int bf = *flagp;
  int idx = blockIdx.x * blockDim.x + threadIdx.x;  // exactly 10240*128
  int m = idx >> 7, c = idx & 127;
  float v; int col;
  if (c < 15)       { v = ld_in(ops, (long)m * 15 + c, bf);            col = c; }
  else if (c < 123) { v = ld_in(extra, (long)m * 108 + (c - 15), bf);  col = c; }
  else              { v = 0.0f;                                        col = 512 + c; } // 635..639
  Astage[(size_t)m * 640 + col] = (__bf16)v;
}

// ---------------- fused 10-step LSTM-1 — R12 form (FROZEN) ----------
// grid 214 x 1024 threads (16 waves). Block owns 48 rows. Wave owns 32 hidden
// cols (cg<2). 4 waves/SIMD. hbuf[2]: augmented h[48][552]. One barrier per
// timestep. kk loop unroll 1, direct hbuf indexing (R11: full unroll spills;
// R13: loop-carried pointers break LDS addrspace inference).
__global__ __launch_bounds__(1024, 4) void lstm1_kernel(
    const int* __restrict__ flagp,
    const void* __restrict__ cond1,     // (10240,10,13)
    const __bf16* __restrict__ w1s,     // swizzled (2048x544)
    const float*  __restrict__ bias,    // (2048)
    __bf16* __restrict__ h_out)         // (10272,512) padded
{
  __shared__ __attribute__((aligned(16))) __bf16 hbuf[2][L1_ROWS * LDH1];
  const int bf   = *flagp;
  const int tid  = threadIdx.x;
  const int wave = tid >> 6;
  const int lane = tid & 63;
  const int colq = lane & 15;
  const int quad = lane >> 4;
  const int r0   = blockIdx.x * L1_ROWS;

  {
    bf16x8 z8 = bzero8();
    for (int i = tid * 8; i < 2 * L1_ROWS * LDH1; i += 1024 * 8)
      *(bf16x8*)&hbuf[0][i] = z8;
  }
  __syncthreads();
  if (tid < L1_ROWS * 8) {           // stage x_0 into buf 0
    int row = tid >> 3, jj = tid & 7;
    int gr = r0 + row;
    if (gr < MROWS) {
      long base = (long)gr * 130;  // t=0
      hbuf[0][row * LDH1 + 512 + jj] = (__bf16)ld_in(cond1, base + jj, bf);
      if (jj < 5) hbuf[0][row * LDH1 + 520 + jj] = (__bf16)ld_in(cond1, base + 8 + jj, bf);
    }
  }
  __syncthreads();

  float c_reg[2][3][4];
#pragma unroll
  for (int a = 0; a < 2; ++a)
#pragma unroll
    for (int b = 0; b < 3; ++b)
#pragma unroll
      for (int r = 0; r < 4; ++r) c_reg[a][b][r] = 0.0f;

  const int jbase = wave * 32;

  // biases hoisted out of the t loop (barrier blocks compiler hoisting)
  float bI[2], bF[2], bG[2], bO[2];
#pragma unroll
  for (int cg = 0; cg < 2; ++cg) {
    const int j = jbase + cg * 16 + colq;
    bI[cg] = bias[j];
    bF[cg] = bias[512 + j];
    bG[cg] = bias[1024 + j];
    bO[cg] = bias[1536 + j];
  }

#pragma unroll 1
  for (int t = 0; t < 10; ++t) {
    const __bf16* hcur = hbuf[t & 1];
    __bf16* hnxt = hbuf[(t + 1) & 1];
#pragma unroll
    for (int cg = 0; cg < 2; ++cg) {
      const int jc = jbase + cg * 16;
      f32x4 acc[3][4];
#pragma unroll
      for (int a = 0; a < 3; ++a)
#pragma unroll
        for (int g = 0; g < 4; ++g)
#pragma unroll
          for (int r = 0; r < 4; ++r) acc[a][g][r] = 0.0f;

      // col-tile index 0..31 = wave*2+cg (same swizzle as 8-wave wave*4+cg)
      const __bf16* wp = w1s + ((size_t)(wave * 2 + cg) * 17 * 4 * 512) + (lane << 3);
#pragma unroll 1
      for (int kk = 0; kk < 17; ++kk) {
        const int kof = (kk << 5) + (quad << 3);
        bf16x8 af[3];
#pragma unroll
        for (int rt = 0; rt < 3; ++rt)
          af[rt] = *(const bf16x8*)&hcur[(rt * 16 + colq) * LDH1 + kof];
        bf16x8 bfr[4];
#pragma unroll
        for (int g = 0; g < 4; ++g)
          bfr[g] = *(const bf16x8*)&wp[(kk * 4 + g) << 9];
#pragma unroll
        for (int g = 0; g < 4; ++g)
#pragma unroll
          for (int rt = 0; rt < 3; ++rt)
            acc[rt][g] = __builtin_amdgcn_mfma_f32_16x16x32_bf16(af[rt], bfr[g], acc[rt][g], 0, 0, 0);
      }
#pragma unroll
      for (int rt = 0; rt < 3; ++rt)
#pragma unroll
        for (int r = 0; r < 4; ++r) {
          float c = fsig(acc[rt][1][r] + bF[cg]) * c_reg[cg][rt][r]
                  + fsig(acc[rt][0][r] + bI[cg]) * ftanh(acc[rt][2][r] + bG[cg]);
          c_reg[cg][rt][r] = c;
          float h = fsig(acc[rt][3][r] + bO[cg]) * ftanh(c);
          hnxt[(rt * 16 + quad * 4 + r) * LDH1 + jc + colq] = (__bf16)h;
        }
    }
    if (t < 9 && tid < L1_ROWS * 8) {   // stage x_{t+1} into next buffer
      int row = tid >> 3, jj = tid & 7;
      int gr = r0 + row;
      if (gr < MROWS) {
        long base = ((long)gr * 10 + (t + 1)) * 13;
        hnxt[row * LDH1 + 512 + jj] = (__bf16)ld_in(cond1, base + jj, bf);
        if (jj < 5) hnxt[row * LDH1 + 520 + jj] = (__bf16)ld_in(cond1, base + 8 + jj, bf);
      }
    }
    __syncthreads();
  }

  // final h is in buffer 0 (t=10 even)
  for (int i = tid; i < L1_ROWS * 64; i += 1024) {
    int row = i >> 6;
    int cb  = (i & 63) << 3;
    *(bf16x8*)&h_out[(size_t)(r0 + row) * 512 + cb] = *(const bf16x8*)&hbuf[0][row * LDH1 + cb];
  }
}

// ---------------- generic MFMA GEMM: out = act(A @ W^T + bias) [* mask] ----------------
template<int ACT, int OUTBF, int MASKED>
__global__ __launch_bounds__(256, 4) void gemm_kernel(
    const __bf16* __restrict__ A, int lda,
    const __bf16* __restrict__ W, int ldw,
    const float* __restrict__ bias,
    float* __restrict__ outf, __bf16* __restrict__ outb, int ldc,
    const float* __restrict__ mask, int K)
{
  const int tid  = threadIdx.x;
  const int wave = tid >> 6;
  const int lane = tid & 63;
  const int colq = lane & 15;
  const int quad = lane >> 4;
  const int m0 = blockIdx.y * 64 + (wave >> 1) * 32;
  const int n0 = blockIdx.x * 64 + (wave & 1) * 32;

  f32x4 acc[2][2];
#pragma unroll
  for (int a = 0; a < 2; ++a)
#pragma unroll
    for (int b = 0; b < 2; ++b)
#pragma unroll
      for (int r = 0; r < 4; ++r) acc[a][b][r] = 0.0f;

  const int nk = (K + 31) >> 5;
  for (int kk = 0; kk < nk; ++kk) {
    const int kof = (kk << 5) + (quad << 3);
    bf16x8 a0, a1, b0, b1;
    if (kof < K) {
      a0 = *(const bf16x8*)&A[(size_t)(m0 + colq) * lda + kof];
      a1 = *(const bf16x8*)&A[(size_t)(m0 + 16 + colq) * lda + kof];
      b0 = *(const bf16x8*)&W[(size_t)(n0 + colq) * ldw + kof];
      b1 = *(const bf16x8*)&W[(size_t)(n0 + 16 + colq) * ldw + kof];
    } else {
      a0 = bzero8(); a1 = a0; b0 = a0; b1 = a0;
    }
    acc[0][0] = __builtin_amdgcn_mfma_f32_16x16x32_bf16(a0, b0, acc[0][0], 0, 0, 0);
    acc[0][1] = __builtin_amdgcn_mfma_f32_16x16x32_bf16(a0, b1, acc[0][1], 0, 0, 0);
    acc[1][0] = __builtin_amdgcn_mfma_f32_16x16x32_bf16(a1, b0, acc[1][0], 0, 0, 0);
    acc[1][1] = __builtin_amdgcn_mfma_f32_16x16x32_bf16(a1, b1, acc[1][1], 0, 0, 0);
  }
#pragma unroll
  for (int ai = 0; ai < 2; ++ai)
#pragma unroll
    for (int bi = 0; bi < 2; ++bi) {
      const int col = n0 + bi * 16 + colq;
      const float bv = bias[col];
#pragma unroll
      for (int r = 0; r < 4; ++r) {
        const int row = m0 + ai * 16 + quad * 4 + r;
        float v = acc[ai][bi][r] + bv;
        if (ACT) v = fmaxf(v, 0.0f);
        if (MASKED) v *= mask[row];
        if (OUTBF) outb[(size_t)row * ldc + col] = (__bf16)v;
        else       outf[(size_t)row * ldc + col] = v;
      }
    }
}

// ---------------- samples GEMM: A chosen by dtype flag ----------------
// out = relu(A @ W^T + b) * mask -> Astage cols 379..634 (ldc 640), K=1000.
__global__ __launch_bounds__(256, 4) void sampgemm_kernel(
    const int* __restrict__ flagp,
    const void* __restrict__ samples_raw,   // bf16 path reads this directly
    const __bf16* __restrict__ samp_bf,     // f32 path: converted copy
    const __bf16* __restrict__ W,
    const float* __restrict__ bias,
    __bf16* __restrict__ outb,
    const float* __restrict__ mask)
{
  const __bf16* A = (*flagp) ? (const __bf16*)samples_raw : samp_bf;
  const int tid  = threadIdx.x;
  const int wave = tid >> 6;
  const int lane = tid & 63;
  const int colq = lane & 15;
  const int quad = lane >> 4;
  const int m0 = blockIdx.y * 64 + (wave >> 1) * 32;
  const int n0 = blockIdx.x * 64 + (wave & 1) * 32;
  const int K = 1000;

  f32x4 acc[2][2];
#pragma unroll
  for (int a = 0; a < 2; ++a)
#pragma unroll
    for (int b = 0; b < 2; ++b)
#pragma unroll
      for (int r = 0; r < 4; ++r) acc[a][b][r] = 0.0f;

  for (int kk = 0; kk < 32; ++kk) {
    const int kof = (kk << 5) + (quad << 3);
    bf16x8 a0, a1, b0, b1;
    if (kof < K) {
      a0 = *(const bf16x8*)&A[(size_t)(m0 + colq) * 1000 + kof];
      a1 = *(const bf16x8*)&A[(size_t)(m0 + 16 + colq) * 1000 + kof];
      b0 = *(const bf16x8*)&W[(size_t)(n0 + colq) * 1000 + kof];
      b1 = *(const bf16x8*)&W[(size_t)(n0 + 16 + colq) * 1000 + kof];
    } else {
      a0 = bzero8(); a1 = a0; b0 = a0; b1 = a0;
    }
    acc[0][0] = __builtin_amdgcn_mfma_f32_16x16x32_bf16(a0, b0, acc[0][0], 0, 0, 0);
    acc[0][1] = __builtin_amdgcn_mfma_f32_16x16x32_bf16(a0, b1, acc[0][1], 0, 0, 0);
    acc[1][0] = __builtin_amdgcn_mfma_f32_16x16x32_bf16(a1, b0, acc[1][0], 0, 0, 0);
    acc[1][1] = __builtin_amdgcn_mfma_f32_16x16x32_bf16(a1, b1, acc[1][1], 0, 0, 0);
  }
#pragma unroll
  for (int ai = 0; ai < 2; ++ai)
#pragma unroll
    for (int bi = 0; bi < 2; ++bi) {
      const int col = n0 + bi * 16 + colq;
      const float bv = bias[col];
#pragma unroll
      for (int r = 0; r < 4; ++r) {
        const int row = m0 + ai * 16 + quad * 4 + r;
        float v = fmaxf(acc[ai][bi][r] + bv, 0.0f) * mask[row];
        outb[(size_t)row * 640 + col] = (__bf16)v;
      }
    }
}

// ---------------- fused tree level: quarter-K gather + GEMM(K=1152) + cell ----------
// R18: 1024 thr (16 waves), same grid (32,8). kq = wave>>2 (K quarter),
// wv = wave&3 (row sub-tile). kq0: feature kk 0..9; kq1: feature kk 10..19;
// kq2: h kk 20..27; kq3: h kk 28..35. Traffic invariant vs R12/R17 (disjoint
// kk slices). 48KB LDS, scalar-f32 conflict-free reduction layout. kq0 adds
// 3 partials and runs the unchanged epilogue. 4 waves/SIMD.
__global__ __launch_bounds__(1024, 4) void treelvl_kernel(
    const __bf16* __restrict__ Alvl,    // (512,640) level features
    const __bf16* __restrict__ w2s,     // swizzled (2048x1152)
    const float* __restrict__ bias,     // 2048
    const int* __restrict__ mapping,    // level's (2,512)
    const __bf16* __restrict__ h_src, const float* __restrict__ c_src,
    __bf16* __restrict__ h_dst, float* __restrict__ c_dst,
    float* __restrict__ h_f32, int first, int last)
{
  __shared__ float red[3][16 * 256];   // 3 slots x 16KB, [g*4+r][wv*64+lane]
  const int tid  = threadIdx.x;
  const int wave = tid >> 6;          // 0..15
  const int lane = tid & 63;
  const int colq = lane & 15;
  const int quad = lane >> 4;
  const int wv   = wave & 3;          // row sub-tile 0..3
  const int kq   = wave >> 2;         // K quarter 0..3
  const int jt = blockIdx.x;
  const int mt = blockIdx.y;
  const int rowA = mt * 64 + wv * 16 + colq;

  const __bf16* wbase = w2s + (size_t)jt * 36 * 4 * 512 + (lane << 3);

  f32x4 acc[4];
#pragma unroll
  for (int g = 0; g < 4; ++g)
#pragma unroll
    for (int r = 0; r < 4; ++r) acc[g][r] = 0.0f;

  if (kq < 2) {
    // ---- feature part of K: kq0 -> kk 0..9, kq1 -> kk 10..19 ----
    const __bf16* arow = Alvl + (size_t)rowA * 640;
    const int kb = kq * 10;
#pragma unroll 2
    for (int ki = 0; ki < 10; ++ki) {
      const int kk = kb + ki;
      const int kof = (kk << 5) + (quad << 3);
      bf16x8 afr = *(const bf16x8*)&arow[kof];
      bf16x8 b0 = *(const bf16x8*)&wbase[(kk * 4 + 0) << 9];
      bf16x8 b1 = *(const bf16x8*)&wbase[(kk * 4 + 1) << 9];
      bf16x8 b2 = *(const bf16x8*)&wbase[(kk * 4 + 2) << 9];
      bf16x8 b3 = *(const bf16x8*)&wbase[(kk * 4 + 3) << 9];
      acc[0] = __builtin_amdgcn_mfma_f32_16x16x32_bf16(afr, b0, acc[0], 0, 0, 0);
      acc[1] = __builtin_amdgcn_mfma_f32_16x16x32_bf16(afr, b1, acc[1], 0, 0, 0);
      acc[2] = __builtin_amdgcn_mfma_f32_16x16x32_bf16(afr, b2, acc[2], 0, 0, 0);
      acc[3] = __builtin_amdgcn_mfma_f32_16x16x32_bf16(afr, b3, acc[3], 0, 0, 0);
    }
  } else {
    // ---- gathered-h part of K: kq2 -> kk 20..27, kq3 -> kk 28..35 ----
    int i0 = 0, i1 = 0;
    if (!first) { i0 = mapping[rowA]; i1 = mapping[512 + rowA]; }
    const float s0 = (i0 > 0) ? 0.5f : 0.0f;
    const float s1 = (i1 > 0) ? 0.5f : 0.0f;
    const __bf16* h0p = h_src + (size_t)((i0 > 0 ? i0 : 1) - 1) * 512;
    const __bf16* h1p = h_src + (size_t)((i1 > 0 ? i1 : 1) - 1) * 512;
    const int kb = 20 + (kq - 2) * 8;
#pragma unroll 2
    for (int ki = 0; ki < 8; ++ki) {
      const int kk = kb + ki;
      const int kh = ((kk - 20) << 5) + (quad << 3);
      bf16x8 v0 = *(const bf16x8*)&h0p[kh];
      bf16x8 v1 = *(const bf16x8*)&h1p[kh];
      bf16x8 afr;
#pragma unroll
      for (int e = 0; e < 8; ++e)
        afr[e] = (__bf16)((float)v0[e] * s0 + (float)v1[e] * s1);
      bf16x8 b0 = *(const bf16x8*)&wbase[(kk * 4 + 0) << 9];
      bf16x8 b1 = *(const bf16x8*)&wbase[(kk * 4 + 1) << 9];
      bf16x8 b2 = *(const bf16x8*)&wbase[(kk * 4 + 2) << 9];
      bf16x8 b3 = *(const bf16x8*)&wbase[(kk * 4 + 3) << 9];
      acc[0] = __builtin_amdgcn_mfma_f32_16x16x32_bf16(afr, b0, acc[0], 0, 0, 0);
      acc[1] = __builtin_amdgcn_mfma_f32_16x16x32_bf16(afr, b1, acc[1], 0, 0, 0);
      acc[2] = __builtin_amdgcn_mfma_f32_16x16x32_bf16(afr, b2, acc[2], 0, 0, 0);
      acc[3] = __builtin_amdgcn_mfma_f32_16x16x32_bf16(afr, b3, acc[3], 0, 0, 0);
    }
  }

  if (kq > 0) {
    // stash partials: scalar f32, lane-consecutive -> conflict-free
    float* rp = red[kq - 1];
    const int base = wv * 64 + lane;
#pragma unroll
    for (int g = 0; g < 4; ++g)
#pragma unroll
      for (int r = 0; r < 4; ++r)
        rp[(g * 4 + r) * 256 + base] = acc[g][r];
  }
  __syncthreads();
  if (kq != 0) return;

  // kq0: combine 3 partials, then the unchanged epilogue
  {
    const int base = wv * 64 + lane;
#pragma unroll
    for (int s = 0; s < 3; ++s) {
      const float* rp = red[s];
#pragma unroll
      for (int g = 0; g < 4; ++g)
#pragma unroll
        for (int r = 0; r < 4; ++r)
          acc[g][r] += rp[(g * 4 + r) * 256 + base];
    }
  }

  // epilogue: i,f,g,o -> c,h
  const int j = jt * 16 + colq;
  const float bi  = bias[j];
  const float bff = bias[512 + j];
  const float bg  = bias[1024 + j];
  const float bo  = bias[1536 + j];
#pragma unroll
  for (int r = 0; r < 4; ++r) {
    const int mrow = mt * 64 + wv * 16 + quad * 4 + r;
    float ci = 0.0f;
    if (!first) {
      int a0 = mapping[mrow], a1 = mapping[512 + mrow];
      if (a0 > 0) ci += c_src[(size_t)(a0 - 1) * 512 + j];
      if (a1 > 0) ci += c_src[(size_t)(a1 - 1) * 512 + j];
      ci *= 0.5f;
    }
    float c = fsig(acc[1][r] + bff) * ci + fsig(acc[0][r] + bi) * ftanh(acc[2][r] + bg);
    float h = fsig(acc[3][r] + bo) * ftanh(c);
    h_dst[(size_t)mrow * 512 + j] = (__bf16)h;
    c_dst[(size_t)mrow * 512 + j] = c;
    if (last) h_f32[(size_t)mrow * 512 + j] = h;
  }
}

// ---------------- batchnorm helpers ----------------
__global__ void stats1_kernel(const float* __restrict__ in, int ld, int N,
                              int rows_per_blk, float* __restrict__ partial)
{
  int b = blockIdx.x;
  int r0 = b * rows_per_blk;
  for (int c = threadIdx.x; c < N; c += blockDim.x) {
    float s = 0.0f, sq = 0.0f;
    for (int r = 0; r < rows_per_blk; ++r) {
      float v = in[(size_t)(r0 + r) * ld + c];
      s += v; sq += v * v;
    }
    partial[(size_t)(2 * b) * N + c] = s;
    partial[(size_t)(2 * b + 1) * N + c] = sq;
  }
}

__global__ void stats2_kernel(const float* __restrict__ partial, int nb, int N,
                              float invM, float* __restrict__ stats)
{
  int c = blockIdx.x * blockDim.x + threadIdx.x;
  if (c >= N) return;
  float s = 0.0f, sq = 0.0f;
  for (int b = 0; b < nb; ++b) {
    s  += partial[(size_t)(2 * b) * N + c];
    sq += partial[(size_t)(2 * b + 1) * N + c];
  }
  float mean = s * invM;
  float var  = sq * invM - mean * mean;
  stats[c]     = mean;
  stats[N + c] = rsqrtf(fmaxf(var, 0.0f) + 1e-5f);
}

__global__ void norm_kernel(const float* __restrict__ in, int ldin,
                            const float* __restrict__ stats, int N, int cshift, int gmask,
                            const float* __restrict__ g, const float* __restrict__ b,
                            __bf16* __restrict__ outp, int ldc, int total)
{
  for (int idx = blockIdx.x * blockDim.x + threadIdx.x; idx < total;
       idx += gridDim.x * blockDim.x) {
    int row = idx >> cshift;
    int c = idx & (N - 1);
    float v = (in[(size_t)row * ldin + c] - stats[c]) * stats[N + c];
    int gi = c & gmask;
    v = v * g[gi] + b[gi];
    outp[(size_t)row * ldc + c] = (__bf16)v;
  }
}

// ---------------- output heads: one wave per output ----------------
// R18: was a 256-iter serial dot per thread (uncoalesced). Now lane k of
// wave gw loads 4 coalesced elements, shfl_down tree-reduce, lane0 stores.
__global__ void head_kernel(const int* __restrict__ flagp,
                            const __bf16* __restrict__ tmp3,
                            const float* __restrict__ pf,
                            void* __restrict__ outp)
{
  const int bf = *flagp;
  const int gw   = blockIdx.x * 4 + (threadIdx.x >> 6);  // 0..1023
  const int lane = threadIdx.x & 63;
  const int which = gw >> 9;
  const int n     = gw & 511;
  const __bf16* row = tmp3 + (size_t)n * 512 + which * 256;
  const float* ow = pf + PF_OW + which * 256;
  float s = 0.0f;
#pragma unroll
  for (int i = 0; i < 4; ++i) {
    const int k = lane + 64 * i;
    s += (float)row[k] * ow[k];
  }
#pragma unroll
  for (int off = 32; off > 0; off >>= 1)
    s += __shfl_down(s, off);
  if (lane == 0) {
    float v = fsig(s + pf[PF_OB + which]);
    if (bf) ((__bf16*)outp)[gw] = (__bf16)v;
    else    ((float*)outp)[gw]  = v;
  }
}

// ---------------- launch ----------------
extern "C" void kernel_launch(void* const* d_in, const int* in_sizes, int n_in,
                              void* d_out, int out_size, void* d_ws, size_t ws_size,
                              hipStream_t stream) {
  const void* operators       = d_in[0];
  const void* extra_infos     = d_in[1];
  const void* condition1s     = d_in[2];
  const void* samples         = d_in[4];
  const void* condition_masks = d_in[5];
  const int*  mapping         = (const int*)d_in[6];
  (void)in_sizes; (void)n_in; (void)out_size; (void)ws_size;

  char* ws = (char*)d_ws;
  size_t off = 0;
  auto alloc = [&](size_t bytes) -> void* {
    void* p = ws + off;
    off += (bytes + 255) & ~(size_t)255;
    return p;
  };
  int*    flag     = (int*)   alloc(256);
  __bf16* w1s      = (__bf16*)alloc((size_t)2048 * 544 * 2);
  __bf16* w2s      = (__bf16*)alloc((size_t)2048 * 1152 * 2);
  __bf16* wcat2    = (__bf16*)alloc(512 * 512 * 2);
  __bf16* cond_w_bf   = (__bf16*)alloc(256 * 512 * 2);
  __bf16* sample_w_bf = (__bf16*)alloc(256 * 1000 * 2);
  __bf16* w3cat_bf    = (__bf16*)alloc(512 * 256 * 2);
  float*  mask_f   = (float*) alloc(10240 * 4);
  float*  pf       = (float*) alloc(PF_TOTAL * 4);
  __bf16* samp_bf  = (__bf16*)alloc((size_t)10240 * 1000 * 2);
  __bf16* h_last   = (__bf16*)alloc((size_t)10272 * 512 * 2);
  float*  condtmp  = (float*) alloc((size_t)10240 * 256 * 4);
  __bf16* Astage   = (__bf16*)alloc((size_t)20 * 512 * 640 * 2);
  __bf16* hs0      = (__bf16*)alloc(512 * 512 * 2);
  __bf16* hs1      = (__bf16*)alloc(512 * 512 * 2);
  float*  cs0      = (float*) alloc(512 * 512 * 4);
  float*  cs1      = (float*) alloc(512 * 512 * 4);
  float*  h_f32    = (float*) alloc(512 * 512 * 4);
  __bf16* zbuf     = (__bf16*)alloc(512 * 512 * 2);
  float*  tmp1     = (float*) alloc(512 * 512 * 4);
  __bf16* tmp2     = (__bf16*)alloc(512 * 512 * 2);
  __bf16* tmp3     = (__bf16*)alloc(512 * 512 * 2);
  float*  partial  = (float*) alloc(64 * 2 * 512 * 4);
  float*  statsb   = (float*) alloc(2 * 512 * 4);

  detect_kernel<<<1, 64, 0, stream>>>((const unsigned*)condition_masks, flag);
  prep_kernel<<<4096, 256, 0, stream>>>(flag,
      d_in[7], d_in[8], d_in[9], d_in[10],
      d_in[17], d_in[18], d_in[19], d_in[20],
      d_in[23], d_in[25], d_in[24], d_in[26],
      d_in[13], d_in[14], d_in[11], d_in[12],
      d_in[15], d_in[16], d_in[21], d_in[22],
      d_in[27], d_in[28],
      d_in[29], d_in[30], d_in[31], d_in[32],
      d_in[33], d_in[34], d_in[35], d_in[36],
      condition_masks,
      w1s, w2s, wcat2, cond_w_bf, sample_w_bf, w3cat_bf, mask_f, pf);
  conv_samples_kernel<<<4096, 256, 0, stream>>>(flag, samples, samp_bf);
  featcopy_kernel<<<5120, 256, 0, stream>>>(flag, operators, extra_infos, Astage);
  lstm1_kernel<<<L1_BLOCKS, 1024, 0, stream>>>(flag, condition1s, w1s, pf + PF_BIAS1, h_last);

  // cond = bn1(relu(h_last @ cond_w^T + cond_b)) -> Astage cols 123..378
  gemm_kernel<1,0,0><<<dim3(4,160), 256, 0, stream>>>(h_last, 512, cond_w_bf, 512,
      pf + PF_CONDB, condtmp, nullptr, 256, nullptr, 512);
  stats1_kernel<<<64, 256, 0, stream>>>(condtmp, 256, 256, 160, partial);
  stats2_kernel<<<1, 256, 0, stream>>>(partial, 64, 256, 1.0f / 10240.0f, statsb);
  norm_kernel<<<2560, 256, 0, stream>>>(condtmp, 256, statsb, 256, 8, 255,
      pf + PF_BN1G, pf + PF_BN1B, Astage + 123, 640, 10240 * 256);

  // samp = relu(samples @ sample_w^T + sample_b) * mask -> Astage cols 379..634
  sampgemm_kernel<<<dim3(4,160), 256, 0, stream>>>(flag, samples, samp_bf,
      sample_w_bf, pf + PF_SAMPB, Astage + 379, mask_f);

  // tree: lvl 19 (zero state) down to 0; ping-pong state by level parity
  for (int lvl = 19; lvl >= 0; --lvl) {
    __bf16* hd = (lvl & 1) ? hs1 : hs0;
    float*  cd = (lvl & 1) ? cs1 : cs0;
    const __bf16* hsrc = (lvl & 1) ? hs0 : hs1;
    const float*  csrc = (lvl & 1) ? cs0 : cs1;
    treelvl_kernel<<<dim3(32,8), 1024, 0, stream>>>(
        Astage + (size_t)lvl * 512 * 640, w2s, pf + PF_BIAS2,
        mapping + lvl * 1024, hsrc, csrc, hd, cd, h_f32,
        (lvl == 19) ? 1 : 0, (lvl == 0) ? 1 : 0);
  }

  // z = bn2(hid)
  stats1_kernel<<<8, 256, 0, stream>>>(h_f32, 512, 512, 64, partial);
  stats2_kernel<<<2, 256, 0, stream>>>(partial, 8, 512, 1.0f / 512.0f, statsb);
  norm_kernel<<<256, 256, 0, stream>>>(h_f32, 512, statsb, 512, 9, 511,
      pf + PF_BN2G, pf + PF_BN2B, zbuf, 512, 512 * 512);

  // [t1|t2] = bn3(relu(z @ [t1_w2;t2_w2]^T + b))
  gemm_kernel<1,0,0><<<dim3(8,8), 256, 0, stream>>>(zbuf, 512, wcat2, 512,
      pf + PF_BCAT2, tmp1, nullptr, 512, nullptr, 512);
  stats1_kernel<<<8, 256, 0, stream>>>(tmp1, 512, 512, 64, partial);
  stats2_kernel<<<2, 256, 0, stream>>>(partial, 8, 512, 1.0f / 512.0f, statsb);
  norm_kernel<<<256, 256, 0, stream>>>(tmp1, 512, statsb, 512, 9, 255,
      pf + PF_BN3G, pf + PF_BN3B, tmp2, 512, 512 * 512);

  // relu(t @ w3^T + b3) for both heads
  gemm_kernel<1,1,0><<<dim3(4,8), 256, 0, stream>>>(tmp2, 512, w3cat_bf, 256,
      pf + PF_B3CAT, nullptr, tmp3, 512, nullptr, 256);
  gemm_kernel<1,1,0><<<dim3(4,8), 256, 0, stream>>>(tmp2 + 256, 512, w3cat_bf + 256 * 256, 256,
      pf + PF_B3CAT + 256, nullptr, tmp3 + 256, 512, nullptr, 256);

  head_kernel<<<256, 256, 0, stream>>>(flag, tmp3, pf, d_out);
}

// Round 11
// 934.621 us; speedup vs baseline: 1.8526x; 1.0221x over previous
//
#include <hip/hip_runtime.h>
#include <hip/hip_bf16.h>

// Representation_32074815766664 — bf16 I/O (runtime-detected f32 fallback),
// bf16 MFMA internally, f32 accumulation/state.
//
// R21 = R20 with the f32-path race fixed:
//  - R20 post-mortem: absmax 0.2246. fused1 ≡ R18 on the bf16 path; the only
//    semantic diff is f32-path conv_samples (writes samp_bf) racing sampgemm
//    (reads samp_bf) in one launch => harness input is f32 (bf=0) and the
//    kernel boundary WAS the sync. conv_samples restored as a separate
//    kernel BEFORE fused1; conv branch removed from fused1 (446->414 blocks).
//  - R19 idea retained: blocks 0..213 = EXACT frozen lstm1; 214..373 =
//    sampgemm (4 virtual 256-thr blocks each); 374..413 = featcopy. The 42
//    CUs idle during lstm1 absorb the independent work; 2 launch boundaries
//    disappear.
//  - tree/bn/head frozen at R18 form. lstm1 FROZEN at R12 form.

typedef __bf16 bf16x8 __attribute__((ext_vector_type(8)));
typedef float f32x4 __attribute__((ext_vector_type(4)));

#define MROWS 10240
#define LDH1  552     // padded LDS stride (2-way bank aliasing only)
#define L1_ROWS 48
#define L1_BLOCKS 214 // ceil(10240/48)
#define SAMP_BASE 214 // 160 blocks (640 virtual)
#define FEAT_BASE 374 // 40 blocks
#define FUSED_BLOCKS 414

// pf (canonical f32 params) offsets
#define PF_BIAS1   0
#define PF_BIAS2   2048
#define PF_CONDB   4096
#define PF_SAMPB   4352
#define PF_BCAT2   4608
#define PF_B3CAT   5120
#define PF_BN1G    5632
#define PF_BN1B    5888
#define PF_BN2G    6144
#define PF_BN2B    6656
#define PF_BN3G    7168
#define PF_BN3B    7424
#define PF_OW      7680
#define PF_OB      8192
#define PF_TOTAL   8194

// sig(x) = 1/(1+exp(-x)); robust without clamps: exp->inf => rcp->0.
__device__ __forceinline__ float fsig(float x) {
  return __builtin_amdgcn_rcpf(1.0f + __expf(-x));
}
// tanh(x) = 2*sig(2x) - 1; robust at both infinities.
__device__ __forceinline__ float ftanh(float x) {
  return fmaf(2.0f, __builtin_amdgcn_rcpf(1.0f + __expf(-2.0f * x)), -1.0f);
}
__device__ __forceinline__ bf16x8 bzero8() {
  bf16x8 z;
#pragma unroll
  for (int i = 0; i < 8; ++i) z[i] = (__bf16)0.0f;
  return z;
}
__device__ __forceinline__ float ld_in(const void* p, long i, int bf) {
  return bf ? (float)((const __bf16*)p)[i] : ((const float*)p)[i];
}

// ---------------- detect ----------------
__global__ void detect_kernel(const unsigned* __restrict__ masks, int* __restrict__ flag) {
  if (blockIdx.x == 0 && threadIdx.x == 0)
    *flag = (masks[0] == 0x3F803F80u) ? 1 : 0;
}

// ---------------- prep: canonicalize; w1s swizzled, w2s swizzled ----------------
// w1s: elem((cgt*17+kk)*4+g, lane, e) = w_aug1[g*512+cgt*16+(lane&15)][kk*32+(lane>>4)*8+e]
__global__ void prep_kernel(const int* __restrict__ flagp,
    const void* w_ih1, const void* w_hh1, const void* b_ih1, const void* b_hh1,
    const void* w_ih2, const void* w_hh2, const void* b_ih2, const void* b_hh2,
    const void* t1_w2, const void* t2_w2, const void* t1_b2, const void* t2_b2,
    const void* cond_w, const void* cond_b, const void* sample_w, const void* sample_b,
    const void* bn1_g, const void* bn1_b, const void* bn2_g, const void* bn2_b,
    const void* bn3_g, const void* bn3_b,
    const void* t1_w3, const void* t1_b3, const void* t2_w3, const void* t2_b3,
    const void* t1_ow, const void* t1_ob, const void* t2_ow, const void* t2_ob,
    const void* masks,
    __bf16* __restrict__ w1s, __bf16* __restrict__ w2s,
    __bf16* __restrict__ wcat2, __bf16* __restrict__ cond_w_bf,
    __bf16* __restrict__ sample_w_bf, __bf16* __restrict__ w3cat_bf,
    float* __restrict__ mask_f, float* __restrict__ pf)
{
  const int bf = *flagp;
  const int S1 = 2048 * 544;   // w1s swizzled
  const int S2 = 2048 * 1152;  // w2s swizzled
  const int S3 = 512 * 512;
  const int S4 = 256 * 512;
  const int S5 = 256 * 1000;
  const int S6 = 512 * 256;
  const int S7 = 10240;
  const int total = S1 + S2 + S3 + S4 + S5 + S6 + S7 + PF_TOTAL;
  for (int idx = blockIdx.x * blockDim.x + threadIdx.x; idx < total;
       idx += gridDim.x * blockDim.x) {
    int i = idx;
    if (i < S1) {
      int e = i & 7, l = (i >> 3) & 63, g = (i >> 9) & 3;
      int grp = i >> 11;               // cgt*17 + kk
      int kk = grp % 17, cgt = grp / 17;
      int colq = l & 15, quad = l >> 4;
      int row = g * 512 + cgt * 16 + colq;
      int k = kk * 32 + quad * 8 + e;
      float v = (k < 512) ? ld_in(w_hh1, (long)row * 512 + k, bf)
              : (k < 525) ? ld_in(w_ih1, (long)row * 13 + (k - 512), bf) : 0.0f;
      w1s[i] = (__bf16)v;
      continue;
    }
    i -= S1;
    if (i < S2) {
      int e = i & 7, l = (i >> 3) & 63, g = (i >> 9) & 3;
      int grp = i >> 11;               // jt*36 + kk
      int kk = grp % 36, jt = grp / 36;
      int colq = l & 15, quad = l >> 4;
      int row = g * 512 + jt * 16 + colq;
      int k = kk * 32 + quad * 8 + e;
      float v = (k < 635) ? ld_in(w_ih2, (long)row * 635 + k, bf)
              : (k < 640) ? 0.0f : ld_in(w_hh2, (long)row * 512 + (k - 640), bf);
      w2s[i] = (__bf16)v;
      continue;
    }
    i -= S2;
    if (i < S3) {
      int r = i >> 9, k = i & 511;
      wcat2[i] = (__bf16)((r < 256) ? ld_in(t1_w2, r * 512 + k, bf)
                                    : ld_in(t2_w2, (r - 256) * 512 + k, bf));
      continue;
    }
    i -= S3;
    if (i < S4) { cond_w_bf[i] = (__bf16)ld_in(cond_w, i, bf); continue; }
    i -= S4;
    if (i < S5) { sample_w_bf[i] = (__bf16)ld_in(sample_w, i, bf); continue; }
    i -= S5;
    if (i < S6) {
      int r = i >> 8, k = i & 255;
      w3cat_bf[i] = (__bf16)((r < 256) ? ld_in(t1_w3, r * 256 + k, bf)
                                       : ld_in(t2_w3, (r - 256) * 256 + k, bf));
      continue;
    }
    i -= S6;
    if (i < S7) { mask_f[i] = ld_in(masks, i, bf); continue; }
    i -= S7;
    {
      int j = i;
      float v;
      if      (j < 2048) v = ld_in(b_ih1, j, bf) + ld_in(b_hh1, j, bf);
      else if (j < 4096) v = ld_in(b_ih2, j - 2048, bf) + ld_in(b_hh2, j - 2048, bf);
      else if (j < 4352) v = ld_in(cond_b, j - 4096, bf);
      else if (j < 4608) v = ld_in(sample_b, j - 4352, bf);
      else if (j < 5120) { int k = j - 4608; v = (k < 256) ? ld_in(t1_b2, k, bf) : ld_in(t2_b2, k - 256, bf); }
      else if (j < 5632) { int k = j - 5120; v = (k < 256) ? ld_in(t1_b3, k, bf) : ld_in(t2_b3, k - 256, bf); }
      else if (j < 5888) v = ld_in(bn1_g, j - 5632, bf);
      else if (j < 6144) v = ld_in(bn1_b, j - 5888, bf);
      else if (j < 6656) v = ld_in(bn2_g, j - 6144, bf);
      else if (j < 7168) v = ld_in(bn2_b, j - 6656, bf);
      else if (j < 7424) v = ld_in(bn3_g, j - 7168, bf);
      else if (j < 7680) v = ld_in(bn3_b, j - 7424, bf);
      else if (j < 8192) { int k = j - 7680; v = (k < 256) ? ld_in(t1_ow, k, bf) : ld_in(t2_ow, k - 256, bf); }
      else v = (j == 8192) ? ld_in(t1_ob, 0, bf) : ld_in(t2_ob, 0, bf);
      pf[j] = v;
    }
  }
}

// ---------------- samples -> bf16 (only needed on f32 path) ----------------
// Separate kernel: its completion is the sync that fused1's sampgemm needs.
__global__ void conv_samples_kernel(const int* __restrict__ flagp,
                                    const void* __restrict__ samples,
                                    __bf16* __restrict__ dst)
{
  const int bf = *flagp;
  if (bf) return;   // bf16 input is already the matrix the GEMM reads
  for (long i = blockIdx.x * blockDim.x + threadIdx.x; i < 10240000L;
       i += (long)gridDim.x * blockDim.x)
    dst[i] = (__bf16)ld_in(samples, i, bf);
}

// ---------------- fused: lstm1 (blocks 0..213, FROZEN body) + sampgemm +
// featcopy on the idle CUs ----------------
__global__ __launch_bounds__(1024, 4) void fused1_kernel(
    const int* __restrict__ flagp,
    const void* __restrict__ cond1,       // (10240,10,13)
    const __bf16* __restrict__ w1s,       // swizzled (2048x544)
    const float*  __restrict__ bias,      // (2048) = pf+PF_BIAS1
    __bf16* __restrict__ h_out,           // (10272,512) padded
    const void* __restrict__ samples_raw, // sampgemm A (bf16 path)
    const __bf16* __restrict__ samp_bf,   // f32 path: pre-converted copy
    const __bf16* __restrict__ sample_w_bf,
    const float* __restrict__ sampb,      // pf+PF_SAMPB
    __bf16* __restrict__ samp_out,        // Astage+379 (ldc 640)
    const float* __restrict__ mask,
    const void* __restrict__ ops,         // featcopy inputs
    const void* __restrict__ extra,
    __bf16* __restrict__ Astage)          // featcopy dst (stride 640)
{
  const int bf = *flagp;
  const int tid = threadIdx.x;

  if (blockIdx.x < L1_BLOCKS) {
    // ================= lstm1 — R12 form, FROZEN =================
    __shared__ __attribute__((aligned(16))) __bf16 hbuf[2][L1_ROWS * LDH1];
    const int wave = tid >> 6;
    const int lane = tid & 63;
    const int colq = lane & 15;
    const int quad = lane >> 4;
    const int r0   = blockIdx.x * L1_ROWS;

    {
      bf16x8 z8 = bzero8();
      for (int i = tid * 8; i < 2 * L1_ROWS * LDH1; i += 1024 * 8)
        *(bf16x8*)&hbuf[0][i] = z8;
    }
    __syncthreads();
    if (tid < L1_ROWS * 8) {           // stage x_0 into buf 0
      int row = tid >> 3, jj = tid & 7;
      int gr = r0 + row;
      if (gr < MROWS) {
        long base = (long)gr * 130;  // t=0
        hbuf[0][row * LDH1 + 512 + jj] = (__bf16)ld_in(cond1, base + jj, bf);
        if (jj < 5) hbuf[0][row * LDH1 + 520 + jj] = (__bf16)ld_in(cond1, base + 8 + jj, bf);
      }
    }
    __syncthreads();

    float c_reg[2][3][4];
#pragma unroll
    for (int a = 0; a < 2; ++a)
#pragma unroll
      for (int b = 0; b < 3; ++b)
#pragma unroll
        for (int r = 0; r < 4; ++r) c_reg[a][b][r] = 0.0f;

    const int jbase = wave * 32;

    float bI[2], bF[2], bG[2], bO[2];
#pragma unroll
    for (int cg = 0; cg < 2; ++cg) {
      const int j = jbase + cg * 16 + colq;
      bI[cg] = bias[j];
      bF[cg] = bias[512 + j];
      bG[cg] = bias[1024 + j];
      bO[cg] = bias[1536 + j];
    }

#pragma unroll 1
    for (int t = 0; t < 10; ++t) {
      const __bf16* hcur = hbuf[t & 1];
      __bf16* hnxt = hbuf[(t + 1) & 1];
#pragma unroll
      for (int cg = 0; cg < 2; ++cg) {
        const int jc = jbase + cg * 16;
        f32x4 acc[3][4];
#pragma unroll
        for (int a = 0; a < 3; ++a)
#pragma unroll
          for (int g = 0; g < 4; ++g)
#pragma unroll
            for (int r = 0; r < 4; ++r) acc[a][g][r] = 0.0f;

        const __bf16* wp = w1s + ((size_t)(wave * 2 + cg) * 17 * 4 * 512) + (lane << 3);
#pragma unroll 1
        for (int kk = 0; kk < 17; ++kk) {
          const int kof = (kk << 5) + (quad << 3);
          bf16x8 af[3];
#pragma unroll
          for (int rt = 0; rt < 3; ++rt)
            af[rt] = *(const bf16x8*)&hcur[(rt * 16 + colq) * LDH1 + kof];
          bf16x8 bfr[4];
#pragma unroll
          for (int g = 0; g < 4; ++g)
            bfr[g] = *(const bf16x8*)&wp[(kk * 4 + g) << 9];
#pragma unroll
          for (int g = 0; g < 4; ++g)
#pragma unroll
            for (int rt = 0; rt < 3; ++rt)
              acc[rt][g] = __builtin_amdgcn_mfma_f32_16x16x32_bf16(af[rt], bfr[g], acc[rt][g], 0, 0, 0);
        }
#pragma unroll
        for (int rt = 0; rt < 3; ++rt)
#pragma unroll
          for (int r = 0; r < 4; ++r) {
            float c = fsig(acc[rt][1][r] + bF[cg]) * c_reg[cg][rt][r]
                    + fsig(acc[rt][0][r] + bI[cg]) * ftanh(acc[rt][2][r] + bG[cg]);
            c_reg[cg][rt][r] = c;
            float h = fsig(acc[rt][3][r] + bO[cg]) * ftanh(c);
            hnxt[(rt * 16 + quad * 4 + r) * LDH1 + jc + colq] = (__bf16)h;
          }
      }
      if (t < 9 && tid < L1_ROWS * 8) {   // stage x_{t+1} into next buffer
        int row = tid >> 3, jj = tid & 7;
        int gr = r0 + row;
        if (gr < MROWS) {
          long base = ((long)gr * 10 + (t + 1)) * 13;
          hnxt[row * LDH1 + 512 + jj] = (__bf16)ld_in(cond1, base + jj, bf);
          if (jj < 5) hnxt[row * LDH1 + 520 + jj] = (__bf16)ld_in(cond1, base + 8 + jj, bf);
        }
      }
      __syncthreads();
    }

    // final h is in buffer 0 (t=10 even)
    for (int i = tid; i < L1_ROWS * 64; i += 1024) {
      int row = i >> 6;
      int cb  = (i & 63) << 3;
      *(bf16x8*)&h_out[(size_t)(r0 + row) * 512 + cb] = *(const bf16x8*)&hbuf[0][row * LDH1 + cb];
    }
    return;
  }

  if (blockIdx.x < FEAT_BASE) {
    // ================= sampgemm: 4 virtual 256-thr blocks =================
    const __bf16* A = bf ? (const __bf16*)samples_raw : samp_bf;
    const int vb   = (blockIdx.x - SAMP_BASE) * 4 + (tid >> 8);  // 0..639
    const int bx   = vb & 3;
    const int by   = vb >> 2;
    const int t    = tid & 255;
    const int wave = t >> 6;
    const int lane = t & 63;
    const int colq = lane & 15;
    const int quad = lane >> 4;
    const int m0 = by * 64 + (wave >> 1) * 32;
    const int n0 = bx * 64 + (wave & 1) * 32;
    const int K = 1000;

    f32x4 acc[2][2];
#pragma unroll
    for (int a = 0; a < 2; ++a)
#pragma unroll
      for (int b = 0; b < 2; ++b)
#pragma unroll
        for (int r = 0; r < 4; ++r) acc[a][b][r] = 0.0f;

    for (int kk = 0; kk < 32; ++kk) {
      const int kof = (kk << 5) + (quad << 3);
      bf16x8 a0, a1, b0, b1;
      if (kof < K) {
        a0 = *(const bf16x8*)&A[(size_t)(m0 + colq) * 1000 + kof];
        a1 = *(const bf16x8*)&A[(size_t)(m0 + 16 + colq) * 1000 + kof];
        b0 = *(const bf16x8*)&sample_w_bf[(size_t)(n0 + colq) * 1000 + kof];
        b1 = *(const bf16x8*)&sample_w_bf[(size_t)(n0 + 16 + colq) * 1000 + kof];
      } else {
        a0 = bzero8(); a1 = a0; b0 = a0; b1 = a0;
      }
      acc[0][0] = __builtin_amdgcn_mfma_f32_16x16x32_bf16(a0, b0, acc[0][0], 0, 0, 0);
      acc[0][1] = __builtin_amdgcn_mfma_f32_16x16x32_bf16(a0, b1, acc[0][1], 0, 0, 0);
      acc[1][0] = __builtin_amdgcn_mfma_f32_16x16x32_bf16(a1, b0, acc[1][0], 0, 0, 0);
      acc[1][1] = __builtin_amdgcn_mfma_f32_16x16x32_bf16(a1, b1, acc[1][1], 0, 0, 0);
    }
#pragma unroll
    for (int ai = 0; ai < 2; ++ai)
#pragma unroll
      for (int bi = 0; bi < 2; ++bi) {
        const int col = n0 + bi * 16 + colq;
        const float bv = sampb[col];
#pragma unroll
        for (int r = 0; r < 4; ++r) {
          const int row = m0 + ai * 16 + quad * 4 + r;
          float v = fmaxf(acc[ai][bi][r] + bv, 0.0f) * mask[row];
          samp_out[(size_t)row * 640 + col] = (__bf16)v;
        }
      }
    return;
  }

  // ================= featcopy (grid-stride over 10240*128) =================
  for (int idx = (blockIdx.x - FEAT_BASE) * 1024 + tid; idx < 10240 * 128;
       idx += 40 * 1024) {
    int m = idx >> 7, c = idx & 127;
    float v; int col;
    if (c < 15)       { v = ld_in(ops, (long)m * 15 + c, bf);            col = c; }
    else if (c < 123) { v = ld_in(extra, (long)m * 108 + (c - 15), bf);  col = c; }
    else              { v = 0.0f;                                        col = 512 + c; } // 635..639
    Astage[(size_t)m * 640 + col] = (__bf16)v;
  }
}

// ---------------- generic MFMA GEMM: out = act(A @ W^T + bias) [* mask] ----------------
template<int ACT, int OUTBF, int MASKED>
__global__ __launch_bounds__(256, 4) void gemm_kernel(
    const __bf16* __restrict__ A, int lda,
    const __bf16* __restrict__ W, int ldw,
    const float* __restrict__ bias,
    float* __restrict__ outf, __bf16* __restrict__ outb, int ldc,
    const float* __restrict__ mask, int K)
{
  const int tid  = threadIdx.x;
  const int wave = tid >> 6;
  const int lane = tid & 63;
  const int colq = lane & 15;
  const int quad = lane >> 4;
  const int m0 = blockIdx.y * 64 + (wave >> 1) * 32;
  const int n0 = blockIdx.x * 64 + (wave & 1) * 32;

  f32x4 acc[2][2];
#pragma unroll
  for (int a = 0; a < 2; ++a)
#pragma unroll
    for (int b = 0; b < 2; ++b)
#pragma unroll
      for (int r = 0; r < 4; ++r) acc[a][b][r] = 0.0f;

  const int nk = (K + 31) >> 5;
  for (int kk = 0; kk < nk; ++kk) {
    const int kof = (kk << 5) + (quad << 3);
    bf16x8 a0, a1, b0, b1;
    if (kof < K) {
      a0 = *(const bf16x8*)&A[(size_t)(m0 + colq) * lda + kof];
      a1 = *(const bf16x8*)&A[(size_t)(m0 + 16 + colq) * lda + kof];
      b0 = *(const bf16x8*)&W[(size_t)(n0 + colq) * ldw + kof];
      b1 = *(const bf16x8*)&W[(size_t)(n0 + 16 + colq) * ldw + kof];
    } else {
      a0 = bzero8(); a1 = a0; b0 = a0; b1 = a0;
    }
    acc[0][0] = __builtin_amdgcn_mfma_f32_16x16x32_bf16(a0, b0, acc[0][0], 0, 0, 0);
    acc[0][1] = __builtin_amdgcn_mfma_f32_16x16x32_bf16(a0, b1, acc[0][1], 0, 0, 0);
    acc[1][0] = __builtin_amdgcn_mfma_f32_16x16x32_bf16(a1, b0, acc[1][0], 0, 0, 0);
    acc[1][1] = __builtin_amdgcn_mfma_f32_16x16x32_bf16(a1, b1, acc[1][1], 0, 0, 0);
  }
#pragma unroll
  for (int ai = 0; ai < 2; ++ai)
#pragma unroll
    for (int bi = 0; bi < 2; ++bi) {
      const int col = n0 + bi * 16 + colq;
      const float bv = bias[col];
#pragma unroll
      for (int r = 0; r < 4; ++r) {
        const int row = m0 + ai * 16 + quad * 4 + r;
        float v = acc[ai][bi][r] + bv;
        if (ACT) v = fmaxf(v, 0.0f);
        if (MASKED) v *= mask[row];
        if (OUTBF) outb[(size_t)row * ldc + col] = (__bf16)v;
        else       outf[(size_t)row * ldc + col] = v;
      }
    }
}

// ---------------- fused tree level: quarter-K gather + GEMM(K=1152) + cell ----------
// R18 form (FROZEN): 1024 thr (16 waves), grid (32,8). kq = wave>>2, wv = wave&3.
__global__ __launch_bounds__(1024, 4) void treelvl_kernel(
    const __bf16* __restrict__ Alvl,    // (512,640) level features
    const __bf16* __restrict__ w2s,     // swizzled (2048x1152)
    const float* __restrict__ bias,     // 2048
    const int* __restrict__ mapping,    // level's (2,512)
    const __bf16* __restrict__ h_src, const float* __restrict__ c_src,
    __bf16* __restrict__ h_dst, float* __restrict__ c_dst,
    float* __restrict__ h_f32, int first, int last)
{
  __shared__ float red[3][16 * 256];   // 3 slots x 16KB, [g*4+r][wv*64+lane]
  const int tid  = threadIdx.x;
  const int wave = tid >> 6;          // 0..15
  const int lane = tid & 63;
  const int colq = lane & 15;
  const int quad = lane >> 4;
  const int wv   = wave & 3;          // row sub-tile 0..3
  const int kq   = wave >> 2;         // K quarter 0..3
  const int jt = blockIdx.x;
  const int mt = blockIdx.y;
  const int rowA = mt * 64 + wv * 16 + colq;

  const __bf16* wbase = w2s + (size_t)jt * 36 * 4 * 512 + (lane << 3);

  f32x4 acc[4];
#pragma unroll
  for (int g = 0; g < 4; ++g)
#pragma unroll
    for (int r = 0; r < 4; ++r) acc[g][r] = 0.0f;

  if (kq < 2) {
    // ---- feature part of K: kq0 -> kk 0..9, kq1 -> kk 10..19 ----
    const __bf16* arow = Alvl + (size_t)rowA * 640;
    const int kb = kq * 10;
#pragma unroll 2
    for (int ki = 0; ki < 10; ++ki) {
      const int kk = kb + ki;
      const int kof = (kk << 5) + (quad << 3);
      bf16x8 afr = *(const bf16x8*)&arow[kof];
      bf16x8 b0 = *(const bf16x8*)&wbase[(kk * 4 + 0) << 9];
      bf16x8 b1 = *(const bf16x8*)&wbase[(kk * 4 + 1) << 9];
      bf16x8 b2 = *(const bf16x8*)&wbase[(kk * 4 + 2) << 9];
      bf16x8 b3 = *(const bf16x8*)&wbase[(kk * 4 + 3) << 9];
      acc[0] = __builtin_amdgcn_mfma_f32_16x16x32_bf16(afr, b0, acc[0], 0, 0, 0);
      acc[1] = __builtin_amdgcn_mfma_f32_16x16x32_bf16(afr, b1, acc[1], 0, 0, 0);
      acc[2] = __builtin_amdgcn_mfma_f32_16x16x32_bf16(afr, b2, acc[2], 0, 0, 0);
      acc[3] = __builtin_amdgcn_mfma_f32_16x16x32_bf16(afr, b3, acc[3], 0, 0, 0);
    }
  } else {
    // ---- gathered-h part of K: kq2 -> kk 20..27, kq3 -> kk 28..35 ----
    int i0 = 0, i1 = 0;
    if (!first) { i0 = mapping[rowA]; i1 = mapping[512 + rowA]; }
    const float s0 = (i0 > 0) ? 0.5f : 0.0f;
    const float s1 = (i1 > 0) ? 0.5f : 0.0f;
    const __bf16* h0p = h_src + (size_t)((i0 > 0 ? i0 : 1) - 1) * 512;
    const __bf16* h1p = h_src + (size_t)((i1 > 0 ? i1 : 1) - 1) * 512;
    const int kb = 20 + (kq - 2) * 8;
#pragma unroll 2
    for (int ki = 0; ki < 8; ++ki) {
      const int kk = kb + ki;
      const int kh = ((kk - 20) << 5) + (quad << 3);
      bf16x8 v0 = *(const bf16x8*)&h0p[kh];
      bf16x8 v1 = *(const bf16x8*)&h1p[kh];
      bf16x8 afr;
#pragma unroll
      for (int e = 0; e < 8; ++e)
        afr[e] = (__bf16)((float)v0[e] * s0 + (float)v1[e] * s1);
      bf16x8 b0 = *(const bf16x8*)&wbase[(kk * 4 + 0) << 9];
      bf16x8 b1 = *(const bf16x8*)&wbase[(kk * 4 + 1) << 9];
      bf16x8 b2 = *(const bf16x8*)&wbase[(kk * 4 + 2) << 9];
      bf16x8 b3 = *(const bf16x8*)&wbase[(kk * 4 + 3) << 9];
      acc[0] = __builtin_amdgcn_mfma_f32_16x16x32_bf16(afr, b0, acc[0], 0, 0, 0);
      acc[1] = __builtin_amdgcn_mfma_f32_16x16x32_bf16(afr, b1, acc[1], 0, 0, 0);
      acc[2] = __builtin_amdgcn_mfma_f32_16x16x32_bf16(afr, b2, acc[2], 0, 0, 0);
      acc[3] = __builtin_amdgcn_mfma_f32_16x16x32_bf16(afr, b3, acc[3], 0, 0, 0);
    }
  }

  if (kq > 0) {
    // stash partials: scalar f32, lane-consecutive -> conflict-free
    float* rp = red[kq - 1];
    const int base = wv * 64 + lane;
#pragma unroll
    for (int g = 0; g < 4; ++g)
#pragma unroll
      for (int r = 0; r < 4; ++r)
        rp[(g * 4 + r) * 256 + base] = acc[g][r];
  }
  __syncthreads();
  if (kq != 0) return;

  // kq0: combine 3 partials, then the unchanged epilogue
  {
    const int base = wv * 64 + lane;
#pragma unroll
    for (int s = 0; s < 3; ++s) {
      const float* rp = red[s];
#pragma unroll
      for (int g = 0; g < 4; ++g)
#pragma unroll
        for (int r = 0; r < 4; ++r)
          acc[g][r] += rp[(g * 4 + r) * 256 + base];
    }
  }

  // epilogue: i,f,g,o -> c,h
  const int j = jt * 16 + colq;
  const float bi  = bias[j];
  const float bff = bias[512 + j];
  const float bg  = bias[1024 + j];
  const float bo  = bias[1536 + j];
#pragma unroll
  for (int r = 0; r < 4; ++r) {
    const int mrow = mt * 64 + wv * 16 + quad * 4 + r;
    float ci = 0.0f;
    if (!first) {
      int a0 = mapping[mrow], a1 = mapping[512 + mrow];
      if (a0 > 0) ci += c_src[(size_t)(a0 - 1) * 512 + j];
      if (a1 > 0) ci += c_src[(size_t)(a1 - 1) * 512 + j];
      ci *= 0.5f;
    }
    float c = fsig(acc[1][r] + bff) * ci + fsig(acc[0][r] + bi) * ftanh(acc[2][r] + bg);
    float h = fsig(acc[3][r] + bo) * ftanh(c);
    h_dst[(size_t)mrow * 512 + j] = (__bf16)h;
    c_dst[(size_t)mrow * 512 + j] = c;
    if (last) h_f32[(size_t)mrow * 512 + j] = h;
  }
}

// ---------------- batchnorm helpers ----------------
__global__ void stats1_kernel(const float* __restrict__ in, int ld, int N,
                              int rows_per_blk, float* __restrict__ partial)
{
  int b = blockIdx.x;
  int r0 = b * rows_per_blk;
  for (int c = threadIdx.x; c < N; c += blockDim.x) {
    float s = 0.0f, sq = 0.0f;
    for (int r = 0; r < rows_per_blk; ++r) {
      float v = in[(size_t)(r0 + r) * ld + c];
      s += v; sq += v * v;
    }
    partial[(size_t)(2 * b) * N + c] = s;
    partial[(size_t)(2 * b + 1) * N + c] = sq;
  }
}

__global__ void stats2_kernel(const float* __restrict__ partial, int nb, int N,
                              float invM, float* __restrict__ stats)
{
  int c = blockIdx.x * blockDim.x + threadIdx.x;
  if (c >= N) return;
  float s = 0.0f, sq = 0.0f;
  for (int b = 0; b < nb; ++b) {
    s  += partial[(size_t)(2 * b) * N + c];
    sq += partial[(size_t)(2 * b + 1) * N + c];
  }
  float mean = s * invM;
  float var  = sq * invM - mean * mean;
  stats[c]     = mean;
  stats[N + c] = rsqrtf(fmaxf(var, 0.0f) + 1e-5f);
}

__global__ void norm_kernel(const float* __restrict__ in, int ldin,
                            const float* __restrict__ stats, int N, int cshift, int gmask,
                            const float* __restrict__ g, const float* __restrict__ b,
                            __bf16* __restrict__ outp, int ldc, int total)
{
  for (int idx = blockIdx.x * blockDim.x + threadIdx.x; idx < total;
       idx += gridDim.x * blockDim.x) {
    int row = idx >> cshift;
    int c = idx & (N - 1);
    float v = (in[(size_t)row * ldin + c] - stats[c]) * stats[N + c];
    int gi = c & gmask;
    v = v * g[gi] + b[gi];
    outp[(size_t)row * ldc + c] = (__bf16)v;
  }
}

// ---------------- output heads: one wave per output ----------------
__global__ void head_kernel(const int* __restrict__ flagp,
                            const __bf16* __restrict__ tmp3,
                            const float* __restrict__ pf,
                            void* __restrict__ outp)
{
  const int bf = *flagp;
  const int gw   = blockIdx.x * 4 + (threadIdx.x >> 6);  // 0..1023
  const int lane = threadIdx.x & 63;
  const int which = gw >> 9;
  const int n     = gw & 511;
  const __bf16* row = tmp3 + (size_t)n * 512 + which * 256;
  const float* ow = pf + PF_OW + which * 256;
  float s = 0.0f;
#pragma unroll
  for (int i = 0; i < 4; ++i) {
    const int k = lane + 64 * i;
    s += (float)row[k] * ow[k];
  }
#pragma unroll
  for (int off = 32; off > 0; off >>= 1)
    s += __shfl_down(s, off);
  if (lane == 0) {
    float v = fsig(s + pf[PF_OB + which]);
    if (bf) ((__bf16*)outp)[gw] = (__bf16)v;
    else    ((float*)outp)[gw]  = v;
  }
}

// ---------------- launch ----------------
extern "C" void kernel_launch(void* const* d_in, const int* in_sizes, int n_in,
                              void* d_out, int out_size, void* d_ws, size_t ws_size,
                              hipStream_t stream) {
  const void* operators       = d_in[0];
  const void* extra_infos     = d_in[1];
  const void* condition1s     = d_in[2];
  const void* samples         = d_in[4];
  const void* condition_masks = d_in[5];
  const int*  mapping         = (const int*)d_in[6];
  (void)in_sizes; (void)n_in; (void)out_size; (void)ws_size;

  char* ws = (char*)d_ws;
  size_t off = 0;
  auto alloc = [&](size_t bytes) -> void* {
    void* p = ws + off;
    off += (bytes + 255) & ~(size_t)255;
    return p;
  };
  int*    flag     = (int*)   alloc(256);
  __bf16* w1s      = (__bf16*)alloc((size_t)2048 * 544 * 2);
  __bf16* w2s      = (__bf16*)alloc((size_t)2048 * 1152 * 2);
  __bf16* wcat2    = (__bf16*)alloc(512 * 512 * 2);
  __bf16* cond_w_bf   = (__bf16*)alloc(256 * 512 * 2);
  __bf16* sample_w_bf = (__bf16*)alloc(256 * 1000 * 2);
  __bf16* w3cat_bf    = (__bf16*)alloc(512 * 256 * 2);
  float*  mask_f   = (float*) alloc(10240 * 4);
  float*  pf       = (float*) alloc(PF_TOTAL * 4);
  __bf16* samp_bf  = (__bf16*)alloc((size_t)10240 * 1000 * 2);
  __bf16* h_last   = (__bf16*)alloc((size_t)10272 * 512 * 2);
  float*  condtmp  = (float*) alloc((size_t)10240 * 256 * 4);
  __bf16* Astage   = (__bf16*)alloc((size_t)20 * 512 * 640 * 2);
  __bf16* hs0      = (__bf16*)alloc(512 * 512 * 2);
  __bf16* hs1      = (__bf16*)alloc(512 * 512 * 2);
  float*  cs0      = (float*) alloc(512 * 512 * 4);
  float*  cs1      = (float*) alloc(512 * 512 * 4);
  float*  h_f32    = (float*) alloc(512 * 512 * 4);
  __bf16* zbuf     = (__bf16*)alloc(512 * 512 * 2);
  float*  tmp1     = (float*) alloc(512 * 512 * 4);
  __bf16* tmp2     = (__bf16*)alloc(512 * 512 * 2);
  __bf16* tmp3     = (__bf16*)alloc(512 * 512 * 2);
  float*  partial  = (float*) alloc(64 * 2 * 512 * 4);
  float*  statsb   = (float*) alloc(2 * 512 * 4);

  detect_kernel<<<1, 64, 0, stream>>>((const unsigned*)condition_masks, flag);
  prep_kernel<<<4096, 256, 0, stream>>>(flag,
      d_in[7], d_in[8], d_in[9], d_in[10],
      d_in[17], d_in[18], d_in[19], d_in[20],
      d_in[23], d_in[25], d_in[24], d_in[26],
      d_in[13], d_in[14], d_in[11], d_in[12],
      d_in[15], d_in[16], d_in[21], d_in[22],
      d_in[27], d_in[28],
      d_in[29], d_in[30], d_in[31], d_in[32],
      d_in[33], d_in[34], d_in[35], d_in[36],
      condition_masks,
      w1s, w2s, wcat2, cond_w_bf, sample_w_bf, w3cat_bf, mask_f, pf);

  // f32 path: samples -> bf16 BEFORE fused1 (kernel boundary = the sync
  // that fused1's sampgemm branch needs; R20's in-kernel version raced).
  conv_samples_kernel<<<4096, 256, 0, stream>>>(flag, samples, samp_bf);

  // lstm1 + sampgemm + featcopy in one launch
  fused1_kernel<<<FUSED_BLOCKS, 1024, 0, stream>>>(flag,
      condition1s, w1s, pf + PF_BIAS1, h_last,
      samples, samp_bf, sample_w_bf, pf + PF_SAMPB, Astage + 379, mask_f,
      operators, extra_infos, Astage);

  // cond = bn1(relu(h_last @ cond_w^T + cond_b)) -> Astage cols 123..378
  gemm_kernel<1,0,0><<<dim3(4,160), 256, 0, stream>>>(h_last, 512, cond_w_bf, 512,
      pf + PF_CONDB, condtmp, nullptr, 256, nullptr, 512);
  stats1_kernel<<<64, 256, 0, stream>>>(condtmp, 256, 256, 160, partial);
  stats2_kernel<<<1, 256, 0, stream>>>(partial, 64, 256, 1.0f / 10240.0f, statsb);
  norm_kernel<<<2560, 256, 0, stream>>>(condtmp, 256, statsb, 256, 8, 255,
      pf + PF_BN1G, pf + PF_BN1B, Astage + 123, 640, 10240 * 256);

  // tree: lvl 19 (zero state) down to 0; ping-pong state by level parity
  for (int lvl = 19; lvl >= 0; --lvl) {
    __bf16* hd = (lvl & 1) ? hs1 : hs0;
    float*  cd = (lvl & 1) ? cs1 : cs0;
    const __bf16* hsrc = (lvl & 1) ? hs0 : hs1;
    const float*  csrc = (lvl & 1) ? cs0 : cs1;
    treelvl_kernel<<<dim3(32,8), 1024, 0, stream>>>(
        Astage + (size_t)lvl * 512 * 640, w2s, pf + PF_BIAS2,
        mapping + lvl * 1024, hsrc, csrc, hd, cd, h_f32,
        (lvl == 19) ? 1 : 0, (lvl == 0) ? 1 : 0);
  }

  // z = bn2(hid)
  stats1_kernel<<<8, 256, 0, stream>>>(h_f32, 512, 512, 64, partial);
  stats2_kernel<<<2, 256, 0, stream>>>(partial, 8, 512, 1.0f / 512.0f, statsb);
  norm_kernel<<<256, 256, 0, stream>>>(h_f32, 512, statsb, 512, 9, 511,
      pf + PF_BN2G, pf + PF_BN2B, zbuf, 512, 512 * 512);

  // [t1|t2] = bn3(relu(z @ [t1_w2;t2_w2]^T + b))
  gemm_kernel<1,0,0><<<dim3(8,8), 256, 0, stream>>>(zbuf, 512, wcat2, 512,
      pf + PF_BCAT2, tmp1, nullptr, 512, nullptr, 512);
  stats1_kernel<<<8, 256, 0, stream>>>(tmp1, 512, 512, 64, partial);
  stats2_kernel<<<2, 256, 0, stream>>>(partial, 8, 512, 1.0f / 512.0f, statsb);
  norm_kernel<<<256, 256, 0, stream>>>(tmp1, 512, statsb, 512, 9, 255,
      pf + PF_BN3G, pf + PF_BN3B, tmp2, 512, 512 * 512);

  // relu(t @ w3^T + b3) for both heads
  gemm_kernel<1,1,0><<<dim3(4,8), 256, 0, stream>>>(tmp2, 512, w3cat_bf, 256,
      pf + PF_B3CAT, nullptr, tmp3, 512, nullptr, 256);
  gemm_kernel<1,1,0><<<dim3(4,8), 256, 0, stream>>>(tmp2 + 256, 512, w3cat_bf + 256 * 256, 256,
      pf + PF_B3CAT + 256, nullptr, tmp3 + 256, 512, nullptr, 256);

  head_kernel<<<256, 256, 0, stream>>>(flag, tmp3, pf, d_out);
}

// Round 12
// 922.005 us; speedup vs baseline: 1.8780x; 1.0137x over previous
//
#include <hip/hip_runtime.h>
#include <hip/hip_bf16.h>

// Representation_32074815766664 — bf16 I/O (runtime-detected f32 fallback),
// bf16 MFMA internally, f32 accumulation/state.
//
// R22 change vs R21 (935 us — WIN, best):
//  - Fuse cond GEMM + bn1 stats1 into lstm1's epilogue: when an lstm1 block
//    finishes, its 48 rows of h are still in LDS. The separate condgemm
//    re-read h_last (10.5MB) and stats1 re-read condtmp (10.5MB), each with
//    a launch. Now: each of the 16 waves computes 3 tiles of
//    relu(h @ cond_w^T + cond_b) (48 MFMAs/wave, ~1% more matrix work,
//    A-frags from LDS), writes condtmp f32, and shfl-reduces its own
//    column sums/sumsq into partial[214] (stats1 gone). Pad rows >=10240
//    masked from stores and sums. stats2 -> nb=214, N=256.
//  - lstm1 timestep loop / tree / bn / head FROZEN at R21 forms.

typedef __bf16 bf16x8 __attribute__((ext_vector_type(8)));
typedef float f32x4 __attribute__((ext_vector_type(4)));

#define MROWS 10240
#define LDH1  552     // padded LDS stride (2-way bank aliasing only)
#define L1_ROWS 48
#define L1_BLOCKS 214 // ceil(10240/48)
#define SAMP_BASE 214 // 160 blocks (640 virtual)
#define FEAT_BASE 374 // 40 blocks
#define FUSED_BLOCKS 414

// pf (canonical f32 params) offsets
#define PF_BIAS1   0
#define PF_BIAS2   2048
#define PF_CONDB   4096
#define PF_SAMPB   4352
#define PF_BCAT2   4608
#define PF_B3CAT   5120
#define PF_BN1G    5632
#define PF_BN1B    5888
#define PF_BN2G    6144
#define PF_BN2B    6656
#define PF_BN3G    7168
#define PF_BN3B    7424
#define PF_OW      7680
#define PF_OB      8192
#define PF_TOTAL   8194

// sig(x) = 1/(1+exp(-x)); robust without clamps: exp->inf => rcp->0.
__device__ __forceinline__ float fsig(float x) {
  return __builtin_amdgcn_rcpf(1.0f + __expf(-x));
}
// tanh(x) = 2*sig(2x) - 1; robust at both infinities.
__device__ __forceinline__ float ftanh(float x) {
  return fmaf(2.0f, __builtin_amdgcn_rcpf(1.0f + __expf(-2.0f * x)), -1.0f);
}
__device__ __forceinline__ bf16x8 bzero8() {
  bf16x8 z;
#pragma unroll
  for (int i = 0; i < 8; ++i) z[i] = (__bf16)0.0f;
  return z;
}
__device__ __forceinline__ float ld_in(const void* p, long i, int bf) {
  return bf ? (float)((const __bf16*)p)[i] : ((const float*)p)[i];
}

// ---------------- detect ----------------
__global__ void detect_kernel(const unsigned* __restrict__ masks, int* __restrict__ flag) {
  if (blockIdx.x == 0 && threadIdx.x == 0)
    *flag = (masks[0] == 0x3F803F80u) ? 1 : 0;
}

// ---------------- prep: canonicalize; w1s swizzled, w2s swizzled ----------------
// w1s: elem((cgt*17+kk)*4+g, lane, e) = w_aug1[g*512+cgt*16+(lane&15)][kk*32+(lane>>4)*8+e]
__global__ void prep_kernel(const int* __restrict__ flagp,
    const void* w_ih1, const void* w_hh1, const void* b_ih1, const void* b_hh1,
    const void* w_ih2, const void* w_hh2, const void* b_ih2, const void* b_hh2,
    const void* t1_w2, const void* t2_w2, const void* t1_b2, const void* t2_b2,
    const void* cond_w, const void* cond_b, const void* sample_w, const void* sample_b,
    const void* bn1_g, const void* bn1_b, const void* bn2_g, const void* bn2_b,
    const void* bn3_g, const void* bn3_b,
    const void* t1_w3, const void* t1_b3, const void* t2_w3, const void* t2_b3,
    const void* t1_ow, const void* t1_ob, const void* t2_ow, const void* t2_ob,
    const void* masks,
    __bf16* __restrict__ w1s, __bf16* __restrict__ w2s,
    __bf16* __restrict__ wcat2, __bf16* __restrict__ cond_w_bf,
    __bf16* __restrict__ sample_w_bf, __bf16* __restrict__ w3cat_bf,
    float* __restrict__ mask_f, float* __restrict__ pf)
{
  const int bf = *flagp;
  const int S1 = 2048 * 544;   // w1s swizzled
  const int S2 = 2048 * 1152;  // w2s swizzled
  const int S3 = 512 * 512;
  const int S4 = 256 * 512;
  const int S5 = 256 * 1000;
  const int S6 = 512 * 256;
  const int S7 = 10240;
  const int total = S1 + S2 + S3 + S4 + S5 + S6 + S7 + PF_TOTAL;
  for (int idx = blockIdx.x * blockDim.x + threadIdx.x; idx < total;
       idx += gridDim.x * blockDim.x) {
    int i = idx;
    if (i < S1) {
      int e = i & 7, l = (i >> 3) & 63, g = (i >> 9) & 3;
      int grp = i >> 11;               // cgt*17 + kk
      int kk = grp % 17, cgt = grp / 17;
      int colq = l & 15, quad = l >> 4;
      int row = g * 512 + cgt * 16 + colq;
      int k = kk * 32 + quad * 8 + e;
      float v = (k < 512) ? ld_in(w_hh1, (long)row * 512 + k, bf)
              : (k < 525) ? ld_in(w_ih1, (long)row * 13 + (k - 512), bf) : 0.0f;
      w1s[i] = (__bf16)v;
      continue;
    }
    i -= S1;
    if (i < S2) {
      int e = i & 7, l = (i >> 3) & 63, g = (i >> 9) & 3;
      int grp = i >> 11;               // jt*36 + kk
      int kk = grp % 36, jt = grp / 36;
      int colq = l & 15, quad = l >> 4;
      int row = g * 512 + jt * 16 + colq;
      int k = kk * 32 + quad * 8 + e;
      float v = (k < 635) ? ld_in(w_ih2, (long)row * 635 + k, bf)
              : (k < 640) ? 0.0f : ld_in(w_hh2, (long)row * 512 + (k - 640), bf);
      w2s[i] = (__bf16)v;
      continue;
    }
    i -= S2;
    if (i < S3) {
      int r = i >> 9, k = i & 511;
      wcat2[i] = (__bf16)((r < 256) ? ld_in(t1_w2, r * 512 + k, bf)
                                    : ld_in(t2_w2, (r - 256) * 512 + k, bf));
      continue;
    }
    i -= S3;
    if (i < S4) { cond_w_bf[i] = (__bf16)ld_in(cond_w, i, bf); continue; }
    i -= S4;
    if (i < S5) { sample_w_bf[i] = (__bf16)ld_in(sample_w, i, bf); continue; }
    i -= S5;
    if (i < S6) {
      int r = i >> 8, k = i & 255;
      w3cat_bf[i] = (__bf16)((r < 256) ? ld_in(t1_w3, r * 256 + k, bf)
                                       : ld_in(t2_w3, (r - 256) * 256 + k, bf));
      continue;
    }
    i -= S6;
    if (i < S7) { mask_f[i] = ld_in(masks, i, bf); continue; }
    i -= S7;
    {
      int j = i;
      float v;
      if      (j < 2048) v = ld_in(b_ih1, j, bf) + ld_in(b_hh1, j, bf);
      else if (j < 4096) v = ld_in(b_ih2, j - 2048, bf) + ld_in(b_hh2, j - 2048, bf);
      else if (j < 4352) v = ld_in(cond_b, j - 4096, bf);
      else if (j < 4608) v = ld_in(sample_b, j - 4352, bf);
      else if (j < 5120) { int k = j - 4608; v = (k < 256) ? ld_in(t1_b2, k, bf) : ld_in(t2_b2, k - 256, bf); }
      else if (j < 5632) { int k = j - 5120; v = (k < 256) ? ld_in(t1_b3, k, bf) : ld_in(t2_b3, k - 256, bf); }
      else if (j < 5888) v = ld_in(bn1_g, j - 5632, bf);
      else if (j < 6144) v = ld_in(bn1_b, j - 5888, bf);
      else if (j < 6656) v = ld_in(bn2_g, j - 6144, bf);
      else if (j < 7168) v = ld_in(bn2_b, j - 6656, bf);
      else if (j < 7424) v = ld_in(bn3_g, j - 7168, bf);
      else if (j < 7680) v = ld_in(bn3_b, j - 7424, bf);
      else if (j < 8192) { int k = j - 7680; v = (k < 256) ? ld_in(t1_ow, k, bf) : ld_in(t2_ow, k - 256, bf); }
      else v = (j == 8192) ? ld_in(t1_ob, 0, bf) : ld_in(t2_ob, 0, bf);
      pf[j] = v;
    }
  }
}

// ---------------- samples -> bf16 (only needed on f32 path) ----------------
// Separate kernel: its completion is the sync that fused1's sampgemm needs.
__global__ void conv_samples_kernel(const int* __restrict__ flagp,
                                    const void* __restrict__ samples,
                                    __bf16* __restrict__ dst)
{
  const int bf = *flagp;
  if (bf) return;   // bf16 input is already the matrix the GEMM reads
  for (long i = blockIdx.x * blockDim.x + threadIdx.x; i < 10240000L;
       i += (long)gridDim.x * blockDim.x)
    dst[i] = (__bf16)ld_in(samples, i, bf);
}

// ---------------- fused: lstm1 (blocks 0..213, FROZEN loop) + cond-gemm/bn1-
// stats epilogue + sampgemm + featcopy on the idle CUs ----------------
__global__ __launch_bounds__(1024, 4) void fused1_kernel(
    const int* __restrict__ flagp,
    const void* __restrict__ cond1,       // (10240,10,13)
    const __bf16* __restrict__ w1s,       // swizzled (2048x544)
    const float*  __restrict__ bias,      // (2048) = pf+PF_BIAS1
    __bf16* __restrict__ h_out,           // (10272,512) padded
    const void* __restrict__ samples_raw, // sampgemm A (bf16 path)
    const __bf16* __restrict__ samp_bf,   // f32 path: pre-converted copy
    const __bf16* __restrict__ sample_w_bf,
    const float* __restrict__ sampb,      // pf+PF_SAMPB
    __bf16* __restrict__ samp_out,        // Astage+379 (ldc 640)
    const float* __restrict__ mask,
    const void* __restrict__ ops,         // featcopy inputs
    const void* __restrict__ extra,
    __bf16* __restrict__ Astage,          // featcopy dst (stride 640)
    const __bf16* __restrict__ cond_w_bf, // (256,512) cond weights
    const float* __restrict__ condb,      // pf+PF_CONDB
    float* __restrict__ condtmp,          // (10240,256) f32
    float* __restrict__ partial)          // (214,2,256) bn1 partial sums
{
  const int bf = *flagp;
  const int tid = threadIdx.x;

  if (blockIdx.x < L1_BLOCKS) {
    // ================= lstm1 — R12 form, FROZEN =================
    __shared__ __attribute__((aligned(16))) __bf16 hbuf[2][L1_ROWS * LDH1];
    const int wave = tid >> 6;
    const int lane = tid & 63;
    const int colq = lane & 15;
    const int quad = lane >> 4;
    const int r0   = blockIdx.x * L1_ROWS;

    {
      bf16x8 z8 = bzero8();
      for (int i = tid * 8; i < 2 * L1_ROWS * LDH1; i += 1024 * 8)
        *(bf16x8*)&hbuf[0][i] = z8;
    }
    __syncthreads();
    if (tid < L1_ROWS * 8) {           // stage x_0 into buf 0
      int row = tid >> 3, jj = tid & 7;
      int gr = r0 + row;
      if (gr < MROWS) {
        long base = (long)gr * 130;  // t=0
        hbuf[0][row * LDH1 + 512 + jj] = (__bf16)ld_in(cond1, base + jj, bf);
        if (jj < 5) hbuf[0][row * LDH1 + 520 + jj] = (__bf16)ld_in(cond1, base + 8 + jj, bf);
      }
    }
    __syncthreads();

    float c_reg[2][3][4];
#pragma unroll
    for (int a = 0; a < 2; ++a)
#pragma unroll
      for (int b = 0; b < 3; ++b)
#pragma unroll
        for (int r = 0; r < 4; ++r) c_reg[a][b][r] = 0.0f;

    const int jbase = wave * 32;

    float bI[2], bF[2], bG[2], bO[2];
#pragma unroll
    for (int cg = 0; cg < 2; ++cg) {
      const int j = jbase + cg * 16 + colq;
      bI[cg] = bias[j];
      bF[cg] = bias[512 + j];
      bG[cg] = bias[1024 + j];
      bO[cg] = bias[1536 + j];
    }

#pragma unroll 1
    for (int t = 0; t < 10; ++t) {
      const __bf16* hcur = hbuf[t & 1];
      __bf16* hnxt = hbuf[(t + 1) & 1];
#pragma unroll
      for (int cg = 0; cg < 2; ++cg) {
        const int jc = jbase + cg * 16;
        f32x4 acc[3][4];
#pragma unroll
        for (int a = 0; a < 3; ++a)
#pragma unroll
          for (int g = 0; g < 4; ++g)
#pragma unroll
            for (int r = 0; r < 4; ++r) acc[a][g][r] = 0.0f;

        const __bf16* wp = w1s + ((size_t)(wave * 2 + cg) * 17 * 4 * 512) + (lane << 3);
#pragma unroll 1
        for (int kk = 0; kk < 17; ++kk) {
          const int kof = (kk << 5) + (quad << 3);
          bf16x8 af[3];
#pragma unroll
          for (int rt = 0; rt < 3; ++rt)
            af[rt] = *(const bf16x8*)&hcur[(rt * 16 + colq) * LDH1 + kof];
          bf16x8 bfr[4];
#pragma unroll
          for (int g = 0; g < 4; ++g)
            bfr[g] = *(const bf16x8*)&wp[(kk * 4 + g) << 9];
#pragma unroll
          for (int g = 0; g < 4; ++g)
#pragma unroll
            for (int rt = 0; rt < 3; ++rt)
              acc[rt][g] = __builtin_amdgcn_mfma_f32_16x16x32_bf16(af[rt], bfr[g], acc[rt][g], 0, 0, 0);
        }
#pragma unroll
        for (int rt = 0; rt < 3; ++rt)
#pragma unroll
          for (int r = 0; r < 4; ++r) {
            float c = fsig(acc[rt][1][r] + bF[cg]) * c_reg[cg][rt][r]
                    + fsig(acc[rt][0][r] + bI[cg]) * ftanh(acc[rt][2][r] + bG[cg]);
            c_reg[cg][rt][r] = c;
            float h = fsig(acc[rt][3][r] + bO[cg]) * ftanh(c);
            hnxt[(rt * 16 + quad * 4 + r) * LDH1 + jc + colq] = (__bf16)h;
          }
      }
      if (t < 9 && tid < L1_ROWS * 8) {   // stage x_{t+1} into next buffer
        int row = tid >> 3, jj = tid & 7;
        int gr = r0 + row;
        if (gr < MROWS) {
          long base = ((long)gr * 10 + (t + 1)) * 13;
          hnxt[row * LDH1 + 512 + jj] = (__bf16)ld_in(cond1, base + jj, bf);
          if (jj < 5) hnxt[row * LDH1 + 520 + jj] = (__bf16)ld_in(cond1, base + 8 + jj, bf);
        }
      }
      __syncthreads();
    }

    // final h is in buffer 0 (t=10 even)
    for (int i = tid; i < L1_ROWS * 64; i += 1024) {
      int row = i >> 6;
      int cb  = (i & 63) << 3;
      *(bf16x8*)&h_out[(size_t)(r0 + row) * 512 + cb] = *(const bf16x8*)&hbuf[0][row * LDH1 + cb];
    }

    // ===== R22 epilogue: cond = relu(h @ cond_w^T + condb) + bn1 partials ==
    // h (48x512) still in hbuf[0]. Wave w owns col tile ct = w (16 cols),
    // 3 row tiles. 48 MFMAs/wave. Pad rows >= MROWS masked everywhere.
    {
      const int ct = wave;          // 0..15 -> cols ct*16 + colq
      f32x4 cacc[3];
#pragma unroll
      for (int rt = 0; rt < 3; ++rt)
#pragma unroll
        for (int r = 0; r < 4; ++r) cacc[rt][r] = 0.0f;

      const __bf16* wb = cond_w_bf + (size_t)(ct * 16 + colq) * 512;
#pragma unroll 1
      for (int kk = 0; kk < 16; ++kk) {
        const int kof = (kk << 5) + (quad << 3);
        bf16x8 bfr = *(const bf16x8*)&wb[kof];
#pragma unroll
        for (int rt = 0; rt < 3; ++rt) {
          bf16x8 af = *(const bf16x8*)&hbuf[0][(rt * 16 + colq) * LDH1 + kof];
          cacc[rt] = __builtin_amdgcn_mfma_f32_16x16x32_bf16(af, bfr, cacc[rt], 0, 0, 0);
        }
      }
      const int col = ct * 16 + colq;
      const float bv = condb[col];
      float s1 = 0.0f, s2 = 0.0f;
#pragma unroll
      for (int rt = 0; rt < 3; ++rt)
#pragma unroll
        for (int r = 0; r < 4; ++r) {
          const int lrow = rt * 16 + quad * 4 + r;
          const int grow = r0 + lrow;
          float v = fmaxf(cacc[rt][r] + bv, 0.0f);
          if (grow < MROWS) {
            condtmp[(size_t)grow * 256 + col] = v;
            s1 += v;
            s2 += v * v;
          }
        }
      // reduce across the 4 quads (lanes colq, colq+16, colq+32, colq+48)
      s1 += __shfl_xor(s1, 16); s2 += __shfl_xor(s2, 16);
      s1 += __shfl_xor(s1, 32); s2 += __shfl_xor(s2, 32);
      if (quad == 0) {
        partial[(size_t)(2 * blockIdx.x) * 256 + col]     = s1;
        partial[(size_t)(2 * blockIdx.x + 1) * 256 + col] = s2;
      }
    }
    return;
  }

  if (blockIdx.x < FEAT_BASE) {
    // ================= sampgemm: 4 virtual 256-thr blocks =================
    const __bf16* A = bf ? (const __bf16*)samples_raw : samp_bf;
    const int vb   = (blockIdx.x - SAMP_BASE) * 4 + (tid >> 8);  // 0..639
    const int bx   = vb & 3;
    const int by   = vb >> 2;
    const int t    = tid & 255;
    const int wave = t >> 6;
    const int lane = t & 63;
    const int colq = lane & 15;
    const int quad = lane >> 4;
    const int m0 = by * 64 + (wave >> 1) * 32;
    const int n0 = bx * 64 + (wave & 1) * 32;
    const int K = 1000;

    f32x4 acc[2][2];
#pragma unroll
    for (int a = 0; a < 2; ++a)
#pragma unroll
      for (int b = 0; b < 2; ++b)
#pragma unroll
        for (int r = 0; r < 4; ++r) acc[a][b][r] = 0.0f;

    for (int kk = 0; kk < 32; ++kk) {
      const int kof = (kk << 5) + (quad << 3);
      bf16x8 a0, a1, b0, b1;
      if (kof < K) {
        a0 = *(const bf16x8*)&A[(size_t)(m0 + colq) * 1000 + kof];
        a1 = *(const bf16x8*)&A[(size_t)(m0 + 16 + colq) * 1000 + kof];
        b0 = *(const bf16x8*)&sample_w_bf[(size_t)(n0 + colq) * 1000 + kof];
        b1 = *(const bf16x8*)&sample_w_bf[(size_t)(n0 + 16 + colq) * 1000 + kof];
      } else {
        a0 = bzero8(); a1 = a0; b0 = a0; b1 = a0;
      }
      acc[0][0] = __builtin_amdgcn_mfma_f32_16x16x32_bf16(a0, b0, acc[0][0], 0, 0, 0);
      acc[0][1] = __builtin_amdgcn_mfma_f32_16x16x32_bf16(a0, b1, acc[0][1], 0, 0, 0);
      acc[1][0] = __builtin_amdgcn_mfma_f32_16x16x32_bf16(a1, b0, acc[1][0], 0, 0, 0);
      acc[1][1] = __builtin_amdgcn_mfma_f32_16x16x32_bf16(a1, b1, acc[1][1], 0, 0, 0);
    }
#pragma unroll
    for (int ai = 0; ai < 2; ++ai)
#pragma unroll
      for (int bi = 0; bi < 2; ++bi) {
        const int col = n0 + bi * 16 + colq;
        const float bv = sampb[col];
#pragma unroll
        for (int r = 0; r < 4; ++r) {
          const int row = m0 + ai * 16 + quad * 4 + r;
          float v = fmaxf(acc[ai][bi][r] + bv, 0.0f) * mask[row];
          samp_out[(size_t)row * 640 + col] = (__bf16)v;
        }
      }
    return;
  }

  // ================= featcopy (grid-stride over 10240*128) =================
  for (int idx = (blockIdx.x - FEAT_BASE) * 1024 + tid; idx < 10240 * 128;
       idx += 40 * 1024) {
    int m = idx >> 7, c = idx & 127;
    float v; int col;
    if (c < 15)       { v = ld_in(ops, (long)m * 15 + c, bf);            col = c; }
    else if (c < 123) { v = ld_in(extra, (long)m * 108 + (c - 15), bf);  col = c; }
    else              { v = 0.0f;                                        col = 512 + c; } // 635..639
    Astage[(size_t)m * 640 + col] = (__bf16)v;
  }
}

// ---------------- generic MFMA GEMM: out = act(A @ W^T + bias) [* mask] ----------------
template<int ACT, int OUTBF, int MASKED>
__global__ __launch_bounds__(256, 4) void gemm_kernel(
    const __bf16* __restrict__ A, int lda,
    const __bf16* __restrict__ W, int ldw,
    const float* __restrict__ bias,
    float* __restrict__ outf, __bf16* __restrict__ outb, int ldc,
    const float* __restrict__ mask, int K)
{
  const int tid  = threadIdx.x;
  const int wave = tid >> 6;
  const int lane = tid & 63;
  const int colq = lane & 15;
  const int quad = lane >> 4;
  const int m0 = blockIdx.y * 64 + (wave >> 1) * 32;
  const int n0 = blockIdx.x * 64 + (wave & 1) * 32;

  f32x4 acc[2][2];
#pragma unroll
  for (int a = 0; a < 2; ++a)
#pragma unroll
    for (int b = 0; b < 2; ++b)
#pragma unroll
      for (int r = 0; r < 4; ++r) acc[a][b][r] = 0.0f;

  const int nk = (K + 31) >> 5;
  for (int kk = 0; kk < nk; ++kk) {
    const int kof = (kk << 5) + (quad << 3);
    bf16x8 a0, a1, b0, b1;
    if (kof < K) {
      a0 = *(const bf16x8*)&A[(size_t)(m0 + colq) * lda + kof];
      a1 = *(const bf16x8*)&A[(size_t)(m0 + 16 + colq) * lda + kof];
      b0 = *(const bf16x8*)&W[(size_t)(n0 + colq) * ldw + kof];
      b1 = *(const bf16x8*)&W[(size_t)(n0 + 16 + colq) * ldw + kof];
    } else {
      a0 = bzero8(); a1 = a0; b0 = a0; b1 = a0;
    }
    acc[0][0] = __builtin_amdgcn_mfma_f32_16x16x32_bf16(a0, b0, acc[0][0], 0, 0, 0);
    acc[0][1] = __builtin_amdgcn_mfma_f32_16x16x32_bf16(a0, b1, acc[0][1], 0, 0, 0);
    acc[1][0] = __builtin_amdgcn_mfma_f32_16x16x32_bf16(a1, b0, acc[1][0], 0, 0, 0);
    acc[1][1] = __builtin_amdgcn_mfma_f32_16x16x32_bf16(a1, b1, acc[1][1], 0, 0, 0);
  }
#pragma unroll
  for (int ai = 0; ai < 2; ++ai)
#pragma unroll
    for (int bi = 0; bi < 2; ++bi) {
      const int col = n0 + bi * 16 + colq;
      const float bv = bias[col];
#pragma unroll
      for (int r = 0; r < 4; ++r) {
        const int row = m0 + ai * 16 + quad * 4 + r;
        float v = acc[ai][bi][r] + bv;
        if (ACT) v = fmaxf(v, 0.0f);
        if (MASKED) v *= mask[row];
        if (OUTBF) outb[(size_t)row * ldc + col] = (__bf16)v;
        else       outf[(size_t)row * ldc + col] = v;
      }
    }
}

// ---------------- fused tree level: quarter-K gather + GEMM(K=1152) + cell ----------
// R18 form (FROZEN): 1024 thr (16 waves), grid (32,8). kq = wave>>2, wv = wave&3.
__global__ __launch_bounds__(1024, 4) void treelvl_kernel(
    const __bf16* __restrict__ Alvl,    // (512,640) level features
    const __bf16* __restrict__ w2s,     // swizzled (2048x1152)
    const float* __restrict__ bias,     // 2048
    const int* __restrict__ mapping,    // level's (2,512)
    const __bf16* __restrict__ h_src, const float* __restrict__ c_src,
    __bf16* __restrict__ h_dst, float* __restrict__ c_dst,
    float* __restrict__ h_f32, int first, int last)
{
  __shared__ float red[3][16 * 256];   // 3 slots x 16KB, [g*4+r][wv*64+lane]
  const int tid  = threadIdx.x;
  const int wave = tid >> 6;          // 0..15
  const int lane = tid & 63;
  const int colq = lane & 15;
  const int quad = lane >> 4;
  const int wv   = wave & 3;          // row sub-tile 0..3
  const int kq   = wave >> 2;         // K quarter 0..3
  const int jt = blockIdx.x;
  const int mt = blockIdx.y;
  const int rowA = mt * 64 + wv * 16 + colq;

  const __bf16* wbase = w2s + (size_t)jt * 36 * 4 * 512 + (lane << 3);

  f32x4 acc[4];
#pragma unroll
  for (int g = 0; g < 4; ++g)
#pragma unroll
    for (int r = 0; r < 4; ++r) acc[g][r] = 0.0f;

  if (kq < 2) {
    // ---- feature part of K: kq0 -> kk 0..9, kq1 -> kk 10..19 ----
    const __bf16* arow = Alvl + (size_t)rowA * 640;
    const int kb = kq * 10;
#pragma unroll 2
    for (int ki = 0; ki < 10; ++ki) {
      const int kk = kb + ki;
      const int kof = (kk << 5) + (quad << 3);
      bf16x8 afr = *(const bf16x8*)&arow[kof];
      bf16x8 b0 = *(const bf16x8*)&wbase[(kk * 4 + 0) << 9];
      bf16x8 b1 = *(const bf16x8*)&wbase[(kk * 4 + 1) << 9];
      bf16x8 b2 = *(const bf16x8*)&wbase[(kk * 4 + 2) << 9];
      bf16x8 b3 = *(const bf16x8*)&wbase[(kk * 4 + 3) << 9];
      acc[0] = __builtin_amdgcn_mfma_f32_16x16x32_bf16(afr, b0, acc[0], 0, 0, 0);
      acc[1] = __builtin_amdgcn_mfma_f32_16x16x32_bf16(afr, b1, acc[1], 0, 0, 0);
      acc[2] = __builtin_amdgcn_mfma_f32_16x16x32_bf16(afr, b2, acc[2], 0, 0, 0);
      acc[3] = __builtin_amdgcn_mfma_f32_16x16x32_bf16(afr, b3, acc[3], 0, 0, 0);
    }
  } else {
    // ---- gathered-h part of K: kq2 -> kk 20..27, kq3 -> kk 28..35 ----
    int i0 = 0, i1 = 0;
    if (!first) { i0 = mapping[rowA]; i1 = mapping[512 + rowA]; }
    const float s0 = (i0 > 0) ? 0.5f : 0.0f;
    const float s1 = (i1 > 0) ? 0.5f : 0.0f;
    const __bf16* h0p = h_src + (size_t)((i0 > 0 ? i0 : 1) - 1) * 512;
    const __bf16* h1p = h_src + (size_t)((i1 > 0 ? i1 : 1) - 1) * 512;
    const int kb = 20 + (kq - 2) * 8;
#pragma unroll 2
    for (int ki = 0; ki < 8; ++ki) {
      const int kk = kb + ki;
      const int kh = ((kk - 20) << 5) + (quad << 3);
      bf16x8 v0 = *(const bf16x8*)&h0p[kh];
      bf16x8 v1 = *(const bf16x8*)&h1p[kh];
      bf16x8 afr;
#pragma unroll
      for (int e = 0; e < 8; ++e)
        afr[e] = (__bf16)((float)v0[e] * s0 + (float)v1[e] * s1);
      bf16x8 b0 = *(const bf16x8*)&wbase[(kk * 4 + 0) << 9];
      bf16x8 b1 = *(const bf16x8*)&wbase[(kk * 4 + 1) << 9];
      bf16x8 b2 = *(const bf16x8*)&wbase[(kk * 4 + 2) << 9];
      bf16x8 b3 = *(const bf16x8*)&wbase[(kk * 4 + 3) << 9];
      acc[0] = __builtin_amdgcn_mfma_f32_16x16x32_bf16(afr, b0, acc[0], 0, 0, 0);
      acc[1] = __builtin_amdgcn_mfma_f32_16x16x32_bf16(afr, b1, acc[1], 0, 0, 0);
      acc[2] = __builtin_amdgcn_mfma_f32_16x16x32_bf16(afr, b2, acc[2], 0, 0, 0);
      acc[3] = __builtin_amdgcn_mfma_f32_16x16x32_bf16(afr, b3, acc[3], 0, 0, 0);
    }
  }

  if (kq > 0) {
    // stash partials: scalar f32, lane-consecutive -> conflict-free
    float* rp = red[kq - 1];
    const int base = wv * 64 + lane;
#pragma unroll
    for (int g = 0; g < 4; ++g)
#pragma unroll
      for (int r = 0; r < 4; ++r)
        rp[(g * 4 + r) * 256 + base] = acc[g][r];
  }
  __syncthreads();
  if (kq != 0) return;

  // kq0: combine 3 partials, then the unchanged epilogue
  {
    const int base = wv * 64 + lane;
#pragma unroll
    for (int s = 0; s < 3; ++s) {
      const float* rp = red[s];
#pragma unroll
      for (int g = 0; g < 4; ++g)
#pragma unroll
        for (int r = 0; r < 4; ++r)
          acc[g][r] += rp[(g * 4 + r) * 256 + base];
    }
  }

  // epilogue: i,f,g,o -> c,h
  const int j = jt * 16 + colq;
  const float bi  = bias[j];
  const float bff = bias[512 + j];
  const float bg  = bias[1024 + j];
  const float bo  = bias[1536 + j];
#pragma unroll
  for (int r = 0; r < 4; ++r) {
    const int mrow = mt * 64 + wv * 16 + quad * 4 + r;
    float ci = 0.0f;
    if (!first) {
      int a0 = mapping[mrow], a1 = mapping[512 + mrow];
      if (a0 > 0) ci += c_src[(size_t)(a0 - 1) * 512 + j];
      if (a1 > 0) ci += c_src[(size_t)(a1 - 1) * 512 + j];
      ci *= 0.5f;
    }
    float c = fsig(acc[1][r] + bff) * ci + fsig(acc[0][r] + bi) * ftanh(acc[2][r] + bg);
    float h = fsig(acc[3][r] + bo) * ftanh(c);
    h_dst[(size_t)mrow * 512 + j] = (__bf16)h;
    c_dst[(size_t)mrow * 512 + j] = c;
    if (last) h_f32[(size_t)mrow * 512 + j] = h;
  }
}

// ---------------- batchnorm helpers ----------------
__global__ void stats1_kernel(const float* __restrict__ in, int ld, int N,
                              int rows_per_blk, float* __restrict__ partial)
{
  int b = blockIdx.x;
  int r0 = b * rows_per_blk;
  for (int c = threadIdx.x; c < N; c += blockDim.x) {
    float s = 0.0f, sq = 0.0f;
    for (int r = 0; r < rows_per_blk; ++r) {
      float v = in[(size_t)(r0 + r) * ld + c];
      s += v; sq += v * v;
    }
    partial[(size_t)(2 * b) * N + c] = s;
    partial[(size_t)(2 * b + 1) * N + c] = sq;
  }
}

__global__ void stats2_kernel(const float* __restrict__ partial, int nb, int N,
                              float invM, float* __restrict__ stats)
{
  int c = blockIdx.x * blockDim.x + threadIdx.x;
  if (c >= N) return;
  float s = 0.0f, sq = 0.0f;
  for (int b = 0; b < nb; ++b) {
    s  += partial[(size_t)(2 * b) * N + c];
    sq += partial[(size_t)(2 * b + 1) * N + c];
  }
  float mean = s * invM;
  float var  = sq * invM - mean * mean;
  stats[c]     = mean;
  stats[N + c] = rsqrtf(fmaxf(var, 0.0f) + 1e-5f);
}

__global__ void norm_kernel(const float* __restrict__ in, int ldin,
                            const float* __restrict__ stats, int N, int cshift, int gmask,
                            const float* __restrict__ g, const float* __restrict__ b,
                            __bf16* __restrict__ outp, int ldc, int total)
{
  for (int idx = blockIdx.x * blockDim.x + threadIdx.x; idx < total;
       idx += gridDim.x * blockDim.x) {
    int row = idx >> cshift;
    int c = idx & (N - 1);
    float v = (in[(size_t)row * ldin + c] - stats[c]) * stats[N + c];
    int gi = c & gmask;
    v = v * g[gi] + b[gi];
    outp[(size_t)row * ldc + c] = (__bf16)v;
  }
}

// ---------------- output heads: one wave per output ----------------
__global__ void head_kernel(const int* __restrict__ flagp,
                            const __bf16* __restrict__ tmp3,
                            const float* __restrict__ pf,
                            void* __restrict__ outp)
{
  const int bf = *flagp;
  const int gw   = blockIdx.x * 4 + (threadIdx.x >> 6);  // 0..1023
  const int lane = threadIdx.x & 63;
  const int which = gw >> 9;
  const int n     = gw & 511;
  const __bf16* row = tmp3 + (size_t)n * 512 + which * 256;
  const float* ow = pf + PF_OW + which * 256;
  float s = 0.0f;
#pragma unroll
  for (int i = 0; i < 4; ++i) {
    const int k = lane + 64 * i;
    s += (float)row[k] * ow[k];
  }
#pragma unroll
  for (int off = 32; off > 0; off >>= 1)
    s += __shfl_down(s, off);
  if (lane == 0) {
    float v = fsig(s + pf[PF_OB + which]);
    if (bf) ((__bf16*)outp)[gw] = (__bf16)v;
    else    ((float*)outp)[gw]  = v;
  }
}

// ---------------- launch ----------------
extern "C" void kernel_launch(void* const* d_in, const int* in_sizes, int n_in,
                              void* d_out, int out_size, void* d_ws, size_t ws_size,
                              hipStream_t stream) {
  const void* operators       = d_in[0];
  const void* extra_infos     = d_in[1];
  const void* condition1s     = d_in[2];
  const void* samples         = d_in[4];
  const void* condition_masks = d_in[5];
  const int*  mapping         = (const int*)d_in[6];
  (void)in_sizes; (void)n_in; (void)out_size; (void)ws_size;

  char* ws = (char*)d_ws;
  size_t off = 0;
  auto alloc = [&](size_t bytes) -> void* {
    void* p = ws + off;
    off += (bytes + 255) & ~(size_t)255;
    return p;
  };
  int*    flag     = (int*)   alloc(256);
  __bf16* w1s      = (__bf16*)alloc((size_t)2048 * 544 * 2);
  __bf16* w2s      = (__bf16*)alloc((size_t)2048 * 1152 * 2);
  __bf16* wcat2    = (__bf16*)alloc(512 * 512 * 2);
  __bf16* cond_w_bf   = (__bf16*)alloc(256 * 512 * 2);
  __bf16* sample_w_bf = (__bf16*)alloc(256 * 1000 * 2);
  __bf16* w3cat_bf    = (__bf16*)alloc(512 * 256 * 2);
  float*  mask_f   = (float*) alloc(10240 * 4);
  float*  pf       = (float*) alloc(PF_TOTAL * 4);
  __bf16* samp_bf  = (__bf16*)alloc((size_t)10240 * 1000 * 2);
  __bf16* h_last   = (__bf16*)alloc((size_t)10272 * 512 * 2);
  float*  condtmp  = (float*) alloc((size_t)10240 * 256 * 4);
  __bf16* Astage   = (__bf16*)alloc((size_t)20 * 512 * 640 * 2);
  __bf16* hs0      = (__bf16*)alloc(512 * 512 * 2);
  __bf16* hs1      = (__bf16*)alloc(512 * 512 * 2);
  float*  cs0      = (float*) alloc(512 * 512 * 4);
  float*  cs1      = (float*) alloc(512 * 512 * 4);
  float*  h_f32    = (float*) alloc(512 * 512 * 4);
  __bf16* zbuf     = (__bf16*)alloc(512 * 512 * 2);
  float*  tmp1     = (float*) alloc(512 * 512 * 4);
  __bf16* tmp2     = (__bf16*)alloc(512 * 512 * 2);
  __bf16* tmp3     = (__bf16*)alloc(512 * 512 * 2);
  float*  partial  = (float*) alloc((size_t)214 * 2 * 256 * 4 + 8 * 2 * 512 * 4);
  float*  statsb   = (float*) alloc(2 * 512 * 4);

  detect_kernel<<<1, 64, 0, stream>>>((const unsigned*)condition_masks, flag);
  prep_kernel<<<4096, 256, 0, stream>>>(flag,
      d_in[7], d_in[8], d_in[9], d_in[10],
      d_in[17], d_in[18], d_in[19], d_in[20],
      d_in[23], d_in[25], d_in[24], d_in[26],
      d_in[13], d_in[14], d_in[11], d_in[12],
      d_in[15], d_in[16], d_in[21], d_in[22],
      d_in[27], d_in[28],
      d_in[29], d_in[30], d_in[31], d_in[32],
      d_in[33], d_in[34], d_in[35], d_in[36],
      condition_masks,
      w1s, w2s, wcat2, cond_w_bf, sample_w_bf, w3cat_bf, mask_f, pf);

  // f32 path: samples -> bf16 BEFORE fused1 (kernel boundary = the sync
  // that fused1's sampgemm branch needs; R20's in-kernel version raced).
  conv_samples_kernel<<<4096, 256, 0, stream>>>(flag, samples, samp_bf);

  // lstm1 (+cond gemm + bn1 partial stats) + sampgemm + featcopy in one launch
  fused1_kernel<<<FUSED_BLOCKS, 1024, 0, stream>>>(flag,
      condition1s, w1s, pf + PF_BIAS1, h_last,
      samples, samp_bf, sample_w_bf, pf + PF_SAMPB, Astage + 379, mask_f,
      operators, extra_infos, Astage,
      cond_w_bf, pf + PF_CONDB, condtmp, partial);

  // bn1: stats2 over the 214 per-block partials, then normalize into Astage
  stats2_kernel<<<1, 256, 0, stream>>>(partial, 214, 256, 1.0f / 10240.0f, statsb);
  norm_kernel<<<2560, 256, 0, stream>>>(condtmp, 256, statsb, 256, 8, 255,
      pf + PF_BN1G, pf + PF_BN1B, Astage + 123, 640, 10240 * 256);

  // tree: lvl 19 (zero state) down to 0; ping-pong state by level parity
  for (int lvl = 19; lvl >= 0; --lvl) {
    __bf16* hd = (lvl & 1) ? hs1 : hs0;
    float*  cd = (lvl & 1) ? cs1 : cs0;
    const __bf16* hsrc = (lvl & 1) ? hs0 : hs1;
    const float*  csrc = (lvl & 1) ? cs0 : cs1;
    treelvl_kernel<<<dim3(32,8), 1024, 0, stream>>>(
        Astage + (size_t)lvl * 512 * 640, w2s, pf + PF_BIAS2,
        mapping + lvl * 1024, hsrc, csrc, hd, cd, h_f32,
        (lvl == 19) ? 1 : 0, (lvl == 0) ? 1 : 0);
  }

  // z = bn2(hid)
  stats1_kernel<<<8, 256, 0, stream>>>(h_f32, 512, 512, 64, partial);
  stats2_kernel<<<2, 256, 0, stream>>>(partial, 8, 512, 1.0f / 512.0f, statsb);
  norm_kernel<<<256, 256, 0, stream>>>(h_f32, 512, statsb, 512, 9, 511,
      pf + PF_BN2G, pf + PF_BN2B, zbuf, 512, 512 * 512);

  // [t1|t2] = bn3(relu(z @ [t1_w2;t2_w2]^T + b))
  gemm_kernel<1,0,0><<<dim3(8,8), 256, 0, stream>>>(zbuf, 512, wcat2, 512,
      pf + PF_BCAT2, tmp1, nullptr, 512, nullptr, 512);
  stats1_kernel<<<8, 256, 0, stream>>>(tmp1, 512, 512, 64, partial);
  stats2_kernel<<<2, 256, 0, stream>>>(partial, 8, 512, 1.0f / 512.0f, statsb);
  norm_kernel<<<256, 256, 0, stream>>>(tmp1, 512, statsb, 512, 9, 255,
      pf + PF_BN3G, pf + PF_BN3B, tmp2, 512, 512 * 512);

  // relu(t @ w3^T + b3) for both heads
  gemm_kernel<1,1,0><<<dim3(4,8), 256, 0, stream>>>(tmp2, 512, w3cat_bf, 256,
      pf + PF_B3CAT, nullptr, tmp3, 512, nullptr, 256);
  gemm_kernel<1,1,0><<<dim3(4,8), 256, 0, stream>>>(tmp2 + 256, 512, w3cat_bf + 256 * 256, 256,
      pf + PF_B3CAT + 256, nullptr, tmp3 + 256, 512, nullptr, 256);

  head_kernel<<<256, 256, 0, stream>>>(flag, tmp3, pf, d_out);
}

// Round 13
// 901.937 us; speedup vs baseline: 1.9198x; 1.0223x over previous
//
#include <hip/hip_runtime.h>
#include <hip/hip_bf16.h>

// Representation_32074815766664 — bf16 I/O (runtime-detected f32 fallback),
// bf16 MFMA internally, f32 accumulation/state.
//
// R23 changes vs R22 (922 us — WIN, best):
//  - conv_samples kernel ELIMINATED: fused1's sampgemm branch converts f32
//    samples -> bf16 during the A-frag load (2 dwordx4 + 8 cvt per frag,
//    VALU on blocks shadowed by lstm1). Same RNE cast => identical numerics.
//    Also kills the R20-race concern at the root (reader converts).
//  - bn1 stats2 was 1 block x 214-iter serial loop (~15 us latency on the
//    critical path). New bn1stats2: wave-per-column (64 blocks x 4 waves,
//    lane-strided + shfl_down) ~3 us.
//  - Two w3 head GEMMs merged into one launch (grid (8,8), which = bx>>2).
//  - fused1 lstm1 loop / cond epilogue / tree / bn / head FROZEN.

typedef __bf16 bf16x8 __attribute__((ext_vector_type(8)));
typedef float f32x4 __attribute__((ext_vector_type(4)));

#define MROWS 10240
#define LDH1  552     // padded LDS stride (2-way bank aliasing only)
#define L1_ROWS 48
#define L1_BLOCKS 214 // ceil(10240/48)
#define SAMP_BASE 214 // 160 blocks (640 virtual)
#define FEAT_BASE 374 // 40 blocks
#define FUSED_BLOCKS 414

// pf (canonical f32 params) offsets
#define PF_BIAS1   0
#define PF_BIAS2   2048
#define PF_CONDB   4096
#define PF_SAMPB   4352
#define PF_BCAT2   4608
#define PF_B3CAT   5120
#define PF_BN1G    5632
#define PF_BN1B    5888
#define PF_BN2G    6144
#define PF_BN2B    6656
#define PF_BN3G    7168
#define PF_BN3B    7424
#define PF_OW      7680
#define PF_OB      8192
#define PF_TOTAL   8194

// sig(x) = 1/(1+exp(-x)); robust without clamps: exp->inf => rcp->0.
__device__ __forceinline__ float fsig(float x) {
  return __builtin_amdgcn_rcpf(1.0f + __expf(-x));
}
// tanh(x) = 2*sig(2x) - 1; robust at both infinities.
__device__ __forceinline__ float ftanh(float x) {
  return fmaf(2.0f, __builtin_amdgcn_rcpf(1.0f + __expf(-2.0f * x)), -1.0f);
}
__device__ __forceinline__ bf16x8 bzero8() {
  bf16x8 z;
#pragma unroll
  for (int i = 0; i < 8; ++i) z[i] = (__bf16)0.0f;
  return z;
}
__device__ __forceinline__ float ld_in(const void* p, long i, int bf) {
  return bf ? (float)((const __bf16*)p)[i] : ((const float*)p)[i];
}

// ---------------- detect ----------------
__global__ void detect_kernel(const unsigned* __restrict__ masks, int* __restrict__ flag) {
  if (blockIdx.x == 0 && threadIdx.x == 0)
    *flag = (masks[0] == 0x3F803F80u) ? 1 : 0;
}

// ---------------- prep: canonicalize; w1s swizzled, w2s swizzled ----------------
// w1s: elem((cgt*17+kk)*4+g, lane, e) = w_aug1[g*512+cgt*16+(lane&15)][kk*32+(lane>>4)*8+e]
__global__ void prep_kernel(const int* __restrict__ flagp,
    const void* w_ih1, const void* w_hh1, const void* b_ih1, const void* b_hh1,
    const void* w_ih2, const void* w_hh2, const void* b_ih2, const void* b_hh2,
    const void* t1_w2, const void* t2_w2, const void* t1_b2, const void* t2_b2,
    const void* cond_w, const void* cond_b, const void* sample_w, const void* sample_b,
    const void* bn1_g, const void* bn1_b, const void* bn2_g, const void* bn2_b,
    const void* bn3_g, const void* bn3_b,
    const void* t1_w3, const void* t1_b3, const void* t2_w3, const void* t2_b3,
    const void* t1_ow, const void* t1_ob, const void* t2_ow, const void* t2_ob,
    const void* masks,
    __bf16* __restrict__ w1s, __bf16* __restrict__ w2s,
    __bf16* __restrict__ wcat2, __bf16* __restrict__ cond_w_bf,
    __bf16* __restrict__ sample_w_bf, __bf16* __restrict__ w3cat_bf,
    float* __restrict__ mask_f, float* __restrict__ pf)
{
  const int bf = *flagp;
  const int S1 = 2048 * 544;   // w1s swizzled
  const int S2 = 2048 * 1152;  // w2s swizzled
  const int S3 = 512 * 512;
  const int S4 = 256 * 512;
  const int S5 = 256 * 1000;
  const int S6 = 512 * 256;
  const int S7 = 10240;
  const int total = S1 + S2 + S3 + S4 + S5 + S6 + S7 + PF_TOTAL;
  for (int idx = blockIdx.x * blockDim.x + threadIdx.x; idx < total;
       idx += gridDim.x * blockDim.x) {
    int i = idx;
    if (i < S1) {
      int e = i & 7, l = (i >> 3) & 63, g = (i >> 9) & 3;
      int grp = i >> 11;               // cgt*17 + kk
      int kk = grp % 17, cgt = grp / 17;
      int colq = l & 15, quad = l >> 4;
      int row = g * 512 + cgt * 16 + colq;
      int k = kk * 32 + quad * 8 + e;
      float v = (k < 512) ? ld_in(w_hh1, (long)row * 512 + k, bf)
              : (k < 525) ? ld_in(w_ih1, (long)row * 13 + (k - 512), bf) : 0.0f;
      w1s[i] = (__bf16)v;
      continue;
    }
    i -= S1;
    if (i < S2) {
      int e = i & 7, l = (i >> 3) & 63, g = (i >> 9) & 3;
      int grp = i >> 11;               // jt*36 + kk
      int kk = grp % 36, jt = grp / 36;
      int colq = l & 15, quad = l >> 4;
      int row = g * 512 + jt * 16 + colq;
      int k = kk * 32 + quad * 8 + e;
      float v = (k < 635) ? ld_in(w_ih2, (long)row * 635 + k, bf)
              : (k < 640) ? 0.0f : ld_in(w_hh2, (long)row * 512 + (k - 640), bf);
      w2s[i] = (__bf16)v;
      continue;
    }
    i -= S2;
    if (i < S3) {
      int r = i >> 9, k = i & 511;
      wcat2[i] = (__bf16)((r < 256) ? ld_in(t1_w2, r * 512 + k, bf)
                                    : ld_in(t2_w2, (r - 256) * 512 + k, bf));
      continue;
    }
    i -= S3;
    if (i < S4) { cond_w_bf[i] = (__bf16)ld_in(cond_w, i, bf); continue; }
    i -= S4;
    if (i < S5) { sample_w_bf[i] = (__bf16)ld_in(sample_w, i, bf); continue; }
    i -= S5;
    if (i < S6) {
      int r = i >> 8, k = i & 255;
      w3cat_bf[i] = (__bf16)((r < 256) ? ld_in(t1_w3, r * 256 + k, bf)
                                       : ld_in(t2_w3, (r - 256) * 256 + k, bf));
      continue;
    }
    i -= S6;
    if (i < S7) { mask_f[i] = ld_in(masks, i, bf); continue; }
    i -= S7;
    {
      int j = i;
      float v;
      if      (j < 2048) v = ld_in(b_ih1, j, bf) + ld_in(b_hh1, j, bf);
      else if (j < 4096) v = ld_in(b_ih2, j - 2048, bf) + ld_in(b_hh2, j - 2048, bf);
      else if (j < 4352) v = ld_in(cond_b, j - 4096, bf);
      else if (j < 4608) v = ld_in(sample_b, j - 4352, bf);
      else if (j < 5120) { int k = j - 4608; v = (k < 256) ? ld_in(t1_b2, k, bf) : ld_in(t2_b2, k - 256, bf); }
      else if (j < 5632) { int k = j - 5120; v = (k < 256) ? ld_in(t1_b3, k, bf) : ld_in(t2_b3, k - 256, bf); }
      else if (j < 5888) v = ld_in(bn1_g, j - 5632, bf);
      else if (j < 6144) v = ld_in(bn1_b, j - 5888, bf);
      else if (j < 6656) v = ld_in(bn2_g, j - 6144, bf);
      else if (j < 7168) v = ld_in(bn2_b, j - 6656, bf);
      else if (j < 7424) v = ld_in(bn3_g, j - 7168, bf);
      else if (j < 7680) v = ld_in(bn3_b, j - 7424, bf);
      else if (j < 8192) { int k = j - 7680; v = (k < 256) ? ld_in(t1_ow, k, bf) : ld_in(t2_ow, k - 256, bf); }
      else v = (j == 8192) ? ld_in(t1_ob, 0, bf) : ld_in(t2_ob, 0, bf);
      pf[j] = v;
    }
  }
}

// ---------------- fused: lstm1 (blocks 0..213, FROZEN loop) + cond-gemm/bn1-
// stats epilogue + sampgemm (f32-converting) + featcopy ----------------
__global__ __launch_bounds__(1024, 4) void fused1_kernel(
    const int* __restrict__ flagp,
    const void* __restrict__ cond1,       // (10240,10,13)
    const __bf16* __restrict__ w1s,       // swizzled (2048x544)
    const float*  __restrict__ bias,      // (2048) = pf+PF_BIAS1
    __bf16* __restrict__ h_out,           // (10272,512) padded
    const void* __restrict__ samples_raw, // sampgemm A (bf16 OR f32, by flag)
    const __bf16* __restrict__ sample_w_bf,
    const float* __restrict__ sampb,      // pf+PF_SAMPB
    __bf16* __restrict__ samp_out,        // Astage+379 (ldc 640)
    const float* __restrict__ mask,
    const void* __restrict__ ops,         // featcopy inputs
    const void* __restrict__ extra,
    __bf16* __restrict__ Astage,          // featcopy dst (stride 640)
    const __bf16* __restrict__ cond_w_bf, // (256,512) cond weights
    const float* __restrict__ condb,      // pf+PF_CONDB
    float* __restrict__ condtmp,          // (10240,256) f32
    float* __restrict__ partial)          // (214,2,256) bn1 partial sums
{
  const int bf = *flagp;
  const int tid = threadIdx.x;

  if (blockIdx.x < L1_BLOCKS) {
    // ================= lstm1 — R12 form, FROZEN =================
    __shared__ __attribute__((aligned(16))) __bf16 hbuf[2][L1_ROWS * LDH1];
    const int wave = tid >> 6;
    const int lane = tid & 63;
    const int colq = lane & 15;
    const int quad = lane >> 4;
    const int r0   = blockIdx.x * L1_ROWS;

    {
      bf16x8 z8 = bzero8();
      for (int i = tid * 8; i < 2 * L1_ROWS * LDH1; i += 1024 * 8)
        *(bf16x8*)&hbuf[0][i] = z8;
    }
    __syncthreads();
    if (tid < L1_ROWS * 8) {           // stage x_0 into buf 0
      int row = tid >> 3, jj = tid & 7;
      int gr = r0 + row;
      if (gr < MROWS) {
        long base = (long)gr * 130;  // t=0
        hbuf[0][row * LDH1 + 512 + jj] = (__bf16)ld_in(cond1, base + jj, bf);
        if (jj < 5) hbuf[0][row * LDH1 + 520 + jj] = (__bf16)ld_in(cond1, base + 8 + jj, bf);
      }
    }
    __syncthreads();

    float c_reg[2][3][4];
#pragma unroll
    for (int a = 0; a < 2; ++a)
#pragma unroll
      for (int b = 0; b < 3; ++b)
#pragma unroll
        for (int r = 0; r < 4; ++r) c_reg[a][b][r] = 0.0f;

    const int jbase = wave * 32;

    float bI[2], bF[2], bG[2], bO[2];
#pragma unroll
    for (int cg = 0; cg < 2; ++cg) {
      const int j = jbase + cg * 16 + colq;
      bI[cg] = bias[j];
      bF[cg] = bias[512 + j];
      bG[cg] = bias[1024 + j];
      bO[cg] = bias[1536 + j];
    }

#pragma unroll 1
    for (int t = 0; t < 10; ++t) {
      const __bf16* hcur = hbuf[t & 1];
      __bf16* hnxt = hbuf[(t + 1) & 1];
#pragma unroll
      for (int cg = 0; cg < 2; ++cg) {
        const int jc = jbase + cg * 16;
        f32x4 acc[3][4];
#pragma unroll
        for (int a = 0; a < 3; ++a)
#pragma unroll
          for (int g = 0; g < 4; ++g)
#pragma unroll
            for (int r = 0; r < 4; ++r) acc[a][g][r] = 0.0f;

        const __bf16* wp = w1s + ((size_t)(wave * 2 + cg) * 17 * 4 * 512) + (lane << 3);
#pragma unroll 1
        for (int kk = 0; kk < 17; ++kk) {
          const int kof = (kk << 5) + (quad << 3);
          bf16x8 af[3];
#pragma unroll
          for (int rt = 0; rt < 3; ++rt)
            af[rt] = *(const bf16x8*)&hcur[(rt * 16 + colq) * LDH1 + kof];
          bf16x8 bfr[4];
#pragma unroll
          for (int g = 0; g < 4; ++g)
            bfr[g] = *(const bf16x8*)&wp[(kk * 4 + g) << 9];
#pragma unroll
          for (int g = 0; g < 4; ++g)
#pragma unroll
            for (int rt = 0; rt < 3; ++rt)
              acc[rt][g] = __builtin_amdgcn_mfma_f32_16x16x32_bf16(af[rt], bfr[g], acc[rt][g], 0, 0, 0);
        }
#pragma unroll
        for (int rt = 0; rt < 3; ++rt)
#pragma unroll
          for (int r = 0; r < 4; ++r) {
            float c = fsig(acc[rt][1][r] + bF[cg]) * c_reg[cg][rt][r]
                    + fsig(acc[rt][0][r] + bI[cg]) * ftanh(acc[rt][2][r] + bG[cg]);
            c_reg[cg][rt][r] = c;
            float h = fsig(acc[rt][3][r] + bO[cg]) * ftanh(c);
            hnxt[(rt * 16 + quad * 4 + r) * LDH1 + jc + colq] = (__bf16)h;
          }
      }
      if (t < 9 && tid < L1_ROWS * 8) {   // stage x_{t+1} into next buffer
        int row = tid >> 3, jj = tid & 7;
        int gr = r0 + row;
        if (gr < MROWS) {
          long base = ((long)gr * 10 + (t + 1)) * 13;
          hnxt[row * LDH1 + 512 + jj] = (__bf16)ld_in(cond1, base + jj, bf);
          if (jj < 5) hnxt[row * LDH1 + 520 + jj] = (__bf16)ld_in(cond1, base + 8 + jj, bf);
        }
      }
      __syncthreads();
    }

    // final h is in buffer 0 (t=10 even)
    for (int i = tid; i < L1_ROWS * 64; i += 1024) {
      int row = i >> 6;
      int cb  = (i & 63) << 3;
      *(bf16x8*)&h_out[(size_t)(r0 + row) * 512 + cb] = *(const bf16x8*)&hbuf[0][row * LDH1 + cb];
    }

    // ===== cond = relu(h @ cond_w^T + condb) + bn1 partials (R22, FROZEN) ==
    {
      const int ct = wave;          // 0..15 -> cols ct*16 + colq
      f32x4 cacc[3];
#pragma unroll
      for (int rt = 0; rt < 3; ++rt)
#pragma unroll
        for (int r = 0; r < 4; ++r) cacc[rt][r] = 0.0f;

      const __bf16* wb = cond_w_bf + (size_t)(ct * 16 + colq) * 512;
#pragma unroll 1
      for (int kk = 0; kk < 16; ++kk) {
        const int kof = (kk << 5) + (quad << 3);
        bf16x8 bfr = *(const bf16x8*)&wb[kof];
#pragma unroll
        for (int rt = 0; rt < 3; ++rt) {
          bf16x8 af = *(const bf16x8*)&hbuf[0][(rt * 16 + colq) * LDH1 + kof];
          cacc[rt] = __builtin_amdgcn_mfma_f32_16x16x32_bf16(af, bfr, cacc[rt], 0, 0, 0);
        }
      }
      const int col = ct * 16 + colq;
      const float bv = condb[col];
      float s1 = 0.0f, s2 = 0.0f;
#pragma unroll
      for (int rt = 0; rt < 3; ++rt)
#pragma unroll
        for (int r = 0; r < 4; ++r) {
          const int lrow = rt * 16 + quad * 4 + r;
          const int grow = r0 + lrow;
          float v = fmaxf(cacc[rt][r] + bv, 0.0f);
          if (grow < MROWS) {
            condtmp[(size_t)grow * 256 + col] = v;
            s1 += v;
            s2 += v * v;
          }
        }
      s1 += __shfl_xor(s1, 16); s2 += __shfl_xor(s2, 16);
      s1 += __shfl_xor(s1, 32); s2 += __shfl_xor(s2, 32);
      if (quad == 0) {
        partial[(size_t)(2 * blockIdx.x) * 256 + col]     = s1;
        partial[(size_t)(2 * blockIdx.x + 1) * 256 + col] = s2;
      }
    }
    return;
  }

  if (blockIdx.x < FEAT_BASE) {
    // ====== sampgemm: 4 virtual 256-thr blocks; f32 A converted on load ====
    const int vb   = (blockIdx.x - SAMP_BASE) * 4 + (tid >> 8);  // 0..639
    const int bx   = vb & 3;
    const int by   = vb >> 2;
    const int t    = tid & 255;
    const int wave = t >> 6;
    const int lane = t & 63;
    const int colq = lane & 15;
    const int quad = lane >> 4;
    const int m0 = by * 64 + (wave >> 1) * 32;
    const int n0 = bx * 64 + (wave & 1) * 32;
    const int K = 1000;

    f32x4 acc[2][2];
#pragma unroll
    for (int a = 0; a < 2; ++a)
#pragma unroll
      for (int b = 0; b < 2; ++b)
#pragma unroll
        for (int r = 0; r < 4; ++r) acc[a][b][r] = 0.0f;

    for (int kk = 0; kk < 32; ++kk) {
      const int kof = (kk << 5) + (quad << 3);
      bf16x8 a0, a1, b0, b1;
      if (kof < K) {
        if (bf) {
          const __bf16* A = (const __bf16*)samples_raw;
          a0 = *(const bf16x8*)&A[(size_t)(m0 + colq) * 1000 + kof];
          a1 = *(const bf16x8*)&A[(size_t)(m0 + 16 + colq) * 1000 + kof];
        } else {
          const float* Af = (const float*)samples_raw;
          const float* p0 = &Af[(size_t)(m0 + colq) * 1000 + kof];
          const float* p1 = &Af[(size_t)(m0 + 16 + colq) * 1000 + kof];
#pragma unroll
          for (int e = 0; e < 8; ++e) {
            a0[e] = (__bf16)p0[e];
            a1[e] = (__bf16)p1[e];
          }
        }
        b0 = *(const bf16x8*)&sample_w_bf[(size_t)(n0 + colq) * 1000 + kof];
        b1 = *(const bf16x8*)&sample_w_bf[(size_t)(n0 + 16 + colq) * 1000 + kof];
      } else {
        a0 = bzero8(); a1 = a0; b0 = a0; b1 = a0;
      }
      acc[0][0] = __builtin_amdgcn_mfma_f32_16x16x32_bf16(a0, b0, acc[0][0], 0, 0, 0);
      acc[0][1] = __builtin_amdgcn_mfma_f32_16x16x32_bf16(a0, b1, acc[0][1], 0, 0, 0);
      acc[1][0] = __builtin_amdgcn_mfma_f32_16x16x32_bf16(a1, b0, acc[1][0], 0, 0, 0);
      acc[1][1] = __builtin_amdgcn_mfma_f32_16x16x32_bf16(a1, b1, acc[1][1], 0, 0, 0);
    }
#pragma unroll
    for (int ai = 0; ai < 2; ++ai)
#pragma unroll
      for (int bi = 0; bi < 2; ++bi) {
        const int col = n0 + bi * 16 + colq;
        const float bv = sampb[col];
#pragma unroll
        for (int r = 0; r < 4; ++r) {
          const int row = m0 + ai * 16 + quad * 4 + r;
          float v = fmaxf(acc[ai][bi][r] + bv, 0.0f) * mask[row];
          samp_out[(size_t)row * 640 + col] = (__bf16)v;
        }
      }
    return;
  }

  // ================= featcopy (grid-stride over 10240*128) =================
  for (int idx = (blockIdx.x - FEAT_BASE) * 1024 + tid; idx < 10240 * 128;
       idx += 40 * 1024) {
    int m = idx >> 7, c = idx & 127;
    float v; int col;
    if (c < 15)       { v = ld_in(ops, (long)m * 15 + c, bf);            col = c; }
    else if (c < 123) { v = ld_in(extra, (long)m * 108 + (c - 15), bf);  col = c; }
    else              { v = 0.0f;                                        col = 512 + c; } // 635..639
    Astage[(size_t)m * 640 + col] = (__bf16)v;
  }
}

// ---------------- bn1 stats2: wave-per-column over 214 partials ----------------
__global__ void bn1stats2_kernel(const float* __restrict__ partial,
                                 float* __restrict__ stats)
{
  const int col  = blockIdx.x * 4 + (threadIdx.x >> 6); // 0..255
  const int lane = threadIdx.x & 63;
  float s = 0.0f, sq = 0.0f;
  for (int b = lane; b < L1_BLOCKS; b += 64) {
    s  += partial[(size_t)(2 * b) * 256 + col];
    sq += partial[(size_t)(2 * b + 1) * 256 + col];
  }
#pragma unroll
  for (int off = 32; off > 0; off >>= 1) {
    s  += __shfl_down(s, off);
    sq += __shfl_down(sq, off);
  }
  if (lane == 0) {
    float mean = s * (1.0f / 10240.0f);
    float var  = sq * (1.0f / 10240.0f) - mean * mean;
    stats[col]       = mean;
    stats[256 + col] = rsqrtf(fmaxf(var, 0.0f) + 1e-5f);
  }
}

// ---------------- generic MFMA GEMM: out = act(A @ W^T + bias) [* mask] ----------------
template<int ACT, int OUTBF, int MASKED>
__global__ __launch_bounds__(256, 4) void gemm_kernel(
    const __bf16* __restrict__ A, int lda,
    const __bf16* __restrict__ W, int ldw,
    const float* __restrict__ bias,
    float* __restrict__ outf, __bf16* __restrict__ outb, int ldc,
    const float* __restrict__ mask, int K)
{
  const int tid  = threadIdx.x;
  const int wave = tid >> 6;
  const int lane = tid & 63;
  const int colq = lane & 15;
  const int quad = lane >> 4;
  const int m0 = blockIdx.y * 64 + (wave >> 1) * 32;
  const int n0 = blockIdx.x * 64 + (wave & 1) * 32;

  f32x4 acc[2][2];
#pragma unroll
  for (int a = 0; a < 2; ++a)
#pragma unroll
    for (int b = 0; b < 2; ++b)
#pragma unroll
      for (int r = 0; r < 4; ++r) acc[a][b][r] = 0.0f;

  const int nk = (K + 31) >> 5;
  for (int kk = 0; kk < nk; ++kk) {
    const int kof = (kk << 5) + (quad << 3);
    bf16x8 a0, a1, b0, b1;
    if (kof < K) {
      a0 = *(const bf16x8*)&A[(size_t)(m0 + colq) * lda + kof];
      a1 = *(const bf16x8*)&A[(size_t)(m0 + 16 + colq) * lda + kof];
      b0 = *(const bf16x8*)&W[(size_t)(n0 + colq) * ldw + kof];
      b1 = *(const bf16x8*)&W[(size_t)(n0 + 16 + colq) * ldw + kof];
    } else {
      a0 = bzero8(); a1 = a0; b0 = a0; b1 = a0;
    }
    acc[0][0] = __builtin_amdgcn_mfma_f32_16x16x32_bf16(a0, b0, acc[0][0], 0, 0, 0);
    acc[0][1] = __builtin_amdgcn_mfma_f32_16x16x32_bf16(a0, b1, acc[0][1], 0, 0, 0);
    acc[1][0] = __builtin_amdgcn_mfma_f32_16x16x32_bf16(a1, b0, acc[1][0], 0, 0, 0);
    acc[1][1] = __builtin_amdgcn_mfma_f32_16x16x32_bf16(a1, b1, acc[1][1], 0, 0, 0);
  }
#pragma unroll
  for (int ai = 0; ai < 2; ++ai)
#pragma unroll
    for (int bi = 0; bi < 2; ++bi) {
      const int col = n0 + bi * 16 + colq;
      const float bv = bias[col];
#pragma unroll
      for (int r = 0; r < 4; ++r) {
        const int row = m0 + ai * 16 + quad * 4 + r;
        float v = acc[ai][bi][r] + bv;
        if (ACT) v = fmaxf(v, 0.0f);
        if (MASKED) v *= mask[row];
        if (OUTBF) outb[(size_t)row * ldc + col] = (__bf16)v;
        else       outf[(size_t)row * ldc + col] = v;
      }
    }
}

// ---------------- merged w3 head GEMMs: both heads in one launch ----------------
// grid (8,8): which = bx>>2, n-tile = bx&3. out = relu(t @ w3^T + b3) per head.
__global__ __launch_bounds__(256, 4) void w3gemm_kernel(
    const __bf16* __restrict__ tmp2,    // (512,512), head h uses cols h*256..
    const __bf16* __restrict__ w3cat,   // (512,256) [t1;t2]
    const float* __restrict__ b3,       // pf+PF_B3CAT (512)
    __bf16* __restrict__ tmp3)          // (512,512), head h writes cols h*256..
{
  const int which = blockIdx.x >> 2;
  const int bx    = blockIdx.x & 3;
  const __bf16* A = tmp2 + which * 256;
  const __bf16* W = w3cat + (size_t)which * 256 * 256;
  const float* bias = b3 + which * 256;
  __bf16* outb = tmp3 + which * 256;
  const int K = 256, lda = 512, ldw = 256, ldc = 512;

  const int tid  = threadIdx.x;
  const int wave = tid >> 6;
  const int lane = tid & 63;
  const int colq = lane & 15;
  const int quad = lane >> 4;
  const int m0 = blockIdx.y * 64 + (wave >> 1) * 32;
  const int n0 = bx * 64 + (wave & 1) * 32;

  f32x4 acc[2][2];
#pragma unroll
  for (int a = 0; a < 2; ++a)
#pragma unroll
    for (int b = 0; b < 2; ++b)
#pragma unroll
      for (int r = 0; r < 4; ++r) acc[a][b][r] = 0.0f;

  for (int kk = 0; kk < 8; ++kk) {
    const int kof = (kk << 5) + (quad << 3);
    bf16x8 a0 = *(const bf16x8*)&A[(size_t)(m0 + colq) * lda + kof];
    bf16x8 a1 = *(const bf16x8*)&A[(size_t)(m0 + 16 + colq) * lda + kof];
    bf16x8 b0 = *(const bf16x8*)&W[(size_t)(n0 + colq) * ldw + kof];
    bf16x8 b1 = *(const bf16x8*)&W[(size_t)(n0 + 16 + colq) * ldw + kof];
    acc[0][0] = __builtin_amdgcn_mfma_f32_16x16x32_bf16(a0, b0, acc[0][0], 0, 0, 0);
    acc[0][1] = __builtin_amdgcn_mfma_f32_16x16x32_bf16(a0, b1, acc[0][1], 0, 0, 0);
    acc[1][0] = __builtin_amdgcn_mfma_f32_16x16x32_bf16(a1, b0, acc[1][0], 0, 0, 0);
    acc[1][1] = __builtin_amdgcn_mfma_f32_16x16x32_bf16(a1, b1, acc[1][1], 0, 0, 0);
  }
  (void)K;
#pragma unroll
  for (int ai = 0; ai < 2; ++ai)
#pragma unroll
    for (int bi = 0; bi < 2; ++bi) {
      const int col = n0 + bi * 16 + colq;
      const float bv = bias[col];
#pragma unroll
      for (int r = 0; r < 4; ++r) {
        const int row = m0 + ai * 16 + quad * 4 + r;
        float v = fmaxf(acc[ai][bi][r] + bv, 0.0f);
        outb[(size_t)row * ldc + col] = (__bf16)v;
      }
    }
}

// ---------------- fused tree level: quarter-K gather + GEMM(K=1152) + cell ----------
// R18 form (FROZEN): 1024 thr (16 waves), grid (32,8). kq = wave>>2, wv = wave&3.
__global__ __launch_bounds__(1024, 4) void treelvl_kernel(
    const __bf16* __restrict__ Alvl,    // (512,640) level features
    const __bf16* __restrict__ w2s,     // swizzled (2048x1152)
    const float* __restrict__ bias,     // 2048
    const int* __restrict__ mapping,    // level's (2,512)
    const __bf16* __restrict__ h_src, const float* __restrict__ c_src,
    __bf16* __restrict__ h_dst, float* __restrict__ c_dst,
    float* __restrict__ h_f32, int first, int last)
{
  __shared__ float red[3][16 * 256];   // 3 slots x 16KB, [g*4+r][wv*64+lane]
  const int tid  = threadIdx.x;
  const int wave = tid >> 6;          // 0..15
  const int lane = tid & 63;
  const int colq = lane & 15;
  const int quad = lane >> 4;
  const int wv   = wave & 3;          // row sub-tile 0..3
  const int kq   = wave >> 2;         // K quarter 0..3
  const int jt = blockIdx.x;
  const int mt = blockIdx.y;
  const int rowA = mt * 64 + wv * 16 + colq;

  const __bf16* wbase = w2s + (size_t)jt * 36 * 4 * 512 + (lane << 3);

  f32x4 acc[4];
#pragma unroll
  for (int g = 0; g < 4; ++g)
#pragma unroll
    for (int r = 0; r < 4; ++r) acc[g][r] = 0.0f;

  if (kq < 2) {
    // ---- feature part of K: kq0 -> kk 0..9, kq1 -> kk 10..19 ----
    const __bf16* arow = Alvl + (size_t)rowA * 640;
    const int kb = kq * 10;
#pragma unroll 2
    for (int ki = 0; ki < 10; ++ki) {
      const int kk = kb + ki;
      const int kof = (kk << 5) + (quad << 3);
      bf16x8 afr = *(const bf16x8*)&arow[kof];
      bf16x8 b0 = *(const bf16x8*)&wbase[(kk * 4 + 0) << 9];
      bf16x8 b1 = *(const bf16x8*)&wbase[(kk * 4 + 1) << 9];
      bf16x8 b2 = *(const bf16x8*)&wbase[(kk * 4 + 2) << 9];
      bf16x8 b3 = *(const bf16x8*)&wbase[(kk * 4 + 3) << 9];
      acc[0] = __builtin_amdgcn_mfma_f32_16x16x32_bf16(afr, b0, acc[0], 0, 0, 0);
      acc[1] = __builtin_amdgcn_mfma_f32_16x16x32_bf16(afr, b1, acc[1], 0, 0, 0);
      acc[2] = __builtin_amdgcn_mfma_f32_16x16x32_bf16(afr, b2, acc[2], 0, 0, 0);
      acc[3] = __builtin_amdgcn_mfma_f32_16x16x32_bf16(afr, b3, acc[3], 0, 0, 0);
    }
  } else {
    // ---- gathered-h part of K: kq2 -> kk 20..27, kq3 -> kk 28..35 ----
    int i0 = 0, i1 = 0;
    if (!first) { i0 = mapping[rowA]; i1 = mapping[512 + rowA]; }
    const float s0 = (i0 > 0) ? 0.5f : 0.0f;
    const float s1 = (i1 > 0) ? 0.5f : 0.0f;
    const __bf16* h0p = h_src + (size_t)((i0 > 0 ? i0 : 1) - 1) * 512;
    const __bf16* h1p = h_src + (size_t)((i1 > 0 ? i1 : 1) - 1) * 512;
    const int kb = 20 + (kq - 2) * 8;
#pragma unroll 2
    for (int ki = 0; ki < 8; ++ki) {
      const int kk = kb + ki;
      const int kh = ((kk - 20) << 5) + (quad << 3);
      bf16x8 v0 = *(const bf16x8*)&h0p[kh];
      bf16x8 v1 = *(const bf16x8*)&h1p[kh];
      bf16x8 afr;
#pragma unroll
      for (int e = 0; e < 8; ++e)
        afr[e] = (__bf16)((float)v0[e] * s0 + (float)v1[e] * s1);
      bf16x8 b0 = *(const bf16x8*)&wbase[(kk * 4 + 0) << 9];
      bf16x8 b1 = *(const bf16x8*)&wbase[(kk * 4 + 1) << 9];
      bf16x8 b2 = *(const bf16x8*)&wbase[(kk * 4 + 2) << 9];
      bf16x8 b3 = *(const bf16x8*)&wbase[(kk * 4 + 3) << 9];
      acc[0] = __builtin_amdgcn_mfma_f32_16x16x32_bf16(afr, b0, acc[0], 0, 0, 0);
      acc[1] = __builtin_amdgcn_mfma_f32_16x16x32_bf16(afr, b1, acc[1], 0, 0, 0);
      acc[2] = __builtin_amdgcn_mfma_f32_16x16x32_bf16(afr, b2, acc[2], 0, 0, 0);
      acc[3] = __builtin_amdgcn_mfma_f32_16x16x32_bf16(afr, b3, acc[3], 0, 0, 0);
    }
  }

  if (kq > 0) {
    // stash partials: scalar f32, lane-consecutive -> conflict-free
    float* rp = red[kq - 1];
    const int base = wv * 64 + lane;
#pragma unroll
    for (int g = 0; g < 4; ++g)
#pragma unroll
      for (int r = 0; r < 4; ++r)
        rp[(g * 4 + r) * 256 + base] = acc[g][r];
  }
  __syncthreads();
  if (kq != 0) return;

  // kq0: combine 3 partials, then the unchanged epilogue
  {
    const int base = wv * 64 + lane;
#pragma unroll
    for (int s = 0; s < 3; ++s) {
      const float* rp = red[s];
#pragma unroll
      for (int g = 0; g < 4; ++g)
#pragma unroll
        for (int r = 0; r < 4; ++r)
          acc[g][r] += rp[(g * 4 + r) * 256 + base];
    }
  }

  // epilogue: i,f,g,o -> c,h
  const int j = jt * 16 + colq;
  const float bi  = bias[j];
  const float bff = bias[512 + j];
  const float bg  = bias[1024 + j];
  const float bo  = bias[1536 + j];
#pragma unroll
  for (int r = 0; r < 4; ++r) {
    const int mrow = mt * 64 + wv * 16 + quad * 4 + r;
    float ci = 0.0f;
    if (!first) {
      int a0 = mapping[mrow], a1 = mapping[512 + mrow];
      if (a0 > 0) ci += c_src[(size_t)(a0 - 1) * 512 + j];
      if (a1 > 0) ci += c_src[(size_t)(a1 - 1) * 512 + j];
      ci *= 0.5f;
    }
    float c = fsig(acc[1][r] + bff) * ci + fsig(acc[0][r] + bi) * ftanh(acc[2][r] + bg);
    float h = fsig(acc[3][r] + bo) * ftanh(c);
    h_dst[(size_t)mrow * 512 + j] = (__bf16)h;
    c_dst[(size_t)mrow * 512 + j] = c;
    if (last) h_f32[(size_t)mrow * 512 + j] = h;
  }
}

// ---------------- batchnorm helpers ----------------
__global__ void stats1_kernel(const float* __restrict__ in, int ld, int N,
                              int rows_per_blk, float* __restrict__ partial)
{
  int b = blockIdx.x;
  int r0 = b * rows_per_blk;
  for (int c = threadIdx.x; c < N; c += blockDim.x) {
    float s = 0.0f, sq = 0.0f;
    for (int r = 0; r < rows_per_blk; ++r) {
      float v = in[(size_t)(r0 + r) * ld + c];
      s += v; sq += v * v;
    }
    partial[(size_t)(2 * b) * N + c] = s;
    partial[(size_t)(2 * b + 1) * N + c] = sq;
  }
}

__global__ void stats2_kernel(const float* __restrict__ partial, int nb, int N,
                              float invM, float* __restrict__ stats)
{
  int c = blockIdx.x * blockDim.x + threadIdx.x;
  if (c >= N) return;
  float s = 0.0f, sq = 0.0f;
  for (int b = 0; b < nb; ++b) {
    s  += partial[(size_t)(2 * b) * N + c];
    sq += partial[(size_t)(2 * b + 1) * N + c];
  }
  float mean = s * invM;
  float var  = sq * invM - mean * mean;
  stats[c]     = mean;
  stats[N + c] = rsqrtf(fmaxf(var, 0.0f) + 1e-5f);
}

__global__ void norm_kernel(const float* __restrict__ in, int ldin,
                            const float* __restrict__ stats, int N, int cshift, int gmask,
                            const float* __restrict__ g, const float* __restrict__ b,
                            __bf16* __restrict__ outp, int ldc, int total)
{
  for (int idx = blockIdx.x * blockDim.x + threadIdx.x; idx < total;
       idx += gridDim.x * blockDim.x) {
    int row = idx >> cshift;
    int c = idx & (N - 1);
    float v = (in[(size_t)row * ldin + c] - stats[c]) * stats[N + c];
    int gi = c & gmask;
    v = v * g[gi] + b[gi];
    outp[(size_t)row * ldc + c] = (__bf16)v;
  }
}

// ---------------- output heads: one wave per output ----------------
__global__ void head_kernel(const int* __restrict__ flagp,
                            const __bf16* __restrict__ tmp3,
                            const float* __restrict__ pf,
                            void* __restrict__ outp)
{
  const int bf = *flagp;
  const int gw   = blockIdx.x * 4 + (threadIdx.x >> 6);  // 0..1023
  const int lane = threadIdx.x & 63;
  const int which = gw >> 9;
  const int n     = gw & 511;
  const __bf16* row = tmp3 + (size_t)n * 512 + which * 256;
  const float* ow = pf + PF_OW + which * 256;
  float s = 0.0f;
#pragma unroll
  for (int i = 0; i < 4; ++i) {
    const int k = lane + 64 * i;
    s += (float)row[k] * ow[k];
  }
#pragma unroll
  for (int off = 32; off > 0; off >>= 1)
    s += __shfl_down(s, off);
  if (lane == 0) {
    float v = fsig(s + pf[PF_OB + which]);
    if (bf) ((__bf16*)outp)[gw] = (__bf16)v;
    else    ((float*)outp)[gw]  = v;
  }
}

// ---------------- launch ----------------
extern "C" void kernel_launch(void* const* d_in, const int* in_sizes, int n_in,
                              void* d_out, int out_size, void* d_ws, size_t ws_size,
                              hipStream_t stream) {
  const void* operators       = d_in[0];
  const void* extra_infos     = d_in[1];
  const void* condition1s     = d_in[2];
  const void* samples         = d_in[4];
  const void* condition_masks = d_in[5];
  const int*  mapping         = (const int*)d_in[6];
  (void)in_sizes; (void)n_in; (void)out_size; (void)ws_size;

  char* ws = (char*)d_ws;
  size_t off = 0;
  auto alloc = [&](size_t bytes) -> void* {
    void* p = ws + off;
    off += (bytes + 255) & ~(size_t)255;
    return p;
  };
  int*    flag     = (int*)   alloc(256);
  __bf16* w1s      = (__bf16*)alloc((size_t)2048 * 544 * 2);
  __bf16* w2s      = (__bf16*)alloc((size_t)2048 * 1152 * 2);
  __bf16* wcat2    = (__bf16*)alloc(512 * 512 * 2);
  __bf16* cond_w_bf   = (__bf16*)alloc(256 * 512 * 2);
  __bf16* sample_w_bf = (__bf16*)alloc(256 * 1000 * 2);
  __bf16* w3cat_bf    = (__bf16*)alloc(512 * 256 * 2);
  float*  mask_f   = (float*) alloc(10240 * 4);
  float*  pf       = (float*) alloc(PF_TOTAL * 4);
  __bf16* h_last   = (__bf16*)alloc((size_t)10272 * 512 * 2);
  float*  condtmp  = (float*) alloc((size_t)10240 * 256 * 4);
  __bf16* Astage   = (__bf16*)alloc((size_t)20 * 512 * 640 * 2);
  __bf16* hs0      = (__bf16*)alloc(512 * 512 * 2);
  __bf16* hs1      = (__bf16*)alloc(512 * 512 * 2);
  float*  cs0      = (float*) alloc(512 * 512 * 4);
  float*  cs1      = (float*) alloc(512 * 512 * 4);
  float*  h_f32    = (float*) alloc(512 * 512 * 4);
  __bf16* zbuf     = (__bf16*)alloc(512 * 512 * 2);
  float*  tmp1     = (float*) alloc(512 * 512 * 4);
  __bf16* tmp2     = (__bf16*)alloc(512 * 512 * 2);
  __bf16* tmp3     = (__bf16*)alloc(512 * 512 * 2);
  float*  partial  = (float*) alloc((size_t)214 * 2 * 256 * 4 + 8 * 2 * 512 * 4);
  float*  statsb   = (float*) alloc(2 * 512 * 4);

  detect_kernel<<<1, 64, 0, stream>>>((const unsigned*)condition_masks, flag);
  prep_kernel<<<4096, 256, 0, stream>>>(flag,
      d_in[7], d_in[8], d_in[9], d_in[10],
      d_in[17], d_in[18], d_in[19], d_in[20],
      d_in[23], d_in[25], d_in[24], d_in[26],
      d_in[13], d_in[14], d_in[11], d_in[12],
      d_in[15], d_in[16], d_in[21], d_in[22],
      d_in[27], d_in[28],
      d_in[29], d_in[30], d_in[31], d_in[32],
      d_in[33], d_in[34], d_in[35], d_in[36],
      condition_masks,
      w1s, w2s, wcat2, cond_w_bf, sample_w_bf, w3cat_bf, mask_f, pf);

  // lstm1 (+cond gemm + bn1 partial stats) + sampgemm (f32-converting) +
  // featcopy in one launch
  fused1_kernel<<<FUSED_BLOCKS, 1024, 0, stream>>>(flag,
      condition1s, w1s, pf + PF_BIAS1, h_last,
      samples, sample_w_bf, pf + PF_SAMPB, Astage + 379, mask_f,
      operators, extra_infos, Astage,
      cond_w_bf, pf + PF_CONDB, condtmp, partial);

  // bn1: wave-per-column stats over the 214 partials, then normalize
  bn1stats2_kernel<<<64, 256, 0, stream>>>(partial, statsb);
  norm_kernel<<<2560, 256, 0, stream>>>(condtmp, 256, statsb, 256, 8, 255,
      pf + PF_BN1G, pf + PF_BN1B, Astage + 123, 640, 10240 * 256);

  // tree: lvl 19 (zero state) down to 0; ping-pong state by level parity
  for (int lvl = 19; lvl >= 0; --lvl) {
    __bf16* hd = (lvl & 1) ? hs1 : hs0;
    float*  cd = (lvl & 1) ? cs1 : cs0;
    const __bf16* hsrc = (lvl & 1) ? hs0 : hs1;
    const float*  csrc = (lvl & 1) ? cs0 : cs1;
    treelvl_kernel<<<dim3(32,8), 1024, 0, stream>>>(
        Astage + (size_t)lvl * 512 * 640, w2s, pf + PF_BIAS2,
        mapping + lvl * 1024, hsrc, csrc, hd, cd, h_f32,
        (lvl == 19) ? 1 : 0, (lvl == 0) ? 1 : 0);
  }

  // z = bn2(hid)
  stats1_kernel<<<8, 256, 0, stream>>>(h_f32, 512, 512, 64, partial);
  stats2_kernel<<<2, 256, 0, stream>>>(partial, 8, 512, 1.0f / 512.0f, statsb);
  norm_kernel<<<256, 256, 0, stream>>>(h_f32, 512, statsb, 512, 9, 511,
      pf + PF_BN2G, pf + PF_BN2B, zbuf, 512, 512 * 512);

  // [t1|t2] = bn3(relu(z @ [t1_w2;t2_w2]^T + b))
  gemm_kernel<1,0,0><<<dim3(8,8), 256, 0, stream>>>(zbuf, 512, wcat2, 512,
      pf + PF_BCAT2, tmp1, nullptr, 512, nullptr, 512);
  stats1_kernel<<<8, 256, 0, stream>>>(tmp1, 512, 512, 64, partial);
  stats2_kernel<<<2, 256, 0, stream>>>(partial, 8, 512, 1.0f / 512.0f, statsb);
  norm_kernel<<<256, 256, 0, stream>>>(tmp1, 512, statsb, 512, 9, 255,
      pf + PF_BN3G, pf + PF_BN3B, tmp2, 512, 512 * 512);

  // relu(t @ w3^T + b3) for both heads in ONE launch
  w3gemm_kernel<<<dim3(8,8), 256, 0, stream>>>(tmp2, w3cat_bf, pf + PF_B3CAT, tmp3);

  head_kernel<<<256, 256, 0, stream>>>(flag, tmp3, pf, d_out);
}